// Round 7
// baseline (1613.205 us; speedup 1.0000x reference)
//
#include <hip/hip_runtime.h>
#include <hip/hip_bf16.h>
#include <math.h>

#define B_TOTAL 65536
#define D 512
#define H 8
#define K 128
#define M 64
#define D2 1024

typedef __attribute__((ext_vector_type(8))) short short8v;   // 8 bf16 (4 VGPRs)
typedef __attribute__((ext_vector_type(4))) float f32x4;

__device__ __forceinline__ unsigned short f2bf(float f) {
    union { float f; unsigned u; } v; v.f = f;
    unsigned r = v.u + 0x7FFF + ((v.u >> 16) & 1);   // RNE
    return (unsigned short)(r >> 16);
}

__device__ __forceinline__ unsigned pk2(float a, float b) {
    float2 t; t.x = a; t.y = b;
    __hip_bfloat162 h = __float22bfloat162_rn(t);    // v_cvt_pk_bf16_f32
    union { __hip_bfloat162 h; unsigned u; } c; c.h = h;
    return c.u;
}

__device__ __forceinline__ float gelu_exact(float x) {
    return 0.5f * x * (1.0f + erff(x * 0.70710678118654752440f));
}

__device__ __forceinline__ void glds16(const void* g, void* l) {
    __builtin_amdgcn_global_load_lds(
        (const __attribute__((address_space(1))) unsigned int*)g,
        (__attribute__((address_space(3))) unsigned int*)l, 16, 0, 0);
}

// ============== converter: weights -> fragment/chunk-linear bf16 in ws ==============
// W1c: [kc(32)][hd(8)][ntl(4)][lane(64)][j(8)]  (32KB chunks; kc=2*k0+ntg)
//      elem j = W1[hd][32*(kc>>1)+8*(l>>4)+j][16*((kc&1)*4+ntl)+(l&15)]
// W2T: [hd(8)][kb(4)][nt2(4)][lane][j]  elem j = W2[hd][32kb+8(l>>4)+j][16nt2+(l&15)]
// gW1T:[kk(32)][nt(32)][lane][j]        elem j = gW1[32kk+8(l>>4)+j][16nt+(l&15)]
__global__ void convert_weights(const float* __restrict__ W1, const float* __restrict__ W2,
                                const float* __restrict__ gW1,
                                unsigned short* __restrict__ W1c, unsigned short* __restrict__ W2T,
                                unsigned short* __restrict__ gW1T)
{
    int t = blockIdx.x * 256 + threadIdx.x;
    if (t < 65536) {
        int l = t & 63, ntl = (t >> 6) & 3, hd = (t >> 8) & 7, kc = t >> 11;
        int n = 16 * ((kc & 1) * 4 + ntl) + (l & 15);
        int k = 32 * (kc >> 1) + 8 * (l >> 4);
        const float* s = W1 + (size_t)hd * 65536 + (size_t)k * 128 + n;
        short8v o;
        #pragma unroll
        for (int j = 0; j < 8; ++j) o[j] = (short)f2bf(s[(size_t)j * 128]);
        *(short8v*)(W1c + (size_t)t * 8) = o;
    } else if (t < 65536 + 8192) {
        int u = t - 65536;
        int l = u & 63, nt = (u >> 6) & 3, kb = (u >> 8) & 3, hd = u >> 10;
        int m = 16 * nt + (l & 15);
        int k = 32 * kb + 8 * (l >> 4);
        const float* s = W2 + (size_t)hd * 8192 + (size_t)k * 64 + m;
        short8v o;
        #pragma unroll
        for (int j = 0; j < 8; ++j) o[j] = (short)f2bf(s[(size_t)j * 64]);
        *(short8v*)(W2T + (size_t)u * 8) = o;
    } else if (t < 65536 + 8192 + 65536) {
        int u = t - 73728;
        int l = u & 63, nt = (u >> 6) & 31, kb = u >> 11;
        int n = 16 * nt + (l & 15);
        int k = 32 * kb + 8 * (l >> 4);
        const float* s = gW1 + (size_t)k * 512 + n;
        short8v o;
        #pragma unroll
        for (int j = 0; j < 8; ++j) o[j] = (short)f2bf(s[(size_t)j * 512]);
        *(short8v*)(gW1T + (size_t)u * 8) = o;
    }
}

// ============== kernel H: per-head path -> per_aspect ==============
// 2048 blocks x 512 threads (8 waves). 32 batch rows/block; wave w = head w, all rows.
// A-rows 0..31 text, 32..63 image; A-tile LDS-resident fragment-linear
// [k0(16)][lg(4)][a(64)][16B] = 64KB. W1 streamed 32x32KB chunks, glds dbuf.
__global__ __launch_bounds__(512, 2) void head_kernel(
    const float* __restrict__ text, const float* __restrict__ image,
    const unsigned short* __restrict__ W1c, const float* __restrict__ b1,
    const float* __restrict__ ln1g, const float* __restrict__ ln1b,
    const unsigned short* __restrict__ W2T, const float* __restrict__ b2,
    float* __restrict__ out_pa)
{
    __shared__ __align__(1024) char smem[131072];   // sX 64KB | bufW0 32KB | bufW1 32KB

    const int tid = threadIdx.x;
    const int w = tid >> 6, lane = tid & 63, lg = lane >> 4, lc = lane & 15;
    const int hd = w;
    const size_t row0 = (size_t)blockIdx.x * 32;

    char* sXb = smem;
    char* bufW0 = smem + 65536;
    char* bufW1 = smem + 98304;
    const char* W1b = (const char*)W1c;
    const char* W2b = (const char*)W2T;

    // ---- prologue: stage A-tile (frag-linear) + W chunk 0 ----
    {
        const int a = tid >> 3, kq = tid & 7;
        const float* rowp = (a < 32) ? (text + (row0 + a) * 512)
                                     : (image + (row0 + (a - 32)) * 512);
        float4 fv[16];
        #pragma unroll
        for (int i = 0; i < 16; ++i)
            fv[i] = *(const float4*)(rowp + 32 * i + 4 * kq);
        // W chunk 0 -> bufW0 (wave-uniform dst, per-lane src)
        {
            const char* src = W1b + w * 4096 + lane * 16;
            char* dst = bufW0 + w * 4096;
            #pragma unroll
            for (int i = 0; i < 4; ++i) glds16(src + i * 1024, dst + i * 1024);
        }
        const int dbase = (kq >> 1) * 1024 + a * 16 + (kq & 1) * 8;
        #pragma unroll
        for (int i = 0; i < 16; ++i) {
            uint2 pk; pk.x = pk2(fv[i].x, fv[i].y); pk.y = pk2(fv[i].z, fv[i].w);
            *(uint2*)(sXb + i * 4096 + dbase) = pk;
        }
    }
    __syncthreads();

    // ---- GEMM1: 32 chunk-iters (k0 x ntg), dbuf ----
    f32x4 acc[4][8];
    #pragma unroll
    for (int rt = 0; rt < 4; ++rt)
        #pragma unroll
        for (int nt = 0; nt < 8; ++nt) acc[rt][nt] = (f32x4){0.f, 0.f, 0.f, 0.f};

    #pragma unroll
    for (int k0 = 0; k0 < 16; ++k0) {
        short8v af[4];
        #pragma unroll
        for (int rt = 0; rt < 4; ++rt)
            af[rt] = *(const short8v*)(sXb + k0 * 4096 + lg * 1024 + (16 * rt + lc) * 16);
        #pragma unroll
        for (int ntg = 0; ntg < 2; ++ntg) {
            const int kc = 2 * k0 + ntg;
            char* curb = (kc & 1) ? bufW1 : bufW0;
            char* nxtb = (kc & 1) ? bufW0 : bufW1;
            if (kc < 31) {   // prefetch next chunk
                const char* src = W1b + (size_t)(kc + 1) * 32768 + w * 4096 + lane * 16;
                char* dst = nxtb + w * 4096;
                #pragma unroll
                for (int i = 0; i < 4; ++i) glds16(src + i * 1024, dst + i * 1024);
            }
            const char* bb = curb + hd * 4096 + lane * 16;
            #pragma unroll
            for (int ntl = 0; ntl < 4; ++ntl) {
                short8v bf_ = *(const short8v*)(bb + ntl * 1024);
                const int nt = ntg * 4 + ntl;
                #pragma unroll
                for (int rt = 0; rt < 4; ++rt)
                    acc[rt][nt] = __builtin_amdgcn_mfma_f32_16x16x32_bf16(af[rt], bf_, acc[rt][nt], 0, 0, 0);
            }
            __syncthreads();
        }
    }

    // ---- + b1, LN stats ----
    #pragma unroll
    for (int nt = 0; nt < 8; ++nt) {
        float bv = b1[hd * 128 + 16 * nt + lc];
        #pragma unroll
        for (int rt = 0; rt < 4; ++rt)
            #pragma unroll
            for (int reg = 0; reg < 4; ++reg) acc[rt][nt][reg] += bv;
    }
    float mu[4][4], rsig[4][4];
    #pragma unroll
    for (int rt = 0; rt < 4; ++rt)
        #pragma unroll
        for (int reg = 0; reg < 4; ++reg) {
            float s1 = 0.f, s2 = 0.f;
            #pragma unroll
            for (int nt = 0; nt < 8; ++nt) { float v = acc[rt][nt][reg]; s1 += v; s2 += v * v; }
            #pragma unroll
            for (int off = 1; off < 16; off <<= 1) {
                s1 += __shfl_xor(s1, off, 64);
                s2 += __shfl_xor(s2, off, 64);
            }
            float m = s1 * (1.0f / 128.0f);
            float var = s2 * (1.0f / 128.0f) - m * m;
            mu[rt][reg] = m;
            rsig[rt][reg] = rsqrtf(var + 1e-5f);
        }

    // ---- LN apply + GELU ----
    #pragma unroll
    for (int nt = 0; nt < 8; ++nt) {
        float gv = ln1g[hd * 128 + 16 * nt + lc];
        float bv = ln1b[hd * 128 + 16 * nt + lc];
        #pragma unroll
        for (int rt = 0; rt < 4; ++rt)
            #pragma unroll
            for (int reg = 0; reg < 4; ++reg) {
                float v = (acc[rt][nt][reg] - mu[rt][reg]) * rsig[rt][reg] * gv + bv;
                acc[rt][nt][reg] = gelu_exact(v);
            }
    }

    // ---- GEMM2 via wave-private transpose slots in retired bufW0 (stride 36) ----
    // W2 fragments loaded per-kb (16 VGPR live, not 64 -> no spill pressure)
    unsigned short* hb = (unsigned short*)(bufW0 + w * 1152);
    f32x4 acc2[4][4];
    #pragma unroll
    for (int rt = 0; rt < 4; ++rt)
        #pragma unroll
        for (int nt2 = 0; nt2 < 4; ++nt2) acc2[rt][nt2] = (f32x4){0.f, 0.f, 0.f, 0.f};

    #pragma unroll
    for (int kb = 0; kb < 4; ++kb) {
        short8v w2f[4];
        #pragma unroll
        for (int nt2 = 0; nt2 < 4; ++nt2)
            w2f[nt2] = *(const short8v*)(W2b + hd * 16384 + kb * 4096 + nt2 * 1024 + lane * 16);
        #pragma unroll
        for (int rt = 0; rt < 4; ++rt) {
            #pragma unroll
            for (int ntl = 0; ntl < 2; ++ntl) {
                const int nt = 2 * kb + ntl;
                const int kk = 16 * ntl + lc;
                #pragma unroll
                for (int reg = 0; reg < 4; ++reg)
                    hb[(4 * lg + reg) * 36 + kk] = f2bf(acc[rt][nt][reg]);
            }
            short8v af2 = *(const short8v*)((const char*)hb + lc * 72 + 16 * lg);
            #pragma unroll
            for (int nt2 = 0; nt2 < 4; ++nt2)
                acc2[rt][nt2] = __builtin_amdgcn_mfma_f32_16x16x32_bf16(af2, w2f[nt2], acc2[rt][nt2], 0, 0, 0);
        }
    }

    // ---- + b2, norms + cosine (in-lane text rt <-> image rt+2) ----
    #pragma unroll
    for (int nt2 = 0; nt2 < 4; ++nt2) {
        float bv = b2[hd * 64 + 16 * nt2 + lc];
        #pragma unroll
        for (int rt = 0; rt < 4; ++rt)
            #pragma unroll
            for (int reg = 0; reg < 4; ++reg) acc2[rt][nt2][reg] += bv;
    }
    #pragma unroll
    for (int rt = 0; rt < 2; ++rt)
        #pragma unroll
        for (int reg = 0; reg < 4; ++reg) {
            float nt_ = 0.f, ni_ = 0.f, pr = 0.f;
            #pragma unroll
            for (int nt2 = 0; nt2 < 4; ++nt2) {
                float a = acc2[rt][nt2][reg];
                float b = acc2[rt + 2][nt2][reg];
                nt_ += a * a; ni_ += b * b; pr += a * b;
            }
            #pragma unroll
            for (int off = 1; off < 16; off <<= 1) {
                nt_ += __shfl_xor(nt_, off, 64);
                ni_ += __shfl_xor(ni_, off, 64);
                pr  += __shfl_xor(pr,  off, 64);
            }
            if (lc == 0) {
                int bl = 16 * rt + 4 * lg + reg;   // 0..31
                float denom = fmaxf(sqrtf(nt_), 1e-12f) * fmaxf(sqrtf(ni_), 1e-12f);
                out_pa[(row0 + bl) * 8 + hd] = pr / denom;
            }
        }
}

// ============== kernel G: global path -> conflict ==============
// 1024 blocks x 512 threads (8 waves). 64 batch rows/block; wave w owns cols
// 64w..64w+63 (4 nt). 32 k-chunks (kk<16 text, else image); A-slice (4KB,
// frag-linear) + gW1 chunk (32KB) double-buffered; counted-vmcnt barriers.
// Invariant: A-chunk c lives in register of parity c&1 (aregsA even, aregsB odd).
__global__ __launch_bounds__(512, 4) void global_kernel(
    const float* __restrict__ text, const float* __restrict__ image,
    const unsigned short* __restrict__ gW1T, const float* __restrict__ gb1,
    const float* __restrict__ glng, const float* __restrict__ glnb,
    const float* __restrict__ gW2, const float* __restrict__ gb2,
    const float* __restrict__ aw, const float* __restrict__ pa,
    float* __restrict__ out_conflict)
{
    __shared__ __align__(1024) char gsm[73728];   // 2 x (A 4KB | W 32KB)

    const int tid = threadIdx.x;
    const int w = tid >> 6, lane = tid & 63, lg = lane >> 4, lc = lane & 15;
    const size_t row0 = (size_t)blockIdx.x * 64;
    const char* gWb = (const char*)gW1T;

    const int r = tid >> 3, kq = tid & 7;        // staging role
    const int dA = (kq >> 1) * 1024 + r * 16 + (kq & 1) * 8;

    // ---- prologue: stage chunk 0 directly, prefetch A(1) ----
    {
        float4 v = *(const float4*)(text + (row0 + r) * 512 + 4 * kq);   // kk=0, col 0..31
        uint2 pk; pk.x = pk2(v.x, v.y); pk.y = pk2(v.z, v.w);
        *(uint2*)(gsm + dA) = pk;
        const char* src = gWb + w * 4096 + lane * 16;
        char* dst = gsm + 4096 + w * 4096;
        #pragma unroll
        for (int i = 0; i < 4; ++i) glds16(src + i * 1024, dst + i * 1024);
    }
    float4 aregsA;
    float4 aregsB = *(const float4*)(text + (row0 + r) * 512 + 32 + 4 * kq);  // A(1), parity 1
    __syncthreads();

    f32x4 acc[4][4];
    #pragma unroll
    for (int rt = 0; rt < 4; ++rt)
        #pragma unroll
        for (int nt = 0; nt < 4; ++nt) acc[rt][nt] = (f32x4){0.f, 0.f, 0.f, 0.f};

    #pragma unroll
    for (int kk = 0; kk < 32; ++kk) {
        char* curb = gsm + (kk & 1) * 36864;
        char* nxtb = gsm + ((kk & 1) ^ 1) * 36864;

        if (kk < 31) {
            // ds_write A(kk+1): parity (kk+1)&1 -> odd kk+1 in aregsB, even in aregsA
            float4 av = (kk & 1) ? aregsA : aregsB;
            uint2 pk; pk.x = pk2(av.x, av.y); pk.y = pk2(av.z, av.w);
            *(uint2*)(nxtb + dA) = pk;
            // glds gW1 chunk kk+1
            const char* src = gWb + (size_t)(kk + 1) * 32768 + w * 4096 + lane * 16;
            char* dst = nxtb + 4096 + w * 4096;
            #pragma unroll
            for (int i = 0; i < 4; ++i) glds16(src + i * 1024, dst + i * 1024);
        }
        if (kk < 30) {
            // prefetch A(kk+2) into reg parity (kk+2)&1 == kk&1
            const int c = kk + 2;
            const float* sp = ((c < 16) ? text : image) + (row0 + r) * 512 + 32 * (c & 15) + 4 * kq;
            if (kk & 1) aregsB = *(const float4*)sp; else aregsA = *(const float4*)sp;
        }

        // compute on cur
        short8v af[4];
        #pragma unroll
        for (int rt = 0; rt < 4; ++rt)
            af[rt] = *(const short8v*)(curb + lg * 1024 + (16 * rt + lc) * 16);
        const char* bb = curb + 4096 + (4 * w) * 1024 + lane * 16;
        #pragma unroll
        for (int nt = 0; nt < 4; ++nt) {
            short8v bf_ = *(const short8v*)(bb + nt * 1024);
            #pragma unroll
            for (int rt = 0; rt < 4; ++rt)
                acc[rt][nt] = __builtin_amdgcn_mfma_f32_16x16x32_bf16(af[rt], bf_, acc[rt][nt], 0, 0, 0);
        }

        if (kk < 30) {
            asm volatile("s_waitcnt vmcnt(1) lgkmcnt(0)" ::: "memory");   // glds done, A-prefetch in flight
            __builtin_amdgcn_s_barrier();
            __builtin_amdgcn_sched_barrier(0);
        } else if (kk == 30) {
            asm volatile("s_waitcnt vmcnt(0) lgkmcnt(0)" ::: "memory");
            __builtin_amdgcn_s_barrier();
            __builtin_amdgcn_sched_barrier(0);
        }
    }
    __syncthreads();   // retire buffers; stats alias below

    float* sStat = (float*)gsm;            // [8][64][2] = 4KB
    float* sDot  = (float*)(gsm + 4096);   // [8][64]    = 2KB

    // ---- + gb1, LN stat partials over wave's 64 cols ----
    #pragma unroll
    for (int nt = 0; nt < 4; ++nt) {
        float bv = gb1[64 * w + 16 * nt + lc];
        #pragma unroll
        for (int rt = 0; rt < 4; ++rt)
            #pragma unroll
            for (int reg = 0; reg < 4; ++reg) acc[rt][nt][reg] += bv;
    }
    #pragma unroll
    for (int rt = 0; rt < 4; ++rt)
        #pragma unroll
        for (int reg = 0; reg < 4; ++reg) {
            float s1 = 0.f, s2 = 0.f;
            #pragma unroll
            for (int nt = 0; nt < 4; ++nt) { float v = acc[rt][nt][reg]; s1 += v; s2 += v * v; }
            #pragma unroll
            for (int off = 1; off < 16; off <<= 1) {
                s1 += __shfl_xor(s1, off, 64);
                s2 += __shfl_xor(s2, off, 64);
            }
            if (lc == 0) {
                int rr = 16 * rt + 4 * lg + reg;
                sStat[(w * 64 + rr) * 2 + 0] = s1;
                sStat[(w * 64 + rr) * 2 + 1] = s2;
            }
        }
    __syncthreads();

    float mug[4][4], rsg[4][4];
    #pragma unroll
    for (int rt = 0; rt < 4; ++rt)
        #pragma unroll
        for (int reg = 0; reg < 4; ++reg) {
            int rr = 16 * rt + 4 * lg + reg;
            float s1 = 0.f, s2 = 0.f;
            #pragma unroll
            for (int ww = 0; ww < 8; ++ww) {
                s1 += sStat[(ww * 64 + rr) * 2 + 0];
                s2 += sStat[(ww * 64 + rr) * 2 + 1];
            }
            float m = s1 * (1.0f / 512.0f);
            float var = s2 * (1.0f / 512.0f) - m * m;
            mug[rt][reg] = m;
            rsg[rt][reg] = rsqrtf(var + 1e-5f);
        }

    // ---- LN + GELU + dot(gW2) partials ----
    float dp[4][4];
    #pragma unroll
    for (int rt = 0; rt < 4; ++rt)
        #pragma unroll
        for (int reg = 0; reg < 4; ++reg) dp[rt][reg] = 0.f;
    #pragma unroll
    for (int nt = 0; nt < 4; ++nt) {
        int col = 64 * w + 16 * nt + lc;
        float gv = glng[col], bv = glnb[col], wv = gW2[col];
        #pragma unroll
        for (int rt = 0; rt < 4; ++rt)
            #pragma unroll
            for (int reg = 0; reg < 4; ++reg) {
                float v = (acc[rt][nt][reg] - mug[rt][reg]) * rsg[rt][reg] * gv + bv;
                dp[rt][reg] += gelu_exact(v) * wv;
            }
    }
    #pragma unroll
    for (int rt = 0; rt < 4; ++rt)
        #pragma unroll
        for (int reg = 0; reg < 4; ++reg) {
            float d = dp[rt][reg];
            #pragma unroll
            for (int off = 1; off < 16; off <<= 1) d += __shfl_xor(d, off, 64);
            if (lc == 0) sDot[w * 64 + 16 * rt + 4 * lg + reg] = d;
        }
    __syncthreads();

    // ---- conflict epilogue ----
    if (tid < 64) {
        int rr = tid;
        float z = gb2[0];
        #pragma unroll
        for (int ww = 0; ww < 8; ++ww) z += sDot[ww * 64 + rr];
        float gs = 1.0f / (1.0f + expf(-z));
        float wv[8], mx = -1e30f;
        #pragma unroll
        for (int i = 0; i < 8; ++i) { wv[i] = aw[i]; mx = fmaxf(mx, wv[i]); }
        float sum = 0.f;
        #pragma unroll
        for (int i = 0; i < 8; ++i) { wv[i] = expf(wv[i] - mx); sum += wv[i]; }
        float inv = 1.0f / sum;
        const float* par = pa + (row0 + rr) * 8;
        float wsim = 0.f;
        #pragma unroll
        for (int i = 0; i < 8; ++i) wsim += par[i] * wv[i] * inv;
        float conf = 1.0f - (0.7f * wsim + 0.3f * gs);
        out_conflict[row0 + rr] = fminf(fmaxf(conf, 0.0f), 1.0f);
    }
}

extern "C" void kernel_launch(void* const* d_in, const int* in_sizes, int n_in,
                              void* d_out, int out_size, void* d_ws, size_t ws_size,
                              hipStream_t stream) {
    const float* text  = (const float*)d_in[0];
    const float* image = (const float*)d_in[1];
    const float* W1    = (const float*)d_in[2];
    const float* b1    = (const float*)d_in[3];
    const float* ln1g  = (const float*)d_in[4];
    const float* ln1b  = (const float*)d_in[5];
    const float* W2    = (const float*)d_in[6];
    const float* b2    = (const float*)d_in[7];
    const float* aw    = (const float*)d_in[8];
    const float* gW1   = (const float*)d_in[9];
    const float* gb1   = (const float*)d_in[10];
    const float* glng  = (const float*)d_in[11];
    const float* glnb  = (const float*)d_in[12];
    const float* gW2   = (const float*)d_in[13];
    const float* gb2   = (const float*)d_in[14];

    unsigned short* W1c  = (unsigned short*)d_ws;                          // 1MB
    unsigned short* W2T  = (unsigned short*)((char*)d_ws + 1048576);       // 128KB
    unsigned short* gW1T = (unsigned short*)((char*)d_ws + 1179648);       // 1MB

    float* out = (float*)d_out;
    float* out_pa = out + B_TOTAL;

    convert_weights<<<544, 256, 0, stream>>>(W1, W2, gW1, W1c, W2T, gW1T);
    head_kernel<<<2048, 512, 0, stream>>>(text, image, W1c, b1, ln1g, ln1b, W2T, b2, out_pa);
    global_kernel<<<1024, 512, 0, stream>>>(text, image, gW1T, gb1, glng, glnb, gW2, gb2,
                                            aw, out_pa, out);
}

// Round 8
// 855.944 us; speedup vs baseline: 1.8847x; 1.8847x over previous
//
#include <hip/hip_runtime.h>
#include <hip/hip_bf16.h>
#include <math.h>

#define B_TOTAL 65536

typedef __attribute__((ext_vector_type(8))) short short8v;   // 8 bf16 (4 VGPRs)
typedef __attribute__((ext_vector_type(4))) float f32x4;

__device__ __forceinline__ unsigned short f2bf(float f) {
    union { float f; unsigned u; } v; v.f = f;
    unsigned r = v.u + 0x7FFF + ((v.u >> 16) & 1);   // RNE
    return (unsigned short)(r >> 16);
}

__device__ __forceinline__ unsigned pk2(float a, float b) {
    float2 t; t.x = a; t.y = b;
    __hip_bfloat162 h = __float22bfloat162_rn(t);    // v_cvt_pk_bf16_f32
    union { __hip_bfloat162 h; unsigned u; } c; c.h = h;
    return c.u;
}

__device__ __forceinline__ float gelu_exact(float x) {
    return 0.5f * x * (1.0f + erff(x * 0.70710678118654752440f));
}

__device__ __forceinline__ void glds16(const void* g, void* l) {
    __builtin_amdgcn_global_load_lds(
        (const __attribute__((address_space(1))) unsigned int*)g,
        (__attribute__((address_space(3))) unsigned int*)l, 16, 0, 0);
}

// ============== converter: weights -> fragment-linear bf16 in ws ==============
// W1L: [hd(8)][k0(8)][kk(2)][nt(8)][lane(64)][j(8)]
//      elem j = W1[hd][k0*64+kk*32+8*(l>>4)+j][16*nt+(l&15)]
// W2T: [hd(8)][kb(4)][nt2(4)][lane][j]  elem j = W2[hd][32kb+8(l>>4)+j][16nt2+(l&15)]
// gW1T:[s(32)][nt(32)][lane][j]         elem j = gW1[32s+8(l>>4)+j][16nt+(l&15)]
__global__ void convert_weights(const float* __restrict__ W1, const float* __restrict__ W2,
                                const float* __restrict__ gW1,
                                unsigned short* __restrict__ W1L, unsigned short* __restrict__ W2T,
                                unsigned short* __restrict__ gW1T)
{
    int t = blockIdx.x * 256 + threadIdx.x;
    if (t < 65536) {
        int l = t & 63, nt = (t >> 6) & 7, kk = (t >> 9) & 1, k0 = (t >> 10) & 7, hd = t >> 13;
        int n = nt * 16 + (l & 15);
        int k = k0 * 64 + kk * 32 + 8 * (l >> 4);
        const float* s = W1 + (size_t)hd * 65536 + (size_t)k * 128 + n;
        short8v o;
        #pragma unroll
        for (int j = 0; j < 8; ++j) o[j] = (short)f2bf(s[(size_t)j * 128]);
        *(short8v*)(W1L + (size_t)t * 8) = o;
    } else if (t < 65536 + 8192) {
        int u = t - 65536;
        int l = u & 63, nt = (u >> 6) & 3, kb = (u >> 8) & 3, hd = u >> 10;
        int m = 16 * nt + (l & 15);
        int k = 32 * kb + 8 * (l >> 4);
        const float* s = W2 + (size_t)hd * 8192 + (size_t)k * 64 + m;
        short8v o;
        #pragma unroll
        for (int j = 0; j < 8; ++j) o[j] = (short)f2bf(s[(size_t)j * 64]);
        *(short8v*)(W2T + (size_t)u * 8) = o;
    } else if (t < 65536 + 8192 + 65536) {
        int u = t - 73728;
        int l = u & 63, nt = (u >> 6) & 31, s0 = u >> 11;
        int n = 16 * nt + (l & 15);
        int k = 32 * s0 + 8 * (l >> 4);
        const float* s = gW1 + (size_t)k * 512 + n;
        short8v o;
        #pragma unroll
        for (int j = 0; j < 8; ++j) o[j] = (short)f2bf(s[(size_t)j * 512]);
        *(short8v*)(gW1T + (size_t)u * 8) = o;
    }
}

// ============== kernel H: per-head path -> per_aspect ==============
// 8192 blocks x 512 threads (8 waves). bid = bblk*8 + hd; 64 batch rows/block.
// A-rows: 0..63 text, 64..127 image. GEMM1 tile 128x128 (one head), BK=64, 8 steps.
// wave (wr=w>>1, wc=w&1): 32 rows x 64 cols -> acc[2][4] (32 VGPR).
// Then: stats -> LDS, acc -> 64KB LDS o-tile (f32 swizzled, aliasing retired bufs),
// GEMM2 (LN+GELU on the fly, acc2[4]=16 VGPR), o2 -> LDS, cosine -> per_aspect.
__global__ __launch_bounds__(512, 4) void head_kernel(
    const float* __restrict__ text, const float* __restrict__ image,
    const unsigned short* __restrict__ W1L, const float* __restrict__ b1,
    const float* __restrict__ ln1g, const float* __restrict__ ln1b,
    const unsigned short* __restrict__ W2T, const float* __restrict__ b2,
    float* __restrict__ out_pa)
{
    __shared__ __align__(1024) char smem[67584];
    // bufA0 @0 (16K) | bufA1 @16384 | bufB0 @32768 (16K) | bufB1 @49152
    // oTile (64KB f32) aliases @0..65536 after K-loop; o2 (32KB) aliases @0..32768 after GEMM2
    // sStat @65536: float [2][128][2]

    const int tid = threadIdx.x;
    const int w = tid >> 6, lane = tid & 63, lg = lane >> 4, lc = lane & 15;
    const int wr = w >> 1, wc = w & 1;
    const int hd = blockIdx.x & 7;
    const size_t row0 = (size_t)(blockIdx.x >> 3) * 64;

    const char* W1base = (const char*)W1L + (size_t)hd * 131072;
    float* sS = (float*)(smem + 65536);

    // staging roles
    const int ra = tid >> 2;                 // A-row 0..127
    const int qa = tid & 3;                  // 16-k segment within 64
    const float* arow = (ra < 64) ? (text + (row0 + ra) * 512)
                                  : (image + (row0 + ra - 64) * 512);
    const int c8a = 2 * qa;                  // chunks c8a, c8a+1
    const int dstoffA0 = (c8a >> 2) * 8192 + (c8a & 3) * 2048 + ra * 16;
    const int dstoffA1 = ((c8a + 1) >> 2) * 8192 + ((c8a + 1) & 3) * 2048 + ra * 16;

    float4 fv0, fv1, fv2, fv3;
#define LOAD_FV(step_) do { \
    const float* p_ = arow + (step_) * 64 + 16 * qa; \
    fv0 = ((const float4*)p_)[0]; fv1 = ((const float4*)p_)[1]; \
    fv2 = ((const float4*)p_)[2]; fv3 = ((const float4*)p_)[3]; } while (0)

#define WRITE_A(buf_) do { \
    uint4 p0_, p1_; \
    p0_.x = pk2(fv0.x, fv0.y); p0_.y = pk2(fv0.z, fv0.w); \
    p0_.z = pk2(fv1.x, fv1.y); p0_.w = pk2(fv1.z, fv1.w); \
    p1_.x = pk2(fv2.x, fv2.y); p1_.y = pk2(fv2.z, fv2.w); \
    p1_.z = pk2(fv3.x, fv3.y); p1_.w = pk2(fv3.z, fv3.w); \
    *(uint4*)((buf_) + dstoffA0) = p0_; \
    *(uint4*)((buf_) + dstoffA1) = p1_; } while (0)

#define STAGE_B(buf_, step_) do { \
    const char* s_ = W1base + (step_) * 16384 + w * 2048 + lane * 16; \
    char* d_ = (buf_) + w * 2048; \
    glds16(s_, d_); glds16(s_ + 1024, d_ + 1024); } while (0)

    // ---- prologue ----
    LOAD_FV(0);
    STAGE_B(smem + 32768, 0);
    WRITE_A(smem);
    LOAD_FV(1);
    __syncthreads();

    f32x4 acc[2][4];
    #pragma unroll
    for (int rt = 0; rt < 2; ++rt)
        #pragma unroll
        for (int nt = 0; nt < 4; ++nt) acc[rt][nt] = (f32x4){0.f, 0.f, 0.f, 0.f};

    // ---- GEMM1 K-loop ----
    #pragma unroll
    for (int k0 = 0; k0 < 8; ++k0) {
        const int cur = k0 & 1;
        char* bufAc = smem + cur * 16384;
        char* bufBc = smem + 32768 + cur * 16384;
        if (k0 < 7) {
            char* bufAn = smem + (cur ^ 1) * 16384;
            char* bufBn = smem + 32768 + (cur ^ 1) * 16384;
            WRITE_A(bufAn);
            STAGE_B(bufBn, k0 + 1);
        }
        if (k0 < 6) LOAD_FV(k0 + 2);

        #pragma unroll
        for (int kk = 0; kk < 2; ++kk) {
            short8v afv[2];
            #pragma unroll
            for (int rt = 0; rt < 2; ++rt)
                afv[rt] = *(const short8v*)(bufAc + kk * 8192 + lg * 2048 + (32 * wr + 16 * rt + lc) * 16);
            #pragma unroll
            for (int nt = 0; nt < 4; ++nt) {
                short8v bfv = *(const short8v*)(bufBc + kk * 8192 + (4 * wc + nt) * 1024 + lane * 16);
                acc[0][nt] = __builtin_amdgcn_mfma_f32_16x16x32_bf16(afv[0], bfv, acc[0][nt], 0, 0, 0);
                acc[1][nt] = __builtin_amdgcn_mfma_f32_16x16x32_bf16(afv[1], bfv, acc[1][nt], 0, 0, 0);
            }
        }
        __syncthreads();
    }
#undef LOAD_FV
#undef WRITE_A
#undef STAGE_B

    // ---- + b1, row-stat partials, dump acc -> oTile ----
    #pragma unroll
    for (int nt = 0; nt < 4; ++nt) {
        float bv = b1[hd * 128 + 64 * wc + 16 * nt + lc];
        #pragma unroll
        for (int rt = 0; rt < 2; ++rt)
            #pragma unroll
            for (int reg = 0; reg < 4; ++reg) acc[rt][nt][reg] += bv;
    }
    #pragma unroll
    for (int rt = 0; rt < 2; ++rt)
        #pragma unroll
        for (int reg = 0; reg < 4; ++reg) {
            float s1 = 0.f, s2 = 0.f;
            #pragma unroll
            for (int nt = 0; nt < 4; ++nt) { float v = acc[rt][nt][reg]; s1 += v; s2 += v * v; }
            #pragma unroll
            for (int off = 1; off < 16; off <<= 1) {
                s1 += __shfl_xor(s1, off, 64);
                s2 += __shfl_xor(s2, off, 64);
            }
            if (lc == 0) {
                int row = 32 * wr + 16 * rt + 4 * lg + reg;
                sS[(wc * 128 + row) * 2 + 0] = s1;
                sS[(wc * 128 + row) * 2 + 1] = s2;
            }
        }
    // oTile f32 [128][128] swizzled: byte = row*512 + ((col*4) ^ ((row&7)<<4))
    #pragma unroll
    for (int rt = 0; rt < 2; ++rt)
        #pragma unroll
        for (int nt = 0; nt < 4; ++nt)
            #pragma unroll
            for (int reg = 0; reg < 4; ++reg) {
                int row = 32 * wr + 16 * rt + 4 * lg + reg;
                int col = 64 * wc + 16 * nt + lc;
                *(float*)(smem + row * 512 + ((col * 4) ^ ((row & 7) << 4))) = acc[rt][nt][reg];
            }
    __syncthreads();

    // ---- GEMM2: wave w -> rows 16w..16w+15, 64 out-cols. LN+GELU on the fly ----
    const int r2 = 16 * w + lc;
    const int sw2 = (lc & 7) << 4;
    float mu2, rsig2;
    {
        float s1 = sS[r2 * 2 + 0] + sS[(128 + r2) * 2 + 0];
        float s2 = sS[r2 * 2 + 1] + sS[(128 + r2) * 2 + 1];
        mu2 = s1 * (1.0f / 128.0f);
        float var = s2 * (1.0f / 128.0f) - mu2 * mu2;
        rsig2 = rsqrtf(var + 1e-5f);
    }
    const char* W2b = (const char*)W2T + (size_t)hd * 16384;
    f32x4 acc2[4];
    #pragma unroll
    for (int nt2 = 0; nt2 < 4; ++nt2) acc2[nt2] = (f32x4){0.f, 0.f, 0.f, 0.f};

    #pragma unroll
    for (int kb = 0; kb < 4; ++kb) {
        short8v w2f[4];
        #pragma unroll
        for (int nt2 = 0; nt2 < 4; ++nt2)
            w2f[nt2] = *(const short8v*)(W2b + kb * 4096 + nt2 * 1024 + lane * 16);
        float4 g0 = *(const float4*)(ln1g + hd * 128 + kb * 32 + 8 * lg);
        float4 g1 = *(const float4*)(ln1g + hd * 128 + kb * 32 + 8 * lg + 4);
        float4 e0 = *(const float4*)(ln1b + hd * 128 + kb * 32 + 8 * lg);
        float4 e1 = *(const float4*)(ln1b + hd * 128 + kb * 32 + 8 * lg + 4);
        float4 a0 = *(const float4*)(smem + r2 * 512 + ((kb * 128 + 32 * lg) ^ sw2));
        float4 a1 = *(const float4*)(smem + r2 * 512 + ((kb * 128 + 32 * lg + 16) ^ sw2));
        float v0 = gelu_exact((a0.x - mu2) * rsig2 * g0.x + e0.x);
        float v1 = gelu_exact((a0.y - mu2) * rsig2 * g0.y + e0.y);
        float v2 = gelu_exact((a0.z - mu2) * rsig2 * g0.z + e0.z);
        float v3 = gelu_exact((a0.w - mu2) * rsig2 * g0.w + e0.w);
        float v4 = gelu_exact((a1.x - mu2) * rsig2 * g1.x + e1.x);
        float v5 = gelu_exact((a1.y - mu2) * rsig2 * g1.y + e1.y);
        float v6 = gelu_exact((a1.z - mu2) * rsig2 * g1.z + e1.z);
        float v7 = gelu_exact((a1.w - mu2) * rsig2 * g1.w + e1.w);
        union { unsigned u[4]; short8v v; } af2;
        af2.u[0] = pk2(v0, v1); af2.u[1] = pk2(v2, v3);
        af2.u[2] = pk2(v4, v5); af2.u[3] = pk2(v6, v7);
        #pragma unroll
        for (int nt2 = 0; nt2 < 4; ++nt2)
            acc2[nt2] = __builtin_amdgcn_mfma_f32_16x16x32_bf16(af2.v, w2f[nt2], acc2[nt2], 0, 0, 0);
    }
    __syncthreads();   // all oTile reads done; o2 may alias below

    // ---- + b2, write o2 [128][64] f32 swizzled @smem[0..32K) ----
    #pragma unroll
    for (int nt2 = 0; nt2 < 4; ++nt2) {
        float bv = b2[hd * 64 + 16 * nt2 + lc];
        #pragma unroll
        for (int reg = 0; reg < 4; ++reg) {
            int row = 16 * w + 4 * lg + reg;
            int col = 16 * nt2 + lc;
            *(float*)(smem + row * 256 + ((col * 4) ^ ((row & 7) << 4))) = acc2[nt2][reg] + bv;
        }
    }
    __syncthreads();

    // ---- cosine: waves 0..3, row r = 16w+lc (text) vs r+64 (image) ----
    if (w < 4) {
        int r = 16 * w + lc;
        int sw = (r & 7) << 4;      // (r+64)&7 == r&7
        float nt_ = 0.f, ni_ = 0.f, pr = 0.f;
        #pragma unroll
        for (int q = 0; q < 4; ++q) {
            int c16 = 2 * lg + (q & 1) + (q >> 1) * 8;
            float4 a = *(const float4*)(smem + r * 256 + ((c16 * 16) ^ sw));
            float4 b = *(const float4*)(smem + (r + 64) * 256 + ((c16 * 16) ^ sw));
            nt_ += a.x * a.x + a.y * a.y + a.z * a.z + a.w * a.w;
            ni_ += b.x * b.x + b.y * b.y + b.z * b.z + b.w * b.w;
            pr  += a.x * b.x + a.y * b.y + a.z * b.z + a.w * b.w;
        }
        nt_ += __shfl_xor(nt_, 16, 64); ni_ += __shfl_xor(ni_, 16, 64); pr += __shfl_xor(pr, 16, 64);
        nt_ += __shfl_xor(nt_, 32, 64); ni_ += __shfl_xor(ni_, 32, 64); pr += __shfl_xor(pr, 32, 64);
        if (lg == 0) {
            float denom = fmaxf(sqrtf(nt_), 1e-12f) * fmaxf(sqrtf(ni_), 1e-12f);
            out_pa[(row0 + r) * 8 + hd] = pr / denom;
        }
    }
}

// ============== kernel G: global path -> conflict ==============
// 1024 blocks x 512 threads (8 waves). 64 rows x 512 cols; K=1024 (s<16 text, else image),
// BK=32, 32 steps. Wave w: cols 64w..+63, acc[4][4]. Fused LN+GELU+dot epilogue.
__global__ __launch_bounds__(512, 4) void global_kernel(
    const float* __restrict__ text, const float* __restrict__ image,
    const unsigned short* __restrict__ gW1T, const float* __restrict__ gb1,
    const float* __restrict__ glng, const float* __restrict__ glnb,
    const float* __restrict__ gW2, const float* __restrict__ gb2,
    const float* __restrict__ aw, const float* __restrict__ pa,
    float* __restrict__ out_conflict)
{
    __shared__ __align__(1024) char gsm[79872];
    // bufA0 @0 (4K) | bufA1 @4096 | bufB0 @8192 (32K) | bufB1 @40960 | sStat @73728 (4K) | sDot @77824 (2K)

    const int tid = threadIdx.x;
    const int w = tid >> 6, lane = tid & 63, lg = lane >> 4, lc = lane & 15;
    const size_t row0 = (size_t)blockIdx.x * 64;
    const char* gWb = (const char*)gW1T;
    float* sStat = (float*)(gsm + 73728);
    float* sDot  = (float*)(gsm + 77824);

    const int r = tid >> 3, c4 = tid & 7;
    const float* arow_t = text + (row0 + r) * 512 + 4 * c4;
    const float* arow_i = image + (row0 + r) * 512 + 4 * c4;
    const int dstoffA = (c4 >> 1) * 1024 + r * 16 + (c4 & 1) * 8;

    float4 fv;
#define LOAD_FV(s_) do { fv = *(const float4*)(((s_) < 16 ? arow_t + (s_) * 32 : arow_i + ((s_) - 16) * 32)); } while (0)
#define WRITE_A(buf_) do { uint2 p_; p_.x = pk2(fv.x, fv.y); p_.y = pk2(fv.z, fv.w); *(uint2*)((buf_) + dstoffA) = p_; } while (0)
#define STAGE_B(buf_, s_) do { \
    const char* s2_ = gWb + (size_t)(s_) * 32768 + w * 4096 + lane * 16; \
    char* d2_ = (buf_) + w * 4096; \
    glds16(s2_, d2_); glds16(s2_ + 1024, d2_ + 1024); \
    glds16(s2_ + 2048, d2_ + 2048); glds16(s2_ + 3072, d2_ + 3072); } while (0)

    LOAD_FV(0);
    STAGE_B(gsm + 8192, 0);
    WRITE_A(gsm);
    LOAD_FV(1);
    __syncthreads();

    f32x4 acc[4][4];
    #pragma unroll
    for (int rt = 0; rt < 4; ++rt)
        #pragma unroll
        for (int nt = 0; nt < 4; ++nt) acc[rt][nt] = (f32x4){0.f, 0.f, 0.f, 0.f};

    #pragma unroll
    for (int s = 0; s < 32; ++s) {
        const int cur = s & 1;
        char* bufAc = gsm + cur * 4096;
        char* bufBc = gsm + 8192 + cur * 32768;
        if (s < 31) {
            WRITE_A(gsm + (cur ^ 1) * 4096);
            STAGE_B(gsm + 8192 + (cur ^ 1) * 32768, s + 1);
        }
        if (s < 30) LOAD_FV(s + 2);

        short8v af[4];
        #pragma unroll
        for (int rt = 0; rt < 4; ++rt)
            af[rt] = *(const short8v*)(bufAc + lg * 1024 + (16 * rt + lc) * 16);
        #pragma unroll
        for (int nt = 0; nt < 4; ++nt) {
            short8v bfv = *(const short8v*)(bufBc + (4 * w + nt) * 1024 + lane * 16);
            #pragma unroll
            for (int rt = 0; rt < 4; ++rt)
                acc[rt][nt] = __builtin_amdgcn_mfma_f32_16x16x32_bf16(af[rt], bfv, acc[rt][nt], 0, 0, 0);
        }
        __syncthreads();
    }
#undef LOAD_FV
#undef WRITE_A
#undef STAGE_B

    // ---- + gb1, LN stat partials ----
    #pragma unroll
    for (int nt = 0; nt < 4; ++nt) {
        float bv = gb1[64 * w + 16 * nt + lc];
        #pragma unroll
        for (int rt = 0; rt < 4; ++rt)
            #pragma unroll
            for (int reg = 0; reg < 4; ++reg) acc[rt][nt][reg] += bv;
    }
    #pragma unroll
    for (int rt = 0; rt < 4; ++rt)
        #pragma unroll
        for (int reg = 0; reg < 4; ++reg) {
            float s1 = 0.f, s2 = 0.f;
            #pragma unroll
            for (int nt = 0; nt < 4; ++nt) { float v = acc[rt][nt][reg]; s1 += v; s2 += v * v; }
            #pragma unroll
            for (int off = 1; off < 16; off <<= 1) {
                s1 += __shfl_xor(s1, off, 64);
                s2 += __shfl_xor(s2, off, 64);
            }
            if (lc == 0) {
                int rr = 16 * rt + 4 * lg + reg;
                sStat[(w * 64 + rr) * 2 + 0] = s1;
                sStat[(w * 64 + rr) * 2 + 1] = s2;
            }
        }
    __syncthreads();

    float mug[4][4], rsg[4][4];
    #pragma unroll
    for (int rt = 0; rt < 4; ++rt)
        #pragma unroll
        for (int reg = 0; reg < 4; ++reg) {
            int rr = 16 * rt + 4 * lg + reg;
            float s1 = 0.f, s2 = 0.f;
            #pragma unroll
            for (int ww = 0; ww < 8; ++ww) {
                s1 += sStat[(ww * 64 + rr) * 2 + 0];
                s2 += sStat[(ww * 64 + rr) * 2 + 1];
            }
            float m = s1 * (1.0f / 512.0f);
            float var = s2 * (1.0f / 512.0f) - m * m;
            mug[rt][reg] = m;
            rsg[rt][reg] = rsqrtf(var + 1e-5f);
        }

    // ---- LN + GELU + dot(gW2) partials ----
    float dp[4][4];
    #pragma unroll
    for (int rt = 0; rt < 4; ++rt)
        #pragma unroll
        for (int reg = 0; reg < 4; ++reg) dp[rt][reg] = 0.f;
    #pragma unroll
    for (int nt = 0; nt < 4; ++nt) {
        int col = 64 * w + 16 * nt + lc;
        float gv = glng[col], bv = glnb[col], wv = gW2[col];
        #pragma unroll
        for (int rt = 0; rt < 4; ++rt)
            #pragma unroll
            for (int reg = 0; reg < 4; ++reg) {
                float v = (acc[rt][nt][reg] - mug[rt][reg]) * rsg[rt][reg] * gv + bv;
                dp[rt][reg] += gelu_exact(v) * wv;
            }
    }
    #pragma unroll
    for (int rt = 0; rt < 4; ++rt)
        #pragma unroll
        for (int reg = 0; reg < 4; ++reg) {
            float d = dp[rt][reg];
            #pragma unroll
            for (int off = 1; off < 16; off <<= 1) d += __shfl_xor(d, off, 64);
            if (lc == 0) sDot[w * 64 + 16 * rt + 4 * lg + reg] = d;
        }
    __syncthreads();

    // ---- conflict epilogue ----
    if (tid < 64) {
        int rr = tid;
        float z = gb2[0];
        #pragma unroll
        for (int ww = 0; ww < 8; ++ww) z += sDot[ww * 64 + rr];
        float gs = 1.0f / (1.0f + expf(-z));
        float wv[8], mx = -1e30f;
        #pragma unroll
        for (int i = 0; i < 8; ++i) { wv[i] = aw[i]; mx = fmaxf(mx, wv[i]); }
        float sum = 0.f;
        #pragma unroll
        for (int i = 0; i < 8; ++i) { wv[i] = expf(wv[i] - mx); sum += wv[i]; }
        float inv = 1.0f / sum;
        const float* par = pa + (row0 + rr) * 8;
        float wsim = 0.f;
        #pragma unroll
        for (int i = 0; i < 8; ++i) wsim += par[i] * wv[i] * inv;
        float conf = 1.0f - (0.7f * wsim + 0.3f * gs);
        out_conflict[row0 + rr] = fminf(fmaxf(conf, 0.0f), 1.0f);
    }
}

extern "C" void kernel_launch(void* const* d_in, const int* in_sizes, int n_in,
                              void* d_out, int out_size, void* d_ws, size_t ws_size,
                              hipStream_t stream) {
    const float* text  = (const float*)d_in[0];
    const float* image = (const float*)d_in[1];
    const float* W1    = (const float*)d_in[2];
    const float* b1    = (const float*)d_in[3];
    const float* ln1g  = (const float*)d_in[4];
    const float* ln1b  = (const float*)d_in[5];
    const float* W2    = (const float*)d_in[6];
    const float* b2    = (const float*)d_in[7];
    const float* aw    = (const float*)d_in[8];
    const float* gW1   = (const float*)d_in[9];
    const float* gb1   = (const float*)d_in[10];
    const float* glng  = (const float*)d_in[11];
    const float* glnb  = (const float*)d_in[12];
    const float* gW2   = (const float*)d_in[13];
    const float* gb2   = (const float*)d_in[14];

    unsigned short* W1L  = (unsigned short*)d_ws;                          // 1MB
    unsigned short* W2T  = (unsigned short*)((char*)d_ws + 1048576);       // 128KB
    unsigned short* gW1T = (unsigned short*)((char*)d_ws + 1179648);       // 1MB

    float* out = (float*)d_out;
    float* out_pa = out + B_TOTAL;

    convert_weights<<<544, 256, 0, stream>>>(W1, W2, gW1, W1L, W2T, gW1T);
    head_kernel<<<8192, 512, 0, stream>>>(text, image, W1L, b1, ln1g, ln1b, W2T, b2, out_pa);
    global_kernel<<<1024, 512, 0, stream>>>(text, image, gW1T, gb1, glng, glnb, gW2, gb2,
                                            aw, out_pa, out);
}

// Round 9
// 819.673 us; speedup vs baseline: 1.9681x; 1.0443x over previous
//
#include <hip/hip_runtime.h>
#include <hip/hip_bf16.h>
#include <math.h>

#define B_TOTAL 65536

typedef __attribute__((ext_vector_type(8))) short short8v;   // 8 bf16 (4 VGPRs)
typedef __attribute__((ext_vector_type(4))) float f32x4;

__device__ __forceinline__ unsigned short f2bf(float f) {
    union { float f; unsigned u; } v; v.f = f;
    unsigned r = v.u + 0x7FFF + ((v.u >> 16) & 1);   // RNE
    return (unsigned short)(r >> 16);
}

__device__ __forceinline__ unsigned pk2(float a, float b) {
    float2 t; t.x = a; t.y = b;
    __hip_bfloat162 h = __float22bfloat162_rn(t);    // v_cvt_pk_bf16_f32
    union { __hip_bfloat162 h; unsigned u; } c; c.h = h;
    return c.u;
}

__device__ __forceinline__ float gelu_exact(float x) {
    return 0.5f * x * (1.0f + erff(x * 0.70710678118654752440f));
}

__device__ __forceinline__ void glds16(const void* g, void* l) {
    __builtin_amdgcn_global_load_lds(
        (const __attribute__((address_space(1))) unsigned int*)g,
        (__attribute__((address_space(3))) unsigned int*)l, 16, 0, 0);
}

// ============== converter: weights -> fragment-linear bf16 in ws ==============
// W1L: [hd(8)][k0(8)][kk(2)][nt(8)][lane(64)][j(8)]
//      elem j = W1[hd][k0*64+kk*32+8*(l>>4)+j][16*nt+(l&15)]
// W2T: [hd(8)][kb(4)][nt2(4)][lane][j]  elem j = W2[hd][32kb+8(l>>4)+j][16nt2+(l&15)]
// gW1T:[s(32)][nt(32)][lane][j]         elem j = gW1[32s+8(l>>4)+j][16nt+(l&15)]
__global__ void convert_weights(const float* __restrict__ W1, const float* __restrict__ W2,
                                const float* __restrict__ gW1,
                                unsigned short* __restrict__ W1L, unsigned short* __restrict__ W2T,
                                unsigned short* __restrict__ gW1T)
{
    int t = blockIdx.x * 256 + threadIdx.x;
    if (t < 65536) {
        int l = t & 63, nt = (t >> 6) & 7, kk = (t >> 9) & 1, k0 = (t >> 10) & 7, hd = t >> 13;
        int n = nt * 16 + (l & 15);
        int k = k0 * 64 + kk * 32 + 8 * (l >> 4);
        const float* s = W1 + (size_t)hd * 65536 + (size_t)k * 128 + n;
        short8v o;
        #pragma unroll
        for (int j = 0; j < 8; ++j) o[j] = (short)f2bf(s[(size_t)j * 128]);
        *(short8v*)(W1L + (size_t)t * 8) = o;
    } else if (t < 65536 + 8192) {
        int u = t - 65536;
        int l = u & 63, nt = (u >> 6) & 3, kb = (u >> 8) & 3, hd = u >> 10;
        int m = 16 * nt + (l & 15);
        int k = 32 * kb + 8 * (l >> 4);
        const float* s = W2 + (size_t)hd * 8192 + (size_t)k * 64 + m;
        short8v o;
        #pragma unroll
        for (int j = 0; j < 8; ++j) o[j] = (short)f2bf(s[(size_t)j * 64]);
        *(short8v*)(W2T + (size_t)u * 8) = o;
    } else if (t < 65536 + 8192 + 65536) {
        int u = t - 73728;
        int l = u & 63, nt = (u >> 6) & 31, s0 = u >> 11;
        int n = 16 * nt + (l & 15);
        int k = 32 * s0 + 8 * (l >> 4);
        const float* s = gW1 + (size_t)k * 512 + n;
        short8v o;
        #pragma unroll
        for (int j = 0; j < 8; ++j) o[j] = (short)f2bf(s[(size_t)j * 512]);
        *(short8v*)(gW1T + (size_t)u * 8) = o;
    }
}

// ============== kernel H: per-head path -> per_aspect ==============
// 8192 blocks x 512 threads (8 waves). XCD swizzle: xr=bid&7 (XCD), q=bid>>3,
// hd=q&7, bblk=((q>>3)<<3)|xr -> all 8 head-blocks of a rowblock share an XCD's L2.
// 64 batch rows/block; A-rows 0..63 text, 64..127 image. GEMM1 tile 128x128, BK=64.
// A-tile layout: [kk(2)][lg(4)][row(128)][16B], byte ^= (lg<<4) ^ (kk<<6) (bank swizzle).
__global__ __launch_bounds__(512, 4) void head_kernel(
    const float* __restrict__ text, const float* __restrict__ image,
    const unsigned short* __restrict__ W1L, const float* __restrict__ b1,
    const float* __restrict__ ln1g, const float* __restrict__ ln1b,
    const unsigned short* __restrict__ W2T, const float* __restrict__ b2,
    float* __restrict__ out_pa)
{
    __shared__ __align__(1024) char smem[67584];
    // bufA0 @0 (16K) | bufA1 @16384 | bufB0 @32768 (16K) | bufB1 @49152
    // oTile (64KB f32) aliases @0..65536 after K-loop; o2 (32KB) aliases @0..32768 after GEMM2
    // sStat @65536: float [2][128][2]

    const int tid = threadIdx.x;
    const int w = tid >> 6, lane = tid & 63, lg = lane >> 4, lc = lane & 15;
    const int wr = w >> 1, wc = w & 1;
    const int bid = blockIdx.x;
    const int xr = bid & 7;
    const int q = bid >> 3;
    const int hd = q & 7;
    const size_t row0 = (size_t)(((q >> 3) << 3) | xr) * 64;

    const char* W1base = (const char*)W1L + (size_t)hd * 131072;
    float* sS = (float*)(smem + 65536);

    // staging roles
    const int ra = tid >> 2;                 // A-row 0..127
    const int qa = tid & 3;                  // 16-k segment within 64
    const float* arow = (ra < 64) ? (text + (row0 + ra) * 512)
                                  : (image + (row0 + ra - 64) * 512);
    const int kkA = qa >> 1;                 // c8a>>2
    const int lgA0 = (2 * qa) & 3;           // even
    const int lgA1 = lgA0 + 1;
    const int dstoffA0 = kkA * 8192 + lgA0 * 2048 + ((ra * 16) ^ (lgA0 << 4) ^ (kkA << 6));
    const int dstoffA1 = kkA * 8192 + lgA1 * 2048 + ((ra * 16) ^ (lgA1 << 4) ^ (kkA << 6));

    float4 fv0, fv1, fv2, fv3;
#define LOAD_FV(step_) do { \
    const float* p_ = arow + (step_) * 64 + 16 * qa; \
    fv0 = ((const float4*)p_)[0]; fv1 = ((const float4*)p_)[1]; \
    fv2 = ((const float4*)p_)[2]; fv3 = ((const float4*)p_)[3]; } while (0)

#define WRITE_A(buf_) do { \
    uint4 p0_, p1_; \
    p0_.x = pk2(fv0.x, fv0.y); p0_.y = pk2(fv0.z, fv0.w); \
    p0_.z = pk2(fv1.x, fv1.y); p0_.w = pk2(fv1.z, fv1.w); \
    p1_.x = pk2(fv2.x, fv2.y); p1_.y = pk2(fv2.z, fv2.w); \
    p1_.z = pk2(fv3.x, fv3.y); p1_.w = pk2(fv3.z, fv3.w); \
    *(uint4*)((buf_) + dstoffA0) = p0_; \
    *(uint4*)((buf_) + dstoffA1) = p1_; } while (0)

#define STAGE_B(buf_, step_) do { \
    const char* s_ = W1base + (step_) * 16384 + w * 2048 + lane * 16; \
    char* d_ = (buf_) + w * 2048; \
    glds16(s_, d_); glds16(s_ + 1024, d_ + 1024); } while (0)

    // ---- prologue ----
    LOAD_FV(0);
    STAGE_B(smem + 32768, 0);
    WRITE_A(smem);
    LOAD_FV(1);
    __syncthreads();

    f32x4 acc[2][4];
    #pragma unroll
    for (int rt = 0; rt < 2; ++rt)
        #pragma unroll
        for (int nt = 0; nt < 4; ++nt) acc[rt][nt] = (f32x4){0.f, 0.f, 0.f, 0.f};

    // ---- GEMM1 K-loop ----
    #pragma unroll
    for (int k0 = 0; k0 < 8; ++k0) {
        const int cur = k0 & 1;
        char* bufAc = smem + cur * 16384;
        char* bufBc = smem + 32768 + cur * 16384;
        if (k0 < 7) {
            char* bufAn = smem + (cur ^ 1) * 16384;
            char* bufBn = smem + 32768 + (cur ^ 1) * 16384;
            WRITE_A(bufAn);
            STAGE_B(bufBn, k0 + 1);
        }
        if (k0 < 6) LOAD_FV(k0 + 2);

        #pragma unroll
        for (int kk = 0; kk < 2; ++kk) {
            short8v afv[2];
            #pragma unroll
            for (int rt = 0; rt < 2; ++rt) {
                const int row = 32 * wr + 16 * rt + lc;
                afv[rt] = *(const short8v*)(bufAc + kk * 8192 + lg * 2048
                                            + ((row * 16) ^ (lg << 4) ^ (kk << 6)));
            }
            #pragma unroll
            for (int nt = 0; nt < 4; ++nt) {
                short8v bfv = *(const short8v*)(bufBc + kk * 8192 + (4 * wc + nt) * 1024 + lane * 16);
                acc[0][nt] = __builtin_amdgcn_mfma_f32_16x16x32_bf16(afv[0], bfv, acc[0][nt], 0, 0, 0);
                acc[1][nt] = __builtin_amdgcn_mfma_f32_16x16x32_bf16(afv[1], bfv, acc[1][nt], 0, 0, 0);
            }
        }
        __syncthreads();
    }
#undef LOAD_FV
#undef WRITE_A
#undef STAGE_B

    // ---- + b1, row-stat partials, dump acc -> oTile ----
    #pragma unroll
    for (int nt = 0; nt < 4; ++nt) {
        float bv = b1[hd * 128 + 64 * wc + 16 * nt + lc];
        #pragma unroll
        for (int rt = 0; rt < 2; ++rt)
            #pragma unroll
            for (int reg = 0; reg < 4; ++reg) acc[rt][nt][reg] += bv;
    }
    #pragma unroll
    for (int rt = 0; rt < 2; ++rt)
        #pragma unroll
        for (int reg = 0; reg < 4; ++reg) {
            float s1 = 0.f, s2 = 0.f;
            #pragma unroll
            for (int nt = 0; nt < 4; ++nt) { float v = acc[rt][nt][reg]; s1 += v; s2 += v * v; }
            #pragma unroll
            for (int off = 1; off < 16; off <<= 1) {
                s1 += __shfl_xor(s1, off, 64);
                s2 += __shfl_xor(s2, off, 64);
            }
            if (lc == 0) {
                int row = 32 * wr + 16 * rt + 4 * lg + reg;
                sS[(wc * 128 + row) * 2 + 0] = s1;
                sS[(wc * 128 + row) * 2 + 1] = s2;
            }
        }
    // oTile f32 [128][128] swizzled: byte = row*512 + ((col*4) ^ ((row&7)<<4))
    #pragma unroll
    for (int rt = 0; rt < 2; ++rt)
        #pragma unroll
        for (int nt = 0; nt < 4; ++nt)
            #pragma unroll
            for (int reg = 0; reg < 4; ++reg) {
                int row = 32 * wr + 16 * rt + 4 * lg + reg;
                int col = 64 * wc + 16 * nt + lc;
                *(float*)(smem + row * 512 + ((col * 4) ^ ((row & 7) << 4))) = acc[rt][nt][reg];
            }
    __syncthreads();

    // ---- GEMM2: wave w -> rows 16w..16w+15, 64 out-cols. LN+GELU on the fly ----
    const int r2 = 16 * w + lc;
    const int sw2 = (lc & 7) << 4;
    float mu2, rsig2;
    {
        float s1 = sS[r2 * 2 + 0] + sS[(128 + r2) * 2 + 0];
        float s2 = sS[r2 * 2 + 1] + sS[(128 + r2) * 2 + 1];
        mu2 = s1 * (1.0f / 128.0f);
        float var = s2 * (1.0f / 128.0f) - mu2 * mu2;
        rsig2 = rsqrtf(var + 1e-5f);
    }
    const char* W2b = (const char*)W2T + (size_t)hd * 16384;
    f32x4 acc2[4];
    #pragma unroll
    for (int nt2 = 0; nt2 < 4; ++nt2) acc2[nt2] = (f32x4){0.f, 0.f, 0.f, 0.f};

    #pragma unroll
    for (int kb = 0; kb < 4; ++kb) {
        short8v w2f[4];
        #pragma unroll
        for (int nt2 = 0; nt2 < 4; ++nt2)
            w2f[nt2] = *(const short8v*)(W2b + kb * 4096 + nt2 * 1024 + lane * 16);
        float4 g0 = *(const float4*)(ln1g + hd * 128 + kb * 32 + 8 * lg);
        float4 g1 = *(const float4*)(ln1g + hd * 128 + kb * 32 + 8 * lg + 4);
        float4 e0 = *(const float4*)(ln1b + hd * 128 + kb * 32 + 8 * lg);
        float4 e1 = *(const float4*)(ln1b + hd * 128 + kb * 32 + 8 * lg + 4);
        float4 a0 = *(const float4*)(smem + r2 * 512 + ((kb * 128 + 32 * lg) ^ sw2));
        float4 a1 = *(const float4*)(smem + r2 * 512 + ((kb * 128 + 32 * lg + 16) ^ sw2));
        float v0 = gelu_exact((a0.x - mu2) * rsig2 * g0.x + e0.x);
        float v1 = gelu_exact((a0.y - mu2) * rsig2 * g0.y + e0.y);
        float v2 = gelu_exact((a0.z - mu2) * rsig2 * g0.z + e0.z);
        float v3 = gelu_exact((a0.w - mu2) * rsig2 * g0.w + e0.w);
        float v4 = gelu_exact((a1.x - mu2) * rsig2 * g1.x + e1.x);
        float v5 = gelu_exact((a1.y - mu2) * rsig2 * g1.y + e1.y);
        float v6 = gelu_exact((a1.z - mu2) * rsig2 * g1.z + e1.z);
        float v7 = gelu_exact((a1.w - mu2) * rsig2 * g1.w + e1.w);
        union { unsigned u[4]; short8v v; } af2;
        af2.u[0] = pk2(v0, v1); af2.u[1] = pk2(v2, v3);
        af2.u[2] = pk2(v4, v5); af2.u[3] = pk2(v6, v7);
        #pragma unroll
        for (int nt2 = 0; nt2 < 4; ++nt2)
            acc2[nt2] = __builtin_amdgcn_mfma_f32_16x16x32_bf16(af2.v, w2f[nt2], acc2[nt2], 0, 0, 0);
    }
    __syncthreads();   // all oTile reads done; o2 may alias below

    // ---- + b2, write o2 [128][64] f32 swizzled @smem[0..32K) ----
    #pragma unroll
    for (int nt2 = 0; nt2 < 4; ++nt2) {
        float bv = b2[hd * 64 + 16 * nt2 + lc];
        #pragma unroll
        for (int reg = 0; reg < 4; ++reg) {
            int row = 16 * w + 4 * lg + reg;
            int col = 16 * nt2 + lc;
            *(float*)(smem + row * 256 + ((col * 4) ^ ((row & 7) << 4))) = acc2[nt2][reg] + bv;
        }
    }
    __syncthreads();

    // ---- cosine: waves 0..3, row r = 16w+lc (text) vs r+64 (image) ----
    if (w < 4) {
        int r = 16 * w + lc;
        int sw = (r & 7) << 4;      // (r+64)&7 == r&7
        float nt_ = 0.f, ni_ = 0.f, pr = 0.f;
        #pragma unroll
        for (int q2 = 0; q2 < 4; ++q2) {
            int c16 = 2 * lg + (q2 & 1) + (q2 >> 1) * 8;
            float4 a = *(const float4*)(smem + r * 256 + ((c16 * 16) ^ sw));
            float4 b = *(const float4*)(smem + (r + 64) * 256 + ((c16 * 16) ^ sw));
            nt_ += a.x * a.x + a.y * a.y + a.z * a.z + a.w * a.w;
            ni_ += b.x * b.x + b.y * b.y + b.z * b.z + b.w * b.w;
            pr  += a.x * b.x + a.y * b.y + a.z * b.z + a.w * b.w;
        }
        nt_ += __shfl_xor(nt_, 16, 64); ni_ += __shfl_xor(ni_, 16, 64); pr += __shfl_xor(pr, 16, 64);
        nt_ += __shfl_xor(nt_, 32, 64); ni_ += __shfl_xor(ni_, 32, 64); pr += __shfl_xor(pr, 32, 64);
        if (lg == 0) {
            float denom = fmaxf(sqrtf(nt_), 1e-12f) * fmaxf(sqrtf(ni_), 1e-12f);
            out_pa[(row0 + r) * 8 + hd] = pr / denom;
        }
    }
}

// ============== kernel G: global path -> conflict ==============
// 1024 blocks x 512 threads (8 waves). 64 rows x 512 cols; K=1024 (s<16 text, else image),
// BK=32, 32 steps. Wave w: cols 64w..+63, acc[4][4]. Fused LN+GELU+dot epilogue.
__global__ __launch_bounds__(512, 4) void global_kernel(
    const float* __restrict__ text, const float* __restrict__ image,
    const unsigned short* __restrict__ gW1T, const float* __restrict__ gb1,
    const float* __restrict__ glng, const float* __restrict__ glnb,
    const float* __restrict__ gW2, const float* __restrict__ gb2,
    const float* __restrict__ aw, const float* __restrict__ pa,
    float* __restrict__ out_conflict)
{
    __shared__ __align__(1024) char gsm[79872];
    // bufA0 @0 (4K) | bufA1 @4096 | bufB0 @8192 (32K) | bufB1 @40960 | sStat @73728 (4K) | sDot @77824 (2K)

    const int tid = threadIdx.x;
    const int w = tid >> 6, lane = tid & 63, lg = lane >> 4, lc = lane & 15;
    const size_t row0 = (size_t)blockIdx.x * 64;
    const char* gWb = (const char*)gW1T;
    float* sStat = (float*)(gsm + 73728);
    float* sDot  = (float*)(gsm + 77824);

    const int r = tid >> 3, c4 = tid & 7;
    const float* arow_t = text + (row0 + r) * 512 + 4 * c4;
    const float* arow_i = image + (row0 + r) * 512 + 4 * c4;
    const int dstoffA = (c4 >> 1) * 1024 + r * 16 + (c4 & 1) * 8;

    float4 fv;
#define LOAD_FV(s_) do { fv = *(const float4*)(((s_) < 16 ? arow_t + (s_) * 32 : arow_i + ((s_) - 16) * 32)); } while (0)
#define WRITE_A(buf_) do { uint2 p_; p_.x = pk2(fv.x, fv.y); p_.y = pk2(fv.z, fv.w); *(uint2*)((buf_) + dstoffA) = p_; } while (0)
#define STAGE_B(buf_, s_) do { \
    const char* s2_ = gWb + (size_t)(s_) * 32768 + w * 4096 + lane * 16; \
    char* d2_ = (buf_) + w * 4096; \
    glds16(s2_, d2_); glds16(s2_ + 1024, d2_ + 1024); \
    glds16(s2_ + 2048, d2_ + 2048); glds16(s2_ + 3072, d2_ + 3072); } while (0)

    LOAD_FV(0);
    STAGE_B(gsm + 8192, 0);
    WRITE_A(gsm);
    LOAD_FV(1);
    __syncthreads();

    f32x4 acc[4][4];
    #pragma unroll
    for (int rt = 0; rt < 4; ++rt)
        #pragma unroll
        for (int nt = 0; nt < 4; ++nt) acc[rt][nt] = (f32x4){0.f, 0.f, 0.f, 0.f};

    #pragma unroll
    for (int s = 0; s < 32; ++s) {
        const int cur = s & 1;
        char* bufAc = gsm + cur * 4096;
        char* bufBc = gsm + 8192 + cur * 32768;
        if (s < 31) {
            WRITE_A(gsm + (cur ^ 1) * 4096);
            STAGE_B(gsm + 8192 + (cur ^ 1) * 32768, s + 1);
        }
        if (s < 30) LOAD_FV(s + 2);

        short8v af[4];
        #pragma unroll
        for (int rt = 0; rt < 4; ++rt)
            af[rt] = *(const short8v*)(bufAc + lg * 1024 + (16 * rt + lc) * 16);
        #pragma unroll
        for (int nt = 0; nt < 4; ++nt) {
            short8v bfv = *(const short8v*)(bufBc + (4 * w + nt) * 1024 + lane * 16);
            #pragma unroll
            for (int rt = 0; rt < 4; ++rt)
                acc[rt][nt] = __builtin_amdgcn_mfma_f32_16x16x32_bf16(af[rt], bfv, acc[rt][nt], 0, 0, 0);
        }
        __syncthreads();
    }
#undef LOAD_FV
#undef WRITE_A
#undef STAGE_B

    // ---- + gb1, LN stat partials ----
    #pragma unroll
    for (int nt = 0; nt < 4; ++nt) {
        float bv = gb1[64 * w + 16 * nt + lc];
        #pragma unroll
        for (int rt = 0; rt < 4; ++rt)
            #pragma unroll
            for (int reg = 0; reg < 4; ++reg) acc[rt][nt][reg] += bv;
    }
    #pragma unroll
    for (int rt = 0; rt < 4; ++rt)
        #pragma unroll
        for (int reg = 0; reg < 4; ++reg) {
            float s1 = 0.f, s2 = 0.f;
            #pragma unroll
            for (int nt = 0; nt < 4; ++nt) { float v = acc[rt][nt][reg]; s1 += v; s2 += v * v; }
            #pragma unroll
            for (int off = 1; off < 16; off <<= 1) {
                s1 += __shfl_xor(s1, off, 64);
                s2 += __shfl_xor(s2, off, 64);
            }
            if (lc == 0) {
                int rr = 16 * rt + 4 * lg + reg;
                sStat[(w * 64 + rr) * 2 + 0] = s1;
                sStat[(w * 64 + rr) * 2 + 1] = s2;
            }
        }
    __syncthreads();

    float mug[4][4], rsg[4][4];
    #pragma unroll
    for (int rt = 0; rt < 4; ++rt)
        #pragma unroll
        for (int reg = 0; reg < 4; ++reg) {
            int rr = 16 * rt + 4 * lg + reg;
            float s1 = 0.f, s2 = 0.f;
            #pragma unroll
            for (int ww = 0; ww < 8; ++ww) {
                s1 += sStat[(ww * 64 + rr) * 2 + 0];
                s2 += sStat[(ww * 64 + rr) * 2 + 1];
            }
            float m = s1 * (1.0f / 512.0f);
            float var = s2 * (1.0f / 512.0f) - m * m;
            mug[rt][reg] = m;
            rsg[rt][reg] = rsqrtf(var + 1e-5f);
        }

    // ---- LN + GELU + dot(gW2) partials ----
    float dp[4][4];
    #pragma unroll
    for (int rt = 0; rt < 4; ++rt)
        #pragma unroll
        for (int reg = 0; reg < 4; ++reg) dp[rt][reg] = 0.f;
    #pragma unroll
    for (int nt = 0; nt < 4; ++nt) {
        int col = 64 * w + 16 * nt + lc;
        float gv = glng[col], bv = glnb[col], wv = gW2[col];
        #pragma unroll
        for (int rt = 0; rt < 4; ++rt)
            #pragma unroll
            for (int reg = 0; reg < 4; ++reg) {
                float v = (acc[rt][nt][reg] - mug[rt][reg]) * rsg[rt][reg] * gv + bv;
                dp[rt][reg] += gelu_exact(v) * wv;
            }
    }
    #pragma unroll
    for (int rt = 0; rt < 4; ++rt)
        #pragma unroll
        for (int reg = 0; reg < 4; ++reg) {
            float d = dp[rt][reg];
            #pragma unroll
            for (int off = 1; off < 16; off <<= 1) d += __shfl_xor(d, off, 64);
            if (lc == 0) sDot[w * 64 + 16 * rt + 4 * lg + reg] = d;
        }
    __syncthreads();

    // ---- conflict epilogue ----
    if (tid < 64) {
        int rr = tid;
        float z = gb2[0];
        #pragma unroll
        for (int ww = 0; ww < 8; ++ww) z += sDot[ww * 64 + rr];
        float gs = 1.0f / (1.0f + expf(-z));
        float wv[8], mx = -1e30f;
        #pragma unroll
        for (int i = 0; i < 8; ++i) { wv[i] = aw[i]; mx = fmaxf(mx, wv[i]); }
        float sum = 0.f;
        #pragma unroll
        for (int i = 0; i < 8; ++i) { wv[i] = expf(wv[i] - mx); sum += wv[i]; }
        float inv = 1.0f / sum;
        const float* par = pa + (row0 + rr) * 8;
        float wsim = 0.f;
        #pragma unroll
        for (int i = 0; i < 8; ++i) wsim += par[i] * wv[i] * inv;
        float conf = 1.0f - (0.7f * wsim + 0.3f * gs);
        out_conflict[row0 + rr] = fminf(fmaxf(conf, 0.0f), 1.0f);
    }
}

extern "C" void kernel_launch(void* const* d_in, const int* in_sizes, int n_in,
                              void* d_out, int out_size, void* d_ws, size_t ws_size,
                              hipStream_t stream) {
    const float* text  = (const float*)d_in[0];
    const float* image = (const float*)d_in[1];
    const float* W1    = (const float*)d_in[2];
    const float* b1    = (const float*)d_in[3];
    const float* ln1g  = (const float*)d_in[4];
    const float* ln1b  = (const float*)d_in[5];
    const float* W2    = (const float*)d_in[6];
    const float* b2    = (const float*)d_in[7];
    const float* aw    = (const float*)d_in[8];
    const float* gW1   = (const float*)d_in[9];
    const float* gb1   = (const float*)d_in[10];
    const float* glng  = (const float*)d_in[11];
    const float* glnb  = (const float*)d_in[12];
    const float* gW2   = (const float*)d_in[13];
    const float* gb2   = (const float*)d_in[14];

    unsigned short* W1L  = (unsigned short*)d_ws;                          // 1MB
    unsigned short* W2T  = (unsigned short*)((char*)d_ws + 1048576);       // 128KB
    unsigned short* gW1T = (unsigned short*)((char*)d_ws + 1179648);       // 1MB

    float* out = (float*)d_out;
    float* out_pa = out + B_TOTAL;

    convert_weights<<<544, 256, 0, stream>>>(W1, W2, gW1, W1L, W2T, gW1T);
    head_kernel<<<8192, 512, 0, stream>>>(text, image, W1L, b1, ln1g, ln1b, W2T, b2, out_pa);
    global_kernel<<<1024, 512, 0, stream>>>(text, image, gW1T, gb1, glng, glnb, gW2, gb2,
                                            aw, out_pa, out);
}

// Round 10
// 793.943 us; speedup vs baseline: 2.0319x; 1.0324x over previous
//
#include <hip/hip_runtime.h>
#include <hip/hip_bf16.h>
#include <math.h>

#define B_TOTAL 65536

typedef __attribute__((ext_vector_type(8))) short short8v;   // 8 bf16 (4 VGPRs)
typedef __attribute__((ext_vector_type(4))) float f32x4;

__device__ __forceinline__ unsigned short f2bf(float f) {
    union { float f; unsigned u; } v; v.f = f;
    unsigned r = v.u + 0x7FFF + ((v.u >> 16) & 1);   // RNE
    return (unsigned short)(r >> 16);
}

__device__ __forceinline__ unsigned pk2(float a, float b) {
    float2 t; t.x = a; t.y = b;
    __hip_bfloat162 h = __float22bfloat162_rn(t);    // v_cvt_pk_bf16_f32
    union { __hip_bfloat162 h; unsigned u; } c; c.h = h;
    return c.u;
}

// Abramowitz-Stegun 7.1.26: |erf - approx| <= 1.5e-7, branch-free
__device__ __forceinline__ float erf_fast(float x) {
    float ax = fabsf(x);
    float t = 1.0f / (1.0f + 0.3275911f * ax);
    float y = t * (0.254829592f + t * (-0.284496736f + t * (1.421413741f
              + t * (-1.453152027f + t * 1.061405429f))));
    float r = 1.0f - y * __expf(-ax * ax);
    return copysignf(r, x);
}

__device__ __forceinline__ float gelu_exact(float x) {
    return 0.5f * x * (1.0f + erf_fast(x * 0.70710678118654752440f));
}

__device__ __forceinline__ void glds16(const void* g, void* l) {
    __builtin_amdgcn_global_load_lds(
        (const __attribute__((address_space(1))) unsigned int*)g,
        (__attribute__((address_space(3))) unsigned int*)l, 16, 0, 0);
}

// ============== converter: weights -> fragment-linear bf16 in ws ==============
// W1L: [hd(8)][step(16)][nt(8)][lane(64)][j(8)]
//      elem j = W1[hd][step*32+8*(l>>4)+j][16*nt+(l&15)]         (8KB per step)
// W2T: [hd(8)][kb(4)][nt2(4)][lane][j]  elem j = W2[hd][32kb+8(l>>4)+j][16nt2+(l&15)]
// gW1T:[s(32)][nt(32)][lane][j]         elem j = gW1[32s+8(l>>4)+j][16nt+(l&15)]
__global__ void convert_weights(const float* __restrict__ W1, const float* __restrict__ W2,
                                const float* __restrict__ gW1,
                                unsigned short* __restrict__ W1L, unsigned short* __restrict__ W2T,
                                unsigned short* __restrict__ gW1T)
{
    int t = blockIdx.x * 256 + threadIdx.x;
    if (t < 65536) {
        int l = t & 63, nt = (t >> 6) & 7, step = (t >> 9) & 15, hd = t >> 13;
        int n = nt * 16 + (l & 15);
        int k = step * 32 + 8 * (l >> 4);
        const float* s = W1 + (size_t)hd * 65536 + (size_t)k * 128 + n;
        short8v o;
        #pragma unroll
        for (int j = 0; j < 8; ++j) o[j] = (short)f2bf(s[(size_t)j * 128]);
        *(short8v*)(W1L + (size_t)t * 8) = o;
    } else if (t < 65536 + 8192) {
        int u = t - 65536;
        int l = u & 63, nt = (u >> 6) & 3, kb = (u >> 8) & 3, hd = u >> 10;
        int m = 16 * nt + (l & 15);
        int k = 32 * kb + 8 * (l >> 4);
        const float* s = W2 + (size_t)hd * 8192 + (size_t)k * 64 + m;
        short8v o;
        #pragma unroll
        for (int j = 0; j < 8; ++j) o[j] = (short)f2bf(s[(size_t)j * 64]);
        *(short8v*)(W2T + (size_t)u * 8) = o;
    } else if (t < 65536 + 8192 + 65536) {
        int u = t - 73728;
        int l = u & 63, nt = (u >> 6) & 31, s0 = u >> 11;
        int n = 16 * nt + (l & 15);
        int k = 32 * s0 + 8 * (l >> 4);
        const float* s = gW1 + (size_t)k * 512 + n;
        short8v o;
        #pragma unroll
        for (int j = 0; j < 8; ++j) o[j] = (short)f2bf(s[(size_t)j * 512]);
        *(short8v*)(gW1T + (size_t)u * 8) = o;
    }
}

// ============== kernel H: per-head path -> per_aspect ==============
// 8192 blocks x 512 threads (8 waves), 3 blocks/CU (LDS 43KB). XCD swizzle:
// xr=bid&7, q=bid>>3, hd=q&7, rowblock=((q>>3)<<3)|xr. 64 batch rows/block
// (A-rows 0..63 text, 64..127 image). GEMM1 128x128, BK=32 dbuf, 16 steps.
// Wave (wr=w>>1, wc=w&1): rows 32wr..+32, cols 64wc..+64, acc[2][4].
// Epilogue: LN+GELU in-register; per-wave half-K GEMM2 through 1.2KB transpose
// scratch; o2 [128][64] f32 combined via 2-pass LDS add (aliases K-loop bufs).
__global__ __launch_bounds__(512, 6) void head_kernel(
    const float* __restrict__ text, const float* __restrict__ image,
    const unsigned short* __restrict__ W1L, const float* __restrict__ b1,
    const float* __restrict__ ln1g, const float* __restrict__ ln1b,
    const unsigned short* __restrict__ W2T, const float* __restrict__ b2,
    float* __restrict__ out_pa)
{
    __shared__ __align__(1024) char smem[44032];
    // loop: A0@0 (8K) | A1@8192 | B0@16384 (8K) | B1@24576 | sS@32768 (2K) | hB@34816 (8x1152)
    // epilogue: o2 [128][64] f32 (32KB) aliases @0..32768

    const int tid = threadIdx.x;
    const int w = tid >> 6, lane = tid & 63, lg = lane >> 4, lc = lane & 15;
    const int wr = w >> 1, wc = w & 1;
    const int bid = blockIdx.x;
    const int xr = bid & 7;
    const int q = bid >> 3;
    const int hd = q & 7;
    const size_t row0 = (size_t)(((q >> 3) << 3) | xr) * 64;

    const char* W1base = (const char*)W1L + (size_t)hd * 131072;
    float* sS = (float*)(smem + 32768);
    unsigned short* hb = (unsigned short*)(smem + 34816 + w * 1152);

    // staging roles: thread = (ra 0..127, qa 0..3); qa = k-octet within 32-k step
    const int ra = tid >> 2, qa = tid & 3;
    const float* arow = (ra < 64) ? (text + (row0 + ra) * 512)
                                  : (image + (row0 + ra - 64) * 512);
    const int dstA = qa * 2048 + ((ra * 16) ^ (qa << 4));

    float4 fva, fvb;
#define LOAD_FV(s_) do { \
    const float* p_ = arow + (s_) * 32 + 8 * qa; \
    fva = ((const float4*)p_)[0]; fvb = ((const float4*)p_)[1]; } while (0)

#define WRITE_A(buf_) do { \
    uint4 p_; \
    p_.x = pk2(fva.x, fva.y); p_.y = pk2(fva.z, fva.w); \
    p_.z = pk2(fvb.x, fvb.y); p_.w = pk2(fvb.z, fvb.w); \
    *(uint4*)((buf_) + dstA) = p_; } while (0)

#define STAGE_B(buf_, s_) do { \
    glds16(W1base + (s_) * 8192 + w * 1024 + lane * 16, (buf_) + w * 1024); } while (0)

    // ---- prologue ----
    LOAD_FV(0);
    STAGE_B(smem + 16384, 0);
    WRITE_A(smem);
    LOAD_FV(1);
    __syncthreads();

    f32x4 acc[2][4];
    #pragma unroll
    for (int rt = 0; rt < 2; ++rt)
        #pragma unroll
        for (int nt = 0; nt < 4; ++nt) acc[rt][nt] = (f32x4){0.f, 0.f, 0.f, 0.f};

    // ---- GEMM1 K-loop: 16 steps of BK=32 ----
    #pragma unroll
    for (int s = 0; s < 16; ++s) {
        const int cur = s & 1;
        char* bufAc = smem + cur * 8192;
        char* bufBc = smem + 16384 + cur * 8192;
        if (s < 15) {
            WRITE_A(smem + (cur ^ 1) * 8192);
            STAGE_B(smem + 16384 + (cur ^ 1) * 8192, s + 1);
        }
        if (s < 14) LOAD_FV(s + 2);

        short8v afv[2];
        #pragma unroll
        for (int rt = 0; rt < 2; ++rt) {
            const int row = 32 * wr + 16 * rt + lc;
            afv[rt] = *(const short8v*)(bufAc + lg * 2048 + ((row * 16) ^ (lg << 4)));
        }
        #pragma unroll
        for (int nt = 0; nt < 4; ++nt) {
            short8v bfv = *(const short8v*)(bufBc + (4 * wc + nt) * 1024 + lane * 16);
            acc[0][nt] = __builtin_amdgcn_mfma_f32_16x16x32_bf16(afv[0], bfv, acc[0][nt], 0, 0, 0);
            acc[1][nt] = __builtin_amdgcn_mfma_f32_16x16x32_bf16(afv[1], bfv, acc[1][nt], 0, 0, 0);
        }
        __syncthreads();
    }
#undef LOAD_FV
#undef WRITE_A
#undef STAGE_B

    // ---- + b1, row-stat partials ----
    #pragma unroll
    for (int nt = 0; nt < 4; ++nt) {
        float bv = b1[hd * 128 + 64 * wc + 16 * nt + lc];
        #pragma unroll
        for (int rt = 0; rt < 2; ++rt)
            #pragma unroll
            for (int reg = 0; reg < 4; ++reg) acc[rt][nt][reg] += bv;
    }
    #pragma unroll
    for (int rt = 0; rt < 2; ++rt)
        #pragma unroll
        for (int reg = 0; reg < 4; ++reg) {
            float s1 = 0.f, s2 = 0.f;
            #pragma unroll
            for (int nt = 0; nt < 4; ++nt) { float v = acc[rt][nt][reg]; s1 += v; s2 += v * v; }
            #pragma unroll
            for (int off = 1; off < 16; off <<= 1) {
                s1 += __shfl_xor(s1, off, 64);
                s2 += __shfl_xor(s2, off, 64);
            }
            if (lc == 0) {
                int row = 32 * wr + 16 * rt + 4 * lg + reg;
                sS[(wc * 128 + row) * 2 + 0] = s1;
                sS[(wc * 128 + row) * 2 + 1] = s2;
            }
        }
    __syncthreads();

    // ---- LN + GELU in-register ----
    float mu[2][4], rsig[2][4];
    #pragma unroll
    for (int rt = 0; rt < 2; ++rt)
        #pragma unroll
        for (int reg = 0; reg < 4; ++reg) {
            int row = 32 * wr + 16 * rt + 4 * lg + reg;
            float s1 = sS[row * 2 + 0] + sS[(128 + row) * 2 + 0];
            float s2 = sS[row * 2 + 1] + sS[(128 + row) * 2 + 1];
            float m = s1 * (1.0f / 128.0f);
            float var = s2 * (1.0f / 128.0f) - m * m;
            mu[rt][reg] = m;
            rsig[rt][reg] = rsqrtf(var + 1e-5f);
        }
    #pragma unroll
    for (int nt = 0; nt < 4; ++nt) {
        int col = 64 * wc + 16 * nt + lc;
        float gv = ln1g[hd * 128 + col];
        float bv = ln1b[hd * 128 + col];
        #pragma unroll
        for (int rt = 0; rt < 2; ++rt)
            #pragma unroll
            for (int reg = 0; reg < 4; ++reg) {
                float v = (acc[rt][nt][reg] - mu[rt][reg]) * rsig[rt][reg] * gv + bv;
                acc[rt][nt][reg] = gelu_exact(v);
            }
    }

    // ---- GEMM2 per-wave half-K + 2-pass o2 accumulate ----
    const char* W2b = (const char*)W2T + (size_t)hd * 16384;
    #pragma unroll
    for (int rt = 0; rt < 2; ++rt) {
        f32x4 acc2[4];
        #pragma unroll
        for (int nt2 = 0; nt2 < 4; ++nt2) acc2[nt2] = (f32x4){0.f, 0.f, 0.f, 0.f};

        #pragma unroll
        for (int kk2 = 0; kk2 < 2; ++kk2) {
            // transpose this 16-row x 32-k chunk into wave-private scratch
            #pragma unroll
            for (int ntl = 0; ntl < 2; ++ntl) {
                const int nt = 2 * kk2 + ntl;
                const int kk = 16 * ntl + lc;
                #pragma unroll
                for (int reg = 0; reg < 4; ++reg)
                    hb[(4 * lg + reg) * 36 + kk] = f2bf(acc[rt][nt][reg]);
            }
            short8v af2 = *(const short8v*)((const char*)hb + lc * 72 + 16 * lg);
            const char* wb = W2b + (2 * wc + kk2) * 4096 + lane * 16;
            #pragma unroll
            for (int nt2 = 0; nt2 < 4; ++nt2) {
                short8v w2f = *(const short8v*)(wb + nt2 * 1024);
                acc2[nt2] = __builtin_amdgcn_mfma_f32_16x16x32_bf16(af2, w2f, acc2[nt2], 0, 0, 0);
            }
        }
        // o2[row][col] f32 swizzled @smem[0..32K): pass wc=0 writes (+b2), pass wc=1 adds
        if (wc == 0) {
            #pragma unroll
            for (int nt2 = 0; nt2 < 4; ++nt2) {
                float bv = b2[hd * 64 + 16 * nt2 + lc];
                #pragma unroll
                for (int reg = 0; reg < 4; ++reg) {
                    int row = 32 * wr + 16 * rt + 4 * lg + reg;
                    int col = 16 * nt2 + lc;
                    *(float*)(smem + row * 256 + ((col * 4) ^ ((row & 7) << 4))) = acc2[nt2][reg] + bv;
                }
            }
        }
        __syncthreads();
        if (wc == 1) {
            #pragma unroll
            for (int nt2 = 0; nt2 < 4; ++nt2)
                #pragma unroll
                for (int reg = 0; reg < 4; ++reg) {
                    int row = 32 * wr + 16 * rt + 4 * lg + reg;
                    int col = 16 * nt2 + lc;
                    float* p = (float*)(smem + row * 256 + ((col * 4) ^ ((row & 7) << 4)));
                    *p += acc2[nt2][reg];
                }
        }
        __syncthreads();
    }

    // ---- cosine: waves 0..3, row r = 16w+lc (text) vs r+64 (image) ----
    if (w < 4) {
        int r = 16 * w + lc;
        int sw = (r & 7) << 4;      // (r+64)&7 == r&7
        float nt_ = 0.f, ni_ = 0.f, pr = 0.f;
        #pragma unroll
        for (int q2 = 0; q2 < 4; ++q2) {
            int c16 = 2 * lg + (q2 & 1) + (q2 >> 1) * 8;
            float4 a = *(const float4*)(smem + r * 256 + ((c16 * 16) ^ sw));
            float4 b = *(const float4*)(smem + (r + 64) * 256 + ((c16 * 16) ^ sw));
            nt_ += a.x * a.x + a.y * a.y + a.z * a.z + a.w * a.w;
            ni_ += b.x * b.x + b.y * b.y + b.z * b.z + b.w * b.w;
            pr  += a.x * b.x + a.y * b.y + a.z * b.z + a.w * b.w;
        }
        nt_ += __shfl_xor(nt_, 16, 64); ni_ += __shfl_xor(ni_, 16, 64); pr += __shfl_xor(pr, 16, 64);
        nt_ += __shfl_xor(nt_, 32, 64); ni_ += __shfl_xor(ni_, 32, 64); pr += __shfl_xor(pr, 32, 64);
        if (lg == 0) {
            float denom = fmaxf(sqrtf(nt_), 1e-12f) * fmaxf(sqrtf(ni_), 1e-12f);
            out_pa[(row0 + r) * 8 + hd] = pr / denom;
        }
    }
}

// ============== kernel G: global path -> conflict (R9 structure, cheap erf) ==============
__global__ __launch_bounds__(512, 4) void global_kernel(
    const float* __restrict__ text, const float* __restrict__ image,
    const unsigned short* __restrict__ gW1T, const float* __restrict__ gb1,
    const float* __restrict__ glng, const float* __restrict__ glnb,
    const float* __restrict__ gW2, const float* __restrict__ gb2,
    const float* __restrict__ aw, const float* __restrict__ pa,
    float* __restrict__ out_conflict)
{
    __shared__ __align__(1024) char gsm[79872];
    // bufA0 @0 (4K) | bufA1 @4096 | bufB0 @8192 (32K) | bufB1 @40960 | sStat @73728 (4K) | sDot @77824 (2K)

    const int tid = threadIdx.x;
    const int w = tid >> 6, lane = tid & 63, lg = lane >> 4, lc = lane & 15;
    const size_t row0 = (size_t)blockIdx.x * 64;
    const char* gWb = (const char*)gW1T;
    float* sStat = (float*)(gsm + 73728);
    float* sDot  = (float*)(gsm + 77824);

    const int r = tid >> 3, c4 = tid & 7;
    const float* arow_t = text + (row0 + r) * 512 + 4 * c4;
    const float* arow_i = image + (row0 + r) * 512 + 4 * c4;
    const int dstoffA = (c4 >> 1) * 1024 + r * 16 + (c4 & 1) * 8;

    float4 fv;
#define LOAD_FV(s_) do { fv = *(const float4*)(((s_) < 16 ? arow_t + (s_) * 32 : arow_i + ((s_) - 16) * 32)); } while (0)
#define WRITE_A(buf_) do { uint2 p_; p_.x = pk2(fv.x, fv.y); p_.y = pk2(fv.z, fv.w); *(uint2*)((buf_) + dstoffA) = p_; } while (0)
#define STAGE_B(buf_, s_) do { \
    const char* s2_ = gWb + (size_t)(s_) * 32768 + w * 4096 + lane * 16; \
    char* d2_ = (buf_) + w * 4096; \
    glds16(s2_, d2_); glds16(s2_ + 1024, d2_ + 1024); \
    glds16(s2_ + 2048, d2_ + 2048); glds16(s2_ + 3072, d2_ + 3072); } while (0)

    LOAD_FV(0);
    STAGE_B(gsm + 8192, 0);
    WRITE_A(gsm);
    LOAD_FV(1);
    __syncthreads();

    f32x4 acc[4][4];
    #pragma unroll
    for (int rt = 0; rt < 4; ++rt)
        #pragma unroll
        for (int nt = 0; nt < 4; ++nt) acc[rt][nt] = (f32x4){0.f, 0.f, 0.f, 0.f};

    #pragma unroll
    for (int s = 0; s < 32; ++s) {
        const int cur = s & 1;
        char* bufAc = gsm + cur * 4096;
        char* bufBc = gsm + 8192 + cur * 32768;
        if (s < 31) {
            WRITE_A(gsm + (cur ^ 1) * 4096);
            STAGE_B(gsm + 8192 + (cur ^ 1) * 32768, s + 1);
        }
        if (s < 30) LOAD_FV(s + 2);

        short8v af[4];
        #pragma unroll
        for (int rt = 0; rt < 4; ++rt)
            af[rt] = *(const short8v*)(bufAc + lg * 1024 + (16 * rt + lc) * 16);
        #pragma unroll
        for (int nt = 0; nt < 4; ++nt) {
            short8v bfv = *(const short8v*)(bufBc + (4 * w + nt) * 1024 + lane * 16);
            #pragma unroll
            for (int rt = 0; rt < 4; ++rt)
                acc[rt][nt] = __builtin_amdgcn_mfma_f32_16x16x32_bf16(af[rt], bfv, acc[rt][nt], 0, 0, 0);
        }
        __syncthreads();
    }
#undef LOAD_FV
#undef WRITE_A
#undef STAGE_B

    // ---- + gb1, LN stat partials ----
    #pragma unroll
    for (int nt = 0; nt < 4; ++nt) {
        float bv = gb1[64 * w + 16 * nt + lc];
        #pragma unroll
        for (int rt = 0; rt < 4; ++rt)
            #pragma unroll
            for (int reg = 0; reg < 4; ++reg) acc[rt][nt][reg] += bv;
    }
    #pragma unroll
    for (int rt = 0; rt < 4; ++rt)
        #pragma unroll
        for (int reg = 0; reg < 4; ++reg) {
            float s1 = 0.f, s2 = 0.f;
            #pragma unroll
            for (int nt = 0; nt < 4; ++nt) { float v = acc[rt][nt][reg]; s1 += v; s2 += v * v; }
            #pragma unroll
            for (int off = 1; off < 16; off <<= 1) {
                s1 += __shfl_xor(s1, off, 64);
                s2 += __shfl_xor(s2, off, 64);
            }
            if (lc == 0) {
                int rr = 16 * rt + 4 * lg + reg;
                sStat[(w * 64 + rr) * 2 + 0] = s1;
                sStat[(w * 64 + rr) * 2 + 1] = s2;
            }
        }
    __syncthreads();

    float mug[4][4], rsg[4][4];
    #pragma unroll
    for (int rt = 0; rt < 4; ++rt)
        #pragma unroll
        for (int reg = 0; reg < 4; ++reg) {
            int rr = 16 * rt + 4 * lg + reg;
            float s1 = 0.f, s2 = 0.f;
            #pragma unroll
            for (int ww = 0; ww < 8; ++ww) {
                s1 += sStat[(ww * 64 + rr) * 2 + 0];
                s2 += sStat[(ww * 64 + rr) * 2 + 1];
            }
            float m = s1 * (1.0f / 512.0f);
            float var = s2 * (1.0f / 512.0f) - m * m;
            mug[rt][reg] = m;
            rsg[rt][reg] = rsqrtf(var + 1e-5f);
        }

    // ---- LN + GELU + dot(gW2) partials ----
    float dp[4][4];
    #pragma unroll
    for (int rt = 0; rt < 4; ++rt)
        #pragma unroll
        for (int reg = 0; reg < 4; ++reg) dp[rt][reg] = 0.f;
    #pragma unroll
    for (int nt = 0; nt < 4; ++nt) {
        int col = 64 * w + 16 * nt + lc;
        float gv = glng[col], bv = glnb[col], wv = gW2[col];
        #pragma unroll
        for (int rt = 0; rt < 4; ++rt)
            #pragma unroll
            for (int reg = 0; reg < 4; ++reg) {
                float v = (acc[rt][nt][reg] - mug[rt][reg]) * rsg[rt][reg] * gv + bv;
                dp[rt][reg] += gelu_exact(v) * wv;
            }
    }
    #pragma unroll
    for (int rt = 0; rt < 4; ++rt)
        #pragma unroll
        for (int reg = 0; reg < 4; ++reg) {
            float d = dp[rt][reg];
            #pragma unroll
            for (int off = 1; off < 16; off <<= 1) d += __shfl_xor(d, off, 64);
            if (lc == 0) sDot[w * 64 + 16 * rt + 4 * lg + reg] = d;
        }
    __syncthreads();

    // ---- conflict epilogue ----
    if (tid < 64) {
        int rr = tid;
        float z = gb2[0];
        #pragma unroll
        for (int ww = 0; ww < 8; ++ww) z += sDot[ww * 64 + rr];
        float gs = 1.0f / (1.0f + expf(-z));
        float wv[8], mx = -1e30f;
        #pragma unroll
        for (int i = 0; i < 8; ++i) { wv[i] = aw[i]; mx = fmaxf(mx, wv[i]); }
        float sum = 0.f;
        #pragma unroll
        for (int i = 0; i < 8; ++i) { wv[i] = expf(wv[i] - mx); sum += wv[i]; }
        float inv = 1.0f / sum;
        const float* par = pa + (row0 + rr) * 8;
        float wsim = 0.f;
        #pragma unroll
        for (int i = 0; i < 8; ++i) wsim += par[i] * wv[i] * inv;
        float conf = 1.0f - (0.7f * wsim + 0.3f * gs);
        out_conflict[row0 + rr] = fminf(fmaxf(conf, 0.0f), 1.0f);
    }
}

extern "C" void kernel_launch(void* const* d_in, const int* in_sizes, int n_in,
                              void* d_out, int out_size, void* d_ws, size_t ws_size,
                              hipStream_t stream) {
    const float* text  = (const float*)d_in[0];
    const float* image = (const float*)d_in[1];
    const float* W1    = (const float*)d_in[2];
    const float* b1    = (const float*)d_in[3];
    const float* ln1g  = (const float*)d_in[4];
    const float* ln1b  = (const float*)d_in[5];
    const float* W2    = (const float*)d_in[6];
    const float* b2    = (const float*)d_in[7];
    const float* aw    = (const float*)d_in[8];
    const float* gW1   = (const float*)d_in[9];
    const float* gb1   = (const float*)d_in[10];
    const float* glng  = (const float*)d_in[11];
    const float* glnb  = (const float*)d_in[12];
    const float* gW2   = (const float*)d_in[13];
    const float* gb2   = (const float*)d_in[14];

    unsigned short* W1L  = (unsigned short*)d_ws;                          // 1MB
    unsigned short* W2T  = (unsigned short*)((char*)d_ws + 1048576);       // 128KB
    unsigned short* gW1T = (unsigned short*)((char*)d_ws + 1179648);       // 1MB

    float* out = (float*)d_out;
    float* out_pa = out + B_TOTAL;

    convert_weights<<<544, 256, 0, stream>>>(W1, W2, gW1, W1L, W2T, gW1T);
    head_kernel<<<8192, 512, 0, stream>>>(text, image, W1L, b1, ln1g, ln1b, W2T, b2, out_pa);
    global_kernel<<<1024, 512, 0, stream>>>(text, image, gW1T, gb1, glng, glnb, gW2, gb2,
                                            aw, out_pa, out);
}

// Round 11
// 759.236 us; speedup vs baseline: 2.1248x; 1.0457x over previous
//
#include <hip/hip_runtime.h>
#include <hip/hip_bf16.h>
#include <math.h>

#define B_TOTAL 65536

typedef __attribute__((ext_vector_type(8))) short short8v;   // 8 bf16 (4 VGPRs)
typedef __attribute__((ext_vector_type(4))) float f32x4;

__device__ __forceinline__ unsigned short f2bf(float f) {
    union { float f; unsigned u; } v; v.f = f;
    unsigned r = v.u + 0x7FFF + ((v.u >> 16) & 1);   // RNE
    return (unsigned short)(r >> 16);
}

__device__ __forceinline__ unsigned pk2(float a, float b) {
    float2 t; t.x = a; t.y = b;
    __hip_bfloat162 h = __float22bfloat162_rn(t);    // v_cvt_pk_bf16_f32
    union { __hip_bfloat162 h; unsigned u; } c; c.h = h;
    return c.u;
}

// Abramowitz-Stegun 7.1.26: |erf - approx| <= 1.5e-7, branch-free
__device__ __forceinline__ float erf_fast(float x) {
    float ax = fabsf(x);
    float t = 1.0f / (1.0f + 0.3275911f * ax);
    float y = t * (0.254829592f + t * (-0.284496736f + t * (1.421413741f
              + t * (-1.453152027f + t * 1.061405429f))));
    float r = 1.0f - y * __expf(-ax * ax);
    return copysignf(r, x);
}

__device__ __forceinline__ float gelu_exact(float x) {
    return 0.5f * x * (1.0f + erf_fast(x * 0.70710678118654752440f));
}

__device__ __forceinline__ void glds16(const void* g, void* l) {
    __builtin_amdgcn_global_load_lds(
        (const __attribute__((address_space(1))) unsigned int*)g,
        (__attribute__((address_space(3))) unsigned int*)l, 16, 0, 0);
}

// ============== converter: weights -> fragment-linear bf16 in ws ==============
// W1L: [hd(8)][step(16)][nt(8)][lane(64)][j(8)]
//      elem j = W1[hd][step*32+8*(l>>4)+j][16*nt+(l&15)]         (8KB per step)
// W2T: [hd(8)][kb(4)][nt2(4)][lane][j]  elem j = W2[hd][32kb+8(l>>4)+j][16nt2+(l&15)]
// gW1T:[s(32)][nt(32)][lane][j]         elem j = gW1[32s+8(l>>4)+j][16nt+(l&15)]
__global__ void convert_weights(const float* __restrict__ W1, const float* __restrict__ W2,
                                const float* __restrict__ gW1,
                                unsigned short* __restrict__ W1L, unsigned short* __restrict__ W2T,
                                unsigned short* __restrict__ gW1T)
{
    int t = blockIdx.x * 256 + threadIdx.x;
    if (t < 65536) {
        int l = t & 63, nt = (t >> 6) & 7, step = (t >> 9) & 15, hd = t >> 13;
        int n = nt * 16 + (l & 15);
        int k = step * 32 + 8 * (l >> 4);
        const float* s = W1 + (size_t)hd * 65536 + (size_t)k * 128 + n;
        short8v o;
        #pragma unroll
        for (int j = 0; j < 8; ++j) o[j] = (short)f2bf(s[(size_t)j * 128]);
        *(short8v*)(W1L + (size_t)t * 8) = o;
    } else if (t < 65536 + 8192) {
        int u = t - 65536;
        int l = u & 63, nt = (u >> 6) & 3, kb = (u >> 8) & 3, hd = u >> 10;
        int m = 16 * nt + (l & 15);
        int k = 32 * kb + 8 * (l >> 4);
        const float* s = W2 + (size_t)hd * 8192 + (size_t)k * 64 + m;
        short8v o;
        #pragma unroll
        for (int j = 0; j < 8; ++j) o[j] = (short)f2bf(s[(size_t)j * 64]);
        *(short8v*)(W2T + (size_t)u * 8) = o;
    } else if (t < 65536 + 8192 + 65536) {
        int u = t - 73728;
        int l = u & 63, nt = (u >> 6) & 31, s0 = u >> 11;
        int n = 16 * nt + (l & 15);
        int k = 32 * s0 + 8 * (l >> 4);
        const float* s = gW1 + (size_t)k * 512 + n;
        short8v o;
        #pragma unroll
        for (int j = 0; j < 8; ++j) o[j] = (short)f2bf(s[(size_t)j * 512]);
        *(short8v*)(gW1T + (size_t)u * 8) = o;
    }
}

// ============== kernel H: per-head path -> per_aspect ==============
// 8192 blocks x 512 threads (8 waves), 3 blocks/CU (LDS 43KB, VGPR ~52-84).
// __launch_bounds__(512,4): min-waves 4 so the allocator does NOT over-squeeze
// (R10's (512,6) forced VGPR=40 -> 510MB spill traffic). Occupancy comes from
// actual resources: 43KB LDS + <=85 VGPR -> 3 blocks/CU.
// XCD swizzle: xr=bid&7, q=bid>>3, hd=q&7, rowblock=((q>>3)<<3)|xr.
// 64 batch rows/block (A-rows 0..63 text, 64..127 image). GEMM1 128x128, BK=32.
__global__ __launch_bounds__(512, 4) void head_kernel(
    const float* __restrict__ text, const float* __restrict__ image,
    const unsigned short* __restrict__ W1L, const float* __restrict__ b1,
    const float* __restrict__ ln1g, const float* __restrict__ ln1b,
    const unsigned short* __restrict__ W2T, const float* __restrict__ b2,
    float* __restrict__ out_pa)
{
    __shared__ __align__(1024) char smem[44032];
    // loop: A0@0 (8K) | A1@8192 | B0@16384 (8K) | B1@24576 | sS@32768 (2K) | hB@34816 (8x1152)
    // epilogue: o2 [128][64] f32 (32KB) aliases @0..32768

    const int tid = threadIdx.x;
    const int w = tid >> 6, lane = tid & 63, lg = lane >> 4, lc = lane & 15;
    const int wr = w >> 1, wc = w & 1;
    const int bid = blockIdx.x;
    const int xr = bid & 7;
    const int q = bid >> 3;
    const int hd = q & 7;
    const size_t row0 = (size_t)(((q >> 3) << 3) | xr) * 64;

    const char* W1base = (const char*)W1L + (size_t)hd * 131072;
    float* sS = (float*)(smem + 32768);
    unsigned short* hb = (unsigned short*)(smem + 34816 + w * 1152);

    // staging roles: thread = (ra 0..127, qa 0..3); qa = k-octet within 32-k step
    const int ra = tid >> 2, qa = tid & 3;
    const float* arow = (ra < 64) ? (text + (row0 + ra) * 512)
                                  : (image + (row0 + ra - 64) * 512);
    const int dstA = qa * 2048 + ((ra * 16) ^ (qa << 4));

    float4 fva, fvb;
#define LOAD_FV(s_) do { \
    const float* p_ = arow + (s_) * 32 + 8 * qa; \
    fva = ((const float4*)p_)[0]; fvb = ((const float4*)p_)[1]; } while (0)

#define WRITE_A(buf_) do { \
    uint4 p_; \
    p_.x = pk2(fva.x, fva.y); p_.y = pk2(fva.z, fva.w); \
    p_.z = pk2(fvb.x, fvb.y); p_.w = pk2(fvb.z, fvb.w); \
    *(uint4*)((buf_) + dstA) = p_; } while (0)

#define STAGE_B(buf_, s_) do { \
    glds16(W1base + (s_) * 8192 + w * 1024 + lane * 16, (buf_) + w * 1024); } while (0)

    // ---- prologue ----
    LOAD_FV(0);
    STAGE_B(smem + 16384, 0);
    WRITE_A(smem);
    LOAD_FV(1);
    __syncthreads();

    f32x4 acc[2][4];
    #pragma unroll
    for (int rt = 0; rt < 2; ++rt)
        #pragma unroll
        for (int nt = 0; nt < 4; ++nt) acc[rt][nt] = (f32x4){0.f, 0.f, 0.f, 0.f};

    // ---- GEMM1 K-loop: 16 steps of BK=32 (unroll 2 = static dbuf parity,
    // bounded live ranges) ----
    #pragma unroll 2
    for (int s = 0; s < 16; ++s) {
        const int cur = s & 1;
        char* bufAc = smem + cur * 8192;
        char* bufBc = smem + 16384 + cur * 8192;
        if (s < 15) {
            WRITE_A(smem + (cur ^ 1) * 8192);
            STAGE_B(smem + 16384 + (cur ^ 1) * 8192, s + 1);
        }
        if (s < 14) LOAD_FV(s + 2);

        short8v afv[2];
        #pragma unroll
        for (int rt = 0; rt < 2; ++rt) {
            const int row = 32 * wr + 16 * rt + lc;
            afv[rt] = *(const short8v*)(bufAc + lg * 2048 + ((row * 16) ^ (lg << 4)));
        }
        #pragma unroll
        for (int nt = 0; nt < 4; ++nt) {
            short8v bfv = *(const short8v*)(bufBc + (4 * wc + nt) * 1024 + lane * 16);
            acc[0][nt] = __builtin_amdgcn_mfma_f32_16x16x32_bf16(afv[0], bfv, acc[0][nt], 0, 0, 0);
            acc[1][nt] = __builtin_amdgcn_mfma_f32_16x16x32_bf16(afv[1], bfv, acc[1][nt], 0, 0, 0);
        }
        __syncthreads();
    }
#undef LOAD_FV
#undef WRITE_A
#undef STAGE_B

    // ---- + b1, row-stat partials ----
    #pragma unroll
    for (int nt = 0; nt < 4; ++nt) {
        float bv = b1[hd * 128 + 64 * wc + 16 * nt + lc];
        #pragma unroll
        for (int rt = 0; rt < 2; ++rt)
            #pragma unroll
            for (int reg = 0; reg < 4; ++reg) acc[rt][nt][reg] += bv;
    }
    #pragma unroll
    for (int rt = 0; rt < 2; ++rt)
        #pragma unroll
        for (int reg = 0; reg < 4; ++reg) {
            float s1 = 0.f, s2 = 0.f;
            #pragma unroll
            for (int nt = 0; nt < 4; ++nt) { float v = acc[rt][nt][reg]; s1 += v; s2 += v * v; }
            #pragma unroll
            for (int off = 1; off < 16; off <<= 1) {
                s1 += __shfl_xor(s1, off, 64);
                s2 += __shfl_xor(s2, off, 64);
            }
            if (lc == 0) {
                int row = 32 * wr + 16 * rt + 4 * lg + reg;
                sS[(wc * 128 + row) * 2 + 0] = s1;
                sS[(wc * 128 + row) * 2 + 1] = s2;
            }
        }
    __syncthreads();

    // ---- LN + GELU in-register ----
    float mu[2][4], rsig[2][4];
    #pragma unroll
    for (int rt = 0; rt < 2; ++rt)
        #pragma unroll
        for (int reg = 0; reg < 4; ++reg) {
            int row = 32 * wr + 16 * rt + 4 * lg + reg;
            float s1 = sS[row * 2 + 0] + sS[(128 + row) * 2 + 0];
            float s2 = sS[row * 2 + 1] + sS[(128 + row) * 2 + 1];
            float m = s1 * (1.0f / 128.0f);
            float var = s2 * (1.0f / 128.0f) - m * m;
            mu[rt][reg] = m;
            rsig[rt][reg] = rsqrtf(var + 1e-5f);
        }
    #pragma unroll
    for (int nt = 0; nt < 4; ++nt) {
        int col = 64 * wc + 16 * nt + lc;
        float gv = ln1g[hd * 128 + col];
        float bv = ln1b[hd * 128 + col];
        #pragma unroll
        for (int rt = 0; rt < 2; ++rt)
            #pragma unroll
            for (int reg = 0; reg < 4; ++reg) {
                float v = (acc[rt][nt][reg] - mu[rt][reg]) * rsig[rt][reg] * gv + bv;
                acc[rt][nt][reg] = gelu_exact(v);
            }
    }

    // ---- GEMM2 per-wave half-K + 2-pass o2 accumulate ----
    const char* W2b = (const char*)W2T + (size_t)hd * 16384;
    #pragma unroll
    for (int rt = 0; rt < 2; ++rt) {
        f32x4 acc2[4];
        #pragma unroll
        for (int nt2 = 0; nt2 < 4; ++nt2) acc2[nt2] = (f32x4){0.f, 0.f, 0.f, 0.f};

        #pragma unroll
        for (int kk2 = 0; kk2 < 2; ++kk2) {
            // transpose this 16-row x 32-k chunk into wave-private scratch
            #pragma unroll
            for (int ntl = 0; ntl < 2; ++ntl) {
                const int nt = 2 * kk2 + ntl;
                const int kk = 16 * ntl + lc;
                #pragma unroll
                for (int reg = 0; reg < 4; ++reg)
                    hb[(4 * lg + reg) * 36 + kk] = f2bf(acc[rt][nt][reg]);
            }
            short8v af2 = *(const short8v*)((const char*)hb + lc * 72 + 16 * lg);
            const char* wb = W2b + (2 * wc + kk2) * 4096 + lane * 16;
            #pragma unroll
            for (int nt2 = 0; nt2 < 4; ++nt2) {
                short8v w2f = *(const short8v*)(wb + nt2 * 1024);
                acc2[nt2] = __builtin_amdgcn_mfma_f32_16x16x32_bf16(af2, w2f, acc2[nt2], 0, 0, 0);
            }
        }
        // o2[row][col] f32 swizzled @smem[0..32K): pass wc=0 writes (+b2), pass wc=1 adds
        if (wc == 0) {
            #pragma unroll
            for (int nt2 = 0; nt2 < 4; ++nt2) {
                float bv = b2[hd * 64 + 16 * nt2 + lc];
                #pragma unroll
                for (int reg = 0; reg < 4; ++reg) {
                    int row = 32 * wr + 16 * rt + 4 * lg + reg;
                    int col = 16 * nt2 + lc;
                    *(float*)(smem + row * 256 + ((col * 4) ^ ((row & 7) << 4))) = acc2[nt2][reg] + bv;
                }
            }
        }
        __syncthreads();
        if (wc == 1) {
            #pragma unroll
            for (int nt2 = 0; nt2 < 4; ++nt2)
                #pragma unroll
                for (int reg = 0; reg < 4; ++reg) {
                    int row = 32 * wr + 16 * rt + 4 * lg + reg;
                    int col = 16 * nt2 + lc;
                    float* p = (float*)(smem + row * 256 + ((col * 4) ^ ((row & 7) << 4)));
                    *p += acc2[nt2][reg];
                }
        }
        __syncthreads();
    }

    // ---- cosine: waves 0..3, row r = 16w+lc (text) vs r+64 (image) ----
    if (w < 4) {
        int r = 16 * w + lc;
        int sw = (r & 7) << 4;      // (r+64)&7 == r&7
        float nt_ = 0.f, ni_ = 0.f, pr = 0.f;
        #pragma unroll
        for (int q2 = 0; q2 < 4; ++q2) {
            int c16 = 2 * lg + (q2 & 1) + (q2 >> 1) * 8;
            float4 a = *(const float4*)(smem + r * 256 + ((c16 * 16) ^ sw));
            float4 b = *(const float4*)(smem + (r + 64) * 256 + ((c16 * 16) ^ sw));
            nt_ += a.x * a.x + a.y * a.y + a.z * a.z + a.w * a.w;
            ni_ += b.x * b.x + b.y * b.y + b.z * b.z + b.w * b.w;
            pr  += a.x * b.x + a.y * b.y + a.z * b.z + a.w * b.w;
        }
        nt_ += __shfl_xor(nt_, 16, 64); ni_ += __shfl_xor(ni_, 16, 64); pr += __shfl_xor(pr, 16, 64);
        nt_ += __shfl_xor(nt_, 32, 64); ni_ += __shfl_xor(ni_, 32, 64); pr += __shfl_xor(pr, 32, 64);
        if (lg == 0) {
            float denom = fmaxf(sqrtf(nt_), 1e-12f) * fmaxf(sqrtf(ni_), 1e-12f);
            out_pa[(row0 + r) * 8 + hd] = pr / denom;
        }
    }
}

// ============== kernel G: global path -> conflict (R9 structure, cheap erf) ==============
__global__ __launch_bounds__(512, 4) void global_kernel(
    const float* __restrict__ text, const float* __restrict__ image,
    const unsigned short* __restrict__ gW1T, const float* __restrict__ gb1,
    const float* __restrict__ glng, const float* __restrict__ glnb,
    const float* __restrict__ gW2, const float* __restrict__ gb2,
    const float* __restrict__ aw, const float* __restrict__ pa,
    float* __restrict__ out_conflict)
{
    __shared__ __align__(1024) char gsm[79872];
    // bufA0 @0 (4K) | bufA1 @4096 | bufB0 @8192 (32K) | bufB1 @40960 | sStat @73728 (4K) | sDot @77824 (2K)

    const int tid = threadIdx.x;
    const int w = tid >> 6, lane = tid & 63, lg = lane >> 4, lc = lane & 15;
    const size_t row0 = (size_t)blockIdx.x * 64;
    const char* gWb = (const char*)gW1T;
    float* sStat = (float*)(gsm + 73728);
    float* sDot  = (float*)(gsm + 77824);

    const int r = tid >> 3, c4 = tid & 7;
    const float* arow_t = text + (row0 + r) * 512 + 4 * c4;
    const float* arow_i = image + (row0 + r) * 512 + 4 * c4;
    const int dstoffA = (c4 >> 1) * 1024 + r * 16 + (c4 & 1) * 8;

    float4 fv;
#define LOAD_FV(s_) do { fv = *(const float4*)(((s_) < 16 ? arow_t + (s_) * 32 : arow_i + ((s_) - 16) * 32)); } while (0)
#define WRITE_A(buf_) do { uint2 p_; p_.x = pk2(fv.x, fv.y); p_.y = pk2(fv.z, fv.w); *(uint2*)((buf_) + dstoffA) = p_; } while (0)
#define STAGE_B(buf_, s_) do { \
    const char* s2_ = gWb + (size_t)(s_) * 32768 + w * 4096 + lane * 16; \
    char* d2_ = (buf_) + w * 4096; \
    glds16(s2_, d2_); glds16(s2_ + 1024, d2_ + 1024); \
    glds16(s2_ + 2048, d2_ + 2048); glds16(s2_ + 3072, d2_ + 3072); } while (0)

    LOAD_FV(0);
    STAGE_B(gsm + 8192, 0);
    WRITE_A(gsm);
    LOAD_FV(1);
    __syncthreads();

    f32x4 acc[4][4];
    #pragma unroll
    for (int rt = 0; rt < 4; ++rt)
        #pragma unroll
        for (int nt = 0; nt < 4; ++nt) acc[rt][nt] = (f32x4){0.f, 0.f, 0.f, 0.f};

    #pragma unroll 2
    for (int s = 0; s < 32; ++s) {
        const int cur = s & 1;
        char* bufAc = gsm + cur * 4096;
        char* bufBc = gsm + 8192 + cur * 32768;
        if (s < 31) {
            WRITE_A(gsm + (cur ^ 1) * 4096);
            STAGE_B(gsm + 8192 + (cur ^ 1) * 32768, s + 1);
        }
        if (s < 30) LOAD_FV(s + 2);

        short8v af[4];
        #pragma unroll
        for (int rt = 0; rt < 4; ++rt)
            af[rt] = *(const short8v*)(bufAc + lg * 1024 + (16 * rt + lc) * 16);
        #pragma unroll
        for (int nt = 0; nt < 4; ++nt) {
            short8v bfv = *(const short8v*)(bufBc + (4 * w + nt) * 1024 + lane * 16);
            #pragma unroll
            for (int rt = 0; rt < 4; ++rt)
                acc[rt][nt] = __builtin_amdgcn_mfma_f32_16x16x32_bf16(af[rt], bfv, acc[rt][nt], 0, 0, 0);
        }
        __syncthreads();
    }
#undef LOAD_FV
#undef WRITE_A
#undef STAGE_B

    // ---- + gb1, LN stat partials ----
    #pragma unroll
    for (int nt = 0; nt < 4; ++nt) {
        float bv = gb1[64 * w + 16 * nt + lc];
        #pragma unroll
        for (int rt = 0; rt < 4; ++rt)
            #pragma unroll
            for (int reg = 0; reg < 4; ++reg) acc[rt][nt][reg] += bv;
    }
    #pragma unroll
    for (int rt = 0; rt < 4; ++rt)
        #pragma unroll
        for (int reg = 0; reg < 4; ++reg) {
            float s1 = 0.f, s2 = 0.f;
            #pragma unroll
            for (int nt = 0; nt < 4; ++nt) { float v = acc[rt][nt][reg]; s1 += v; s2 += v * v; }
            #pragma unroll
            for (int off = 1; off < 16; off <<= 1) {
                s1 += __shfl_xor(s1, off, 64);
                s2 += __shfl_xor(s2, off, 64);
            }
            if (lc == 0) {
                int rr = 16 * rt + 4 * lg + reg;
                sStat[(w * 64 + rr) * 2 + 0] = s1;
                sStat[(w * 64 + rr) * 2 + 1] = s2;
            }
        }
    __syncthreads();

    float mug[4][4], rsg[4][4];
    #pragma unroll
    for (int rt = 0; rt < 4; ++rt)
        #pragma unroll
        for (int reg = 0; reg < 4; ++reg) {
            int rr = 16 * rt + 4 * lg + reg;
            float s1 = 0.f, s2 = 0.f;
            #pragma unroll
            for (int ww = 0; ww < 8; ++ww) {
                s1 += sStat[(ww * 64 + rr) * 2 + 0];
                s2 += sStat[(ww * 64 + rr) * 2 + 1];
            }
            float m = s1 * (1.0f / 512.0f);
            float var = s2 * (1.0f / 512.0f) - m * m;
            mug[rt][reg] = m;
            rsg[rt][reg] = rsqrtf(var + 1e-5f);
        }

    // ---- LN + GELU + dot(gW2) partials ----
    float dp[4][4];
    #pragma unroll
    for (int rt = 0; rt < 4; ++rt)
        #pragma unroll
        for (int reg = 0; reg < 4; ++reg) dp[rt][reg] = 0.f;
    #pragma unroll
    for (int nt = 0; nt < 4; ++nt) {
        int col = 64 * w + 16 * nt + lc;
        float gv = glng[col], bv = glnb[col], wv = gW2[col];
        #pragma unroll
        for (int rt = 0; rt < 4; ++rt)
            #pragma unroll
            for (int reg = 0; reg < 4; ++reg) {
                float v = (acc[rt][nt][reg] - mug[rt][reg]) * rsg[rt][reg] * gv + bv;
                dp[rt][reg] += gelu_exact(v) * wv;
            }
    }
    #pragma unroll
    for (int rt = 0; rt < 4; ++rt)
        #pragma unroll
        for (int reg = 0; reg < 4; ++reg) {
            float d = dp[rt][reg];
            #pragma unroll
            for (int off = 1; off < 16; off <<= 1) d += __shfl_xor(d, off, 64);
            if (lc == 0) sDot[w * 64 + 16 * rt + 4 * lg + reg] = d;
        }
    __syncthreads();

    // ---- conflict epilogue ----
    if (tid < 64) {
        int rr = tid;
        float z = gb2[0];
        #pragma unroll
        for (int ww = 0; ww < 8; ++ww) z += sDot[ww * 64 + rr];
        float gs = 1.0f / (1.0f + expf(-z));
        float wv[8], mx = -1e30f;
        #pragma unroll
        for (int i = 0; i < 8; ++i) { wv[i] = aw[i]; mx = fmaxf(mx, wv[i]); }
        float sum = 0.f;
        #pragma unroll
        for (int i = 0; i < 8; ++i) { wv[i] = expf(wv[i] - mx); sum += wv[i]; }
        float inv = 1.0f / sum;
        const float* par = pa + (row0 + rr) * 8;
        float wsim = 0.f;
        #pragma unroll
        for (int i = 0; i < 8; ++i) wsim += par[i] * wv[i] * inv;
        float conf = 1.0f - (0.7f * wsim + 0.3f * gs);
        out_conflict[row0 + rr] = fminf(fmaxf(conf, 0.0f), 1.0f);
    }
}

extern "C" void kernel_launch(void* const* d_in, const int* in_sizes, int n_in,
                              void* d_out, int out_size, void* d_ws, size_t ws_size,
                              hipStream_t stream) {
    const float* text  = (const float*)d_in[0];
    const float* image = (const float*)d_in[1];
    const float* W1    = (const float*)d_in[2];
    const float* b1    = (const float*)d_in[3];
    const float* ln1g  = (const float*)d_in[4];
    const float* ln1b  = (const float*)d_in[5];
    const float* W2    = (const float*)d_in[6];
    const float* b2    = (const float*)d_in[7];
    const float* aw    = (const float*)d_in[8];
    const float* gW1   = (const float*)d_in[9];
    const float* gb1   = (const float*)d_in[10];
    const float* glng  = (const float*)d_in[11];
    const float* glnb  = (const float*)d_in[12];
    const float* gW2   = (const float*)d_in[13];
    const float* gb2   = (const float*)d_in[14];

    unsigned short* W1L  = (unsigned short*)d_ws;                          // 1MB
    unsigned short* W2T  = (unsigned short*)((char*)d_ws + 1048576);       // 128KB
    unsigned short* gW1T = (unsigned short*)((char*)d_ws + 1179648);       // 1MB

    float* out = (float*)d_out;
    float* out_pa = out + B_TOTAL;

    convert_weights<<<544, 256, 0, stream>>>(W1, W2, gW1, W1L, W2T, gW1T);
    head_kernel<<<8192, 512, 0, stream>>>(text, image, W1L, b1, ln1g, ln1b, W2T, b2, out_pa);
    global_kernel<<<1024, 512, 0, stream>>>(text, image, gW1T, gb1, glng, glnb, gW2, gb2,
                                            aw, out_pa, out);
}

// Round 12
// 705.823 us; speedup vs baseline: 2.2856x; 1.0757x over previous
//
#include <hip/hip_runtime.h>
#include <hip/hip_bf16.h>
#include <math.h>

#define B_TOTAL 65536

typedef __attribute__((ext_vector_type(8))) short short8v;   // 8 bf16 (4 VGPRs)
typedef __attribute__((ext_vector_type(4))) float f32x4;

__device__ __forceinline__ unsigned short f2bf(float f) {
    union { float f; unsigned u; } v; v.f = f;
    unsigned r = v.u + 0x7FFF + ((v.u >> 16) & 1);   // RNE
    return (unsigned short)(r >> 16);
}

__device__ __forceinline__ unsigned pk2(float a, float b) {
    float2 t; t.x = a; t.y = b;
    __hip_bfloat162 h = __float22bfloat162_rn(t);    // v_cvt_pk_bf16_f32
    union { __hip_bfloat162 h; unsigned u; } c; c.h = h;
    return c.u;
}

// Abramowitz-Stegun 7.1.26: |erf - approx| <= 1.5e-7, branch-free
__device__ __forceinline__ float erf_fast(float x) {
    float ax = fabsf(x);
    float t = 1.0f / (1.0f + 0.3275911f * ax);
    float y = t * (0.254829592f + t * (-0.284496736f + t * (1.421413741f
              + t * (-1.453152027f + t * 1.061405429f))));
    float r = 1.0f - y * __expf(-ax * ax);
    return copysignf(r, x);
}

__device__ __forceinline__ float gelu_exact(float x) {
    return 0.5f * x * (1.0f + erf_fast(x * 0.70710678118654752440f));
}

__device__ __forceinline__ void glds16(const void* g, void* l) {
    __builtin_amdgcn_global_load_lds(
        (const __attribute__((address_space(1))) unsigned int*)g,
        (__attribute__((address_space(3))) unsigned int*)l, 16, 0, 0);
}

// ============== converter: weights -> fragment-linear bf16 in ws ==============
// W1L: [hd(8)][step(16)][nt(8)][lane(64)][j(8)]
//      elem j = W1[hd][step*32+8*(l>>4)+j][16*nt+(l&15)]         (8KB per 32-k step)
// W2T: [hd(8)][kb(4)][nt2(4)][lane][j]  elem j = W2[hd][32kb+8(l>>4)+j][16nt2+(l&15)]
// gW1T:[s(32)][nt(32)][lane][j]         elem j = gW1[32s+8(l>>4)+j][16nt+(l&15)]
__global__ void convert_weights(const float* __restrict__ W1, const float* __restrict__ W2,
                                const float* __restrict__ gW1,
                                unsigned short* __restrict__ W1L, unsigned short* __restrict__ W2T,
                                unsigned short* __restrict__ gW1T)
{
    int t = blockIdx.x * 256 + threadIdx.x;
    if (t < 65536) {
        int l = t & 63, nt = (t >> 6) & 7, step = (t >> 9) & 15, hd = t >> 13;
        int n = nt * 16 + (l & 15);
        int k = step * 32 + 8 * (l >> 4);
        const float* s = W1 + (size_t)hd * 65536 + (size_t)k * 128 + n;
        short8v o;
        #pragma unroll
        for (int j = 0; j < 8; ++j) o[j] = (short)f2bf(s[(size_t)j * 128]);
        *(short8v*)(W1L + (size_t)t * 8) = o;
    } else if (t < 65536 + 8192) {
        int u = t - 65536;
        int l = u & 63, nt = (u >> 6) & 3, kb = (u >> 8) & 3, hd = u >> 10;
        int m = 16 * nt + (l & 15);
        int k = 32 * kb + 8 * (l >> 4);
        const float* s = W2 + (size_t)hd * 8192 + (size_t)k * 64 + m;
        short8v o;
        #pragma unroll
        for (int j = 0; j < 8; ++j) o[j] = (short)f2bf(s[(size_t)j * 64]);
        *(short8v*)(W2T + (size_t)u * 8) = o;
    } else if (t < 65536 + 8192 + 65536) {
        int u = t - 73728;
        int l = u & 63, nt = (u >> 6) & 31, s0 = u >> 11;
        int n = 16 * nt + (l & 15);
        int k = 32 * s0 + 8 * (l >> 4);
        const float* s = gW1 + (size_t)k * 512 + n;
        short8v o;
        #pragma unroll
        for (int j = 0; j < 8; ++j) o[j] = (short)f2bf(s[(size_t)j * 512]);
        *(short8v*)(gW1T + (size_t)u * 8) = o;
    }
}

// ============== converter: inputs -> bf16, pre-swizzled fragment layout ==============
// textW/imageW: [rb(1024)][s(8)][oct(8)][byteq(1024)]  (64KB per 64-row block)
// byte chunk at (oct, lane*16) holds row = (lane*16 ^ (oct<<4))>>4, k = s*64+oct*8 .. +8
// so a linear glds16 (wave-uniform dst + lane*16) lands each row's fragment at
// LDS offset row*16 ^ (oct<<4)  — bank-swizzled without per-lane LDS scatter (m173).
__global__ void convert_inputs(const float* __restrict__ text, const float* __restrict__ image,
                               unsigned short* __restrict__ textW, unsigned short* __restrict__ imageW)
{
    int t = blockIdx.x * 256 + threadIdx.x;     // 2 x 4,194,304 chunks
    int tensor = t >> 22;
    int u = t & 4194303;
    int lane = u & 63, oct = (u >> 6) & 7, s = (u >> 9) & 7, rb = u >> 12;
    int row = ((lane * 16) ^ (oct << 4)) >> 4;
    const float* src = (tensor ? image : text)
                     + ((size_t)rb * 64 + row) * 512 + s * 64 + oct * 8;
    float4 a = ((const float4*)src)[0];
    float4 b = ((const float4*)src)[1];
    uint4 p;
    p.x = pk2(a.x, a.y); p.y = pk2(a.z, a.w);
    p.z = pk2(b.x, b.y); p.w = pk2(b.z, b.w);
    *(uint4*)((tensor ? imageW : textW) + (size_t)u * 8) = p;
}

// ============== kernel H (pre-converted): per-head path -> per_aspect ==============
// 8192 blocks x 512 threads. XCD swizzle: xr=bid&7, q=bid>>3, hd=q&7, rb=((q>>3)<<3)|xr.
// 64 batch rows/block (A-rows 0..63 text, 64..127 image). GEMM1 128x128, BK=64, 8 steps,
// 16 MFMA/wave/step (m97 density). A AND B staged via global_load_lds (no staging VALU).
// A LDS: [oct(8)][2048B] with byte row*16 ^ (oct<<4) (pre-swizzled in ws).
__global__ __launch_bounds__(512, 4) void head_pre(
    const unsigned short* __restrict__ textW, const unsigned short* __restrict__ imageW,
    const unsigned short* __restrict__ W1L, const float* __restrict__ b1,
    const float* __restrict__ ln1g, const float* __restrict__ ln1b,
    const unsigned short* __restrict__ W2T, const float* __restrict__ b2,
    float* __restrict__ out_pa)
{
    __shared__ __align__(1024) char smem[76800];
    // A0@0 (16K) | A1@16384 | B0@32768 (16K) | B1@49152 | sS@65536 (2K) | hB@67584 (8x1152)
    // epilogue: o2 [128][64] f32 (32KB) aliases @0..32768

    const int tid = threadIdx.x;
    const int w = tid >> 6, lane = tid & 63, lg = lane >> 4, lc = lane & 15;
    const int wr = w >> 1, wc = w & 1;
    const int bid = blockIdx.x;
    const int xr = bid & 7;
    const int q = bid >> 3;
    const int hd = q & 7;
    const int rb = ((q >> 3) << 3) | xr;
    const size_t row0 = (size_t)rb * 64;

    const char* W1base = (const char*)W1L + (size_t)hd * 131072;
    const char* tWb = (const char*)textW + (size_t)rb * 65536 + w * 1024 + lane * 16;
    const char* iWb = (const char*)imageW + (size_t)rb * 65536 + w * 1024 + lane * 16;
    float* sS = (float*)(smem + 65536);
    unsigned short* hb = (unsigned short*)(smem + 67584 + w * 1152);

    // wave w stages A-octet w (text half + image half) and 2KB of B per step
#define STAGE_A(buf_, s_) do { \
    glds16(tWb + (s_) * 8192, (buf_) + w * 2048); \
    glds16(iWb + (s_) * 8192, (buf_) + w * 2048 + 1024); } while (0)
#define STAGE_B(buf_, s_) do { \
    const char* bs_ = W1base + (s_) * 16384 + w * 2048 + lane * 16; \
    glds16(bs_, (buf_) + w * 2048); \
    glds16(bs_ + 1024, (buf_) + w * 2048 + 1024); } while (0)

    // ---- prologue ----
    STAGE_A(smem, 0);
    STAGE_B(smem + 32768, 0);
    __syncthreads();

    f32x4 acc[2][4];
    #pragma unroll
    for (int rt = 0; rt < 2; ++rt)
        #pragma unroll
        for (int nt = 0; nt < 4; ++nt) acc[rt][nt] = (f32x4){0.f, 0.f, 0.f, 0.f};

    // ---- GEMM1 K-loop: 8 steps of BK=64 ----
    #pragma unroll
    for (int s = 0; s < 8; ++s) {
        const int cur = s & 1;
        char* bufAc = smem + cur * 16384;
        char* bufBc = smem + 32768 + cur * 16384;
        if (s < 7) {
            STAGE_A(smem + (cur ^ 1) * 16384, s + 1);
            STAGE_B(smem + 32768 + (cur ^ 1) * 16384, s + 1);
        }
        #pragma unroll
        for (int kk = 0; kk < 2; ++kk) {
            const int o = kk * 4 + lg;
            short8v afv[2];
            #pragma unroll
            for (int rt = 0; rt < 2; ++rt) {
                const int row = 32 * wr + 16 * rt + lc;
                afv[rt] = *(const short8v*)(bufAc + o * 2048 + ((row * 16) ^ (o << 4)));
            }
            #pragma unroll
            for (int nt = 0; nt < 4; ++nt) {
                short8v bfv = *(const short8v*)(bufBc + kk * 8192 + (4 * wc + nt) * 1024 + lane * 16);
                acc[0][nt] = __builtin_amdgcn_mfma_f32_16x16x32_bf16(afv[0], bfv, acc[0][nt], 0, 0, 0);
                acc[1][nt] = __builtin_amdgcn_mfma_f32_16x16x32_bf16(afv[1], bfv, acc[1][nt], 0, 0, 0);
            }
        }
        __syncthreads();
    }
#undef STAGE_A
#undef STAGE_B

    // ---- + b1, row-stat partials ----
    #pragma unroll
    for (int nt = 0; nt < 4; ++nt) {
        float bv = b1[hd * 128 + 64 * wc + 16 * nt + lc];
        #pragma unroll
        for (int rt = 0; rt < 2; ++rt)
            #pragma unroll
            for (int reg = 0; reg < 4; ++reg) acc[rt][nt][reg] += bv;
    }
    #pragma unroll
    for (int rt = 0; rt < 2; ++rt)
        #pragma unroll
        for (int reg = 0; reg < 4; ++reg) {
            float s1 = 0.f, s2 = 0.f;
            #pragma unroll
            for (int nt = 0; nt < 4; ++nt) { float v = acc[rt][nt][reg]; s1 += v; s2 += v * v; }
            #pragma unroll
            for (int off = 1; off < 16; off <<= 1) {
                s1 += __shfl_xor(s1, off, 64);
                s2 += __shfl_xor(s2, off, 64);
            }
            if (lc == 0) {
                int row = 32 * wr + 16 * rt + 4 * lg + reg;
                sS[(wc * 128 + row) * 2 + 0] = s1;
                sS[(wc * 128 + row) * 2 + 1] = s2;
            }
        }
    __syncthreads();

    // ---- LN + GELU in-register ----
    float mu[2][4], rsig[2][4];
    #pragma unroll
    for (int rt = 0; rt < 2; ++rt)
        #pragma unroll
        for (int reg = 0; reg < 4; ++reg) {
            int row = 32 * wr + 16 * rt + 4 * lg + reg;
            float s1 = sS[row * 2 + 0] + sS[(128 + row) * 2 + 0];
            float s2 = sS[row * 2 + 1] + sS[(128 + row) * 2 + 1];
            float m = s1 * (1.0f / 128.0f);
            float var = s2 * (1.0f / 128.0f) - m * m;
            mu[rt][reg] = m;
            rsig[rt][reg] = rsqrtf(var + 1e-5f);
        }
    #pragma unroll
    for (int nt = 0; nt < 4; ++nt) {
        int col = 64 * wc + 16 * nt + lc;
        float gv = ln1g[hd * 128 + col];
        float bv = ln1b[hd * 128 + col];
        #pragma unroll
        for (int rt = 0; rt < 2; ++rt)
            #pragma unroll
            for (int reg = 0; reg < 4; ++reg) {
                float v = (acc[rt][nt][reg] - mu[rt][reg]) * rsig[rt][reg] * gv + bv;
                acc[rt][nt][reg] = gelu_exact(v);
            }
    }

    // ---- GEMM2 per-wave half-K + 2-pass o2 accumulate ----
    const char* W2b = (const char*)W2T + (size_t)hd * 16384;
    #pragma unroll
    for (int rt = 0; rt < 2; ++rt) {
        f32x4 acc2[4];
        #pragma unroll
        for (int nt2 = 0; nt2 < 4; ++nt2) acc2[nt2] = (f32x4){0.f, 0.f, 0.f, 0.f};

        #pragma unroll
        for (int kk2 = 0; kk2 < 2; ++kk2) {
            #pragma unroll
            for (int ntl = 0; ntl < 2; ++ntl) {
                const int nt = 2 * kk2 + ntl;
                const int kk = 16 * ntl + lc;
                #pragma unroll
                for (int reg = 0; reg < 4; ++reg)
                    hb[(4 * lg + reg) * 36 + kk] = f2bf(acc[rt][nt][reg]);
            }
            short8v af2 = *(const short8v*)((const char*)hb + lc * 72 + 16 * lg);
            const char* wb = W2b + (2 * wc + kk2) * 4096 + lane * 16;
            #pragma unroll
            for (int nt2 = 0; nt2 < 4; ++nt2) {
                short8v w2f = *(const short8v*)(wb + nt2 * 1024);
                acc2[nt2] = __builtin_amdgcn_mfma_f32_16x16x32_bf16(af2, w2f, acc2[nt2], 0, 0, 0);
            }
        }
        if (wc == 0) {
            #pragma unroll
            for (int nt2 = 0; nt2 < 4; ++nt2) {
                float bv = b2[hd * 64 + 16 * nt2 + lc];
                #pragma unroll
                for (int reg = 0; reg < 4; ++reg) {
                    int row = 32 * wr + 16 * rt + 4 * lg + reg;
                    int col = 16 * nt2 + lc;
                    *(float*)(smem + row * 256 + ((col * 4) ^ ((row & 7) << 4))) = acc2[nt2][reg] + bv;
                }
            }
        }
        __syncthreads();
        if (wc == 1) {
            #pragma unroll
            for (int nt2 = 0; nt2 < 4; ++nt2)
                #pragma unroll
                for (int reg = 0; reg < 4; ++reg) {
                    int row = 32 * wr + 16 * rt + 4 * lg + reg;
                    int col = 16 * nt2 + lc;
                    float* p = (float*)(smem + row * 256 + ((col * 4) ^ ((row & 7) << 4)));
                    *p += acc2[nt2][reg];
                }
        }
        __syncthreads();
    }

    // ---- cosine ----
    if (w < 4) {
        int r = 16 * w + lc;
        int sw = (r & 7) << 4;
        float nt_ = 0.f, ni_ = 0.f, pr = 0.f;
        #pragma unroll
        for (int q2 = 0; q2 < 4; ++q2) {
            int c16 = 2 * lg + (q2 & 1) + (q2 >> 1) * 8;
            float4 a = *(const float4*)(smem + r * 256 + ((c16 * 16) ^ sw));
            float4 b = *(const float4*)(smem + (r + 64) * 256 + ((c16 * 16) ^ sw));
            nt_ += a.x * a.x + a.y * a.y + a.z * a.z + a.w * a.w;
            ni_ += b.x * b.x + b.y * b.y + b.z * b.z + b.w * b.w;
            pr  += a.x * b.x + a.y * b.y + a.z * b.z + a.w * b.w;
        }
        nt_ += __shfl_xor(nt_, 16, 64); ni_ += __shfl_xor(ni_, 16, 64); pr += __shfl_xor(pr, 16, 64);
        nt_ += __shfl_xor(nt_, 32, 64); ni_ += __shfl_xor(ni_, 32, 64); pr += __shfl_xor(pr, 32, 64);
        if (lg == 0) {
            float denom = fmaxf(sqrtf(nt_), 1e-12f) * fmaxf(sqrtf(ni_), 1e-12f);
            out_pa[(row0 + r) * 8 + hd] = pr / denom;
        }
    }
}

// ============== kernel G (pre-converted): global path -> conflict ==============
// 1024 blocks x 512 threads. 64 rows x 512 cols; 32 steps of BK=32 (st<16 text).
// A from textW/imageW sub-chunks (glds, pre-swizzled); B = gW1T (glds).
__global__ __launch_bounds__(512, 4) void global_pre(
    const unsigned short* __restrict__ textW, const unsigned short* __restrict__ imageW,
    const unsigned short* __restrict__ gW1T, const float* __restrict__ gb1,
    const float* __restrict__ glng, const float* __restrict__ glnb,
    const float* __restrict__ gW2, const float* __restrict__ gb2,
    const float* __restrict__ aw, const float* __restrict__ pa,
    float* __restrict__ out_conflict)
{
    __shared__ __align__(1024) char gsm[79872];
    // A0@0 (4K) | A1@4096 | B0@8192 (32K) | B1@40960 | sStat@73728 (4K) | sDot@77824 (2K)

    const int tid = threadIdx.x;
    const int w = tid >> 6, lane = tid & 63, lg = lane >> 4, lc = lane & 15;
    const int rb = blockIdx.x;
    const size_t row0 = (size_t)rb * 64;
    const char* gWb = (const char*)gW1T;
    const char* tWb = (const char*)textW + (size_t)rb * 65536;
    const char* iWb = (const char*)imageW + (size_t)rb * 65536;
    float* sStat = (float*)(gsm + 73728);
    float* sDot  = (float*)(gsm + 77824);

#define STAGE(p_, st_) do { \
    char* bb_ = gsm + 8192 + (p_) * 32768 + w * 4096; \
    const char* bs_ = gWb + (size_t)(st_) * 32768 + w * 4096 + lane * 16; \
    glds16(bs_, bb_); glds16(bs_ + 1024, bb_ + 1024); \
    glds16(bs_ + 2048, bb_ + 2048); glds16(bs_ + 3072, bb_ + 3072); \
    if (w < 4) { \
        int stx_ = ((st_) < 16) ? (st_) : ((st_) - 16); \
        const char* as_ = (((st_) < 16) ? tWb : iWb) \
                        + (stx_ >> 1) * 8192 + ((stx_ & 1) * 4 + w) * 1024 + lane * 16; \
        glds16(as_, gsm + (p_) * 4096 + w * 1024); \
    } } while (0)

    STAGE(0, 0);
    __syncthreads();

    f32x4 acc[4][4];
    #pragma unroll
    for (int rt = 0; rt < 4; ++rt)
        #pragma unroll
        for (int nt = 0; nt < 4; ++nt) acc[rt][nt] = (f32x4){0.f, 0.f, 0.f, 0.f};

    #pragma unroll 2
    for (int st = 0; st < 32; ++st) {
        const int cur = st & 1;
        char* bufAc = gsm + cur * 4096;
        char* bufBc = gsm + 8192 + cur * 32768;
        if (st < 31) STAGE(cur ^ 1, st + 1);

        const int xk = (st & 1) << 6;
        short8v af[4];
        #pragma unroll
        for (int rt = 0; rt < 4; ++rt) {
            const int row = 16 * rt + lc;
            af[rt] = *(const short8v*)(bufAc + lg * 1024 + ((row * 16) ^ (lg << 4) ^ xk));
        }
        #pragma unroll
        for (int nt = 0; nt < 4; ++nt) {
            short8v bfv = *(const short8v*)(bufBc + (4 * w + nt) * 1024 + lane * 16);
            #pragma unroll
            for (int rt = 0; rt < 4; ++rt)
                acc[rt][nt] = __builtin_amdgcn_mfma_f32_16x16x32_bf16(af[rt], bfv, acc[rt][nt], 0, 0, 0);
        }
        __syncthreads();
    }
#undef STAGE

    // ---- + gb1, LN stat partials ----
    #pragma unroll
    for (int nt = 0; nt < 4; ++nt) {
        float bv = gb1[64 * w + 16 * nt + lc];
        #pragma unroll
        for (int rt = 0; rt < 4; ++rt)
            #pragma unroll
            for (int reg = 0; reg < 4; ++reg) acc[rt][nt][reg] += bv;
    }
    #pragma unroll
    for (int rt = 0; rt < 4; ++rt)
        #pragma unroll
        for (int reg = 0; reg < 4; ++reg) {
            float s1 = 0.f, s2 = 0.f;
            #pragma unroll
            for (int nt = 0; nt < 4; ++nt) { float v = acc[rt][nt][reg]; s1 += v; s2 += v * v; }
            #pragma unroll
            for (int off = 1; off < 16; off <<= 1) {
                s1 += __shfl_xor(s1, off, 64);
                s2 += __shfl_xor(s2, off, 64);
            }
            if (lc == 0) {
                int rr = 16 * rt + 4 * lg + reg;
                sStat[(w * 64 + rr) * 2 + 0] = s1;
                sStat[(w * 64 + rr) * 2 + 1] = s2;
            }
        }
    __syncthreads();

    float mug[4][4], rsg[4][4];
    #pragma unroll
    for (int rt = 0; rt < 4; ++rt)
        #pragma unroll
        for (int reg = 0; reg < 4; ++reg) {
            int rr = 16 * rt + 4 * lg + reg;
            float s1 = 0.f, s2 = 0.f;
            #pragma unroll
            for (int ww = 0; ww < 8; ++ww) {
                s1 += sStat[(ww * 64 + rr) * 2 + 0];
                s2 += sStat[(ww * 64 + rr) * 2 + 1];
            }
            float m = s1 * (1.0f / 512.0f);
            float var = s2 * (1.0f / 512.0f) - m * m;
            mug[rt][reg] = m;
            rsg[rt][reg] = rsqrtf(var + 1e-5f);
        }

    // ---- LN + GELU + dot(gW2) partials ----
    float dp[4][4];
    #pragma unroll
    for (int rt = 0; rt < 4; ++rt)
        #pragma unroll
        for (int reg = 0; reg < 4; ++reg) dp[rt][reg] = 0.f;
    #pragma unroll
    for (int nt = 0; nt < 4; ++nt) {
        int col = 64 * w + 16 * nt + lc;
        float gv = glng[col], bv = glnb[col], wv = gW2[col];
        #pragma unroll
        for (int rt = 0; rt < 4; ++rt)
            #pragma unroll
            for (int reg = 0; reg < 4; ++reg) {
                float v = (acc[rt][nt][reg] - mug[rt][reg]) * rsg[rt][reg] * gv + bv;
                dp[rt][reg] += gelu_exact(v) * wv;
            }
    }
    #pragma unroll
    for (int rt = 0; rt < 4; ++rt)
        #pragma unroll
        for (int reg = 0; reg < 4; ++reg) {
            float d = dp[rt][reg];
            #pragma unroll
            for (int off = 1; off < 16; off <<= 1) d += __shfl_xor(d, off, 64);
            if (lc == 0) sDot[w * 64 + 16 * rt + 4 * lg + reg] = d;
        }
    __syncthreads();

    if (tid < 64) {
        int rr = tid;
        float z = gb2[0];
        #pragma unroll
        for (int ww = 0; ww < 8; ++ww) z += sDot[ww * 64 + rr];
        float gs = 1.0f / (1.0f + expf(-z));
        float wv[8], mx = -1e30f;
        #pragma unroll
        for (int i = 0; i < 8; ++i) { wv[i] = aw[i]; mx = fmaxf(mx, wv[i]); }
        float sum = 0.f;
        #pragma unroll
        for (int i = 0; i < 8; ++i) { wv[i] = expf(wv[i] - mx); sum += wv[i]; }
        float inv = 1.0f / sum;
        const float* par = pa + (row0 + rr) * 8;
        float wsim = 0.f;
        #pragma unroll
        for (int i = 0; i < 8; ++i) wsim += par[i] * wv[i] * inv;
        float conf = 1.0f - (0.7f * wsim + 0.3f * gs);
        out_conflict[row0 + rr] = fminf(fmaxf(conf, 0.0f), 1.0f);
    }
}

// ===================== FALLBACK (R11, f32-input staging) =====================
__global__ __launch_bounds__(512, 4) void head_kernel(
    const float* __restrict__ text, const float* __restrict__ image,
    const unsigned short* __restrict__ W1L, const float* __restrict__ b1,
    const float* __restrict__ ln1g, const float* __restrict__ ln1b,
    const unsigned short* __restrict__ W2T, const float* __restrict__ b2,
    float* __restrict__ out_pa)
{
    __shared__ __align__(1024) char smem[44032];
    const int tid = threadIdx.x;
    const int w = tid >> 6, lane = tid & 63, lg = lane >> 4, lc = lane & 15;
    const int wr = w >> 1, wc = w & 1;
    const int bid = blockIdx.x;
    const int xr = bid & 7;
    const int q = bid >> 3;
    const int hd = q & 7;
    const size_t row0 = (size_t)(((q >> 3) << 3) | xr) * 64;

    const char* W1base = (const char*)W1L + (size_t)hd * 131072;
    float* sS = (float*)(smem + 32768);
    unsigned short* hb = (unsigned short*)(smem + 34816 + w * 1152);

    const int ra = tid >> 2, qa = tid & 3;
    const float* arow = (ra < 64) ? (text + (row0 + ra) * 512)
                                  : (image + (row0 + ra - 64) * 512);
    const int dstA = qa * 2048 + ((ra * 16) ^ (qa << 4));

    float4 fva, fvb;
#define LOAD_FV(s_) do { \
    const float* p_ = arow + (s_) * 32 + 8 * qa; \
    fva = ((const float4*)p_)[0]; fvb = ((const float4*)p_)[1]; } while (0)
#define WRITE_A(buf_) do { \
    uint4 p_; \
    p_.x = pk2(fva.x, fva.y); p_.y = pk2(fva.z, fva.w); \
    p_.z = pk2(fvb.x, fvb.y); p_.w = pk2(fvb.z, fvb.w); \
    *(uint4*)((buf_) + dstA) = p_; } while (0)
#define STAGE_B(buf_, s_) do { \
    glds16(W1base + (s_) * 8192 + w * 1024 + lane * 16, (buf_) + w * 1024); } while (0)

    LOAD_FV(0);
    STAGE_B(smem + 16384, 0);
    WRITE_A(smem);
    LOAD_FV(1);
    __syncthreads();

    f32x4 acc[2][4];
    #pragma unroll
    for (int rt = 0; rt < 2; ++rt)
        #pragma unroll
        for (int nt = 0; nt < 4; ++nt) acc[rt][nt] = (f32x4){0.f, 0.f, 0.f, 0.f};

    #pragma unroll 2
    for (int s = 0; s < 16; ++s) {
        const int cur = s & 1;
        char* bufAc = smem + cur * 8192;
        char* bufBc = smem + 16384 + cur * 8192;
        if (s < 15) {
            WRITE_A(smem + (cur ^ 1) * 8192);
            STAGE_B(smem + 16384 + (cur ^ 1) * 8192, s + 1);
        }
        if (s < 14) LOAD_FV(s + 2);

        short8v afv[2];
        #pragma unroll
        for (int rt = 0; rt < 2; ++rt) {
            const int row = 32 * wr + 16 * rt + lc;
            afv[rt] = *(const short8v*)(bufAc + lg * 2048 + ((row * 16) ^ (lg << 4)));
        }
        #pragma unroll
        for (int nt = 0; nt < 4; ++nt) {
            short8v bfv = *(const short8v*)(bufBc + (4 * wc + nt) * 1024 + lane * 16);
            acc[0][nt] = __builtin_amdgcn_mfma_f32_16x16x32_bf16(afv[0], bfv, acc[0][nt], 0, 0, 0);
            acc[1][nt] = __builtin_amdgcn_mfma_f32_16x16x32_bf16(afv[1], bfv, acc[1][nt], 0, 0, 0);
        }
        __syncthreads();
    }
#undef LOAD_FV
#undef WRITE_A
#undef STAGE_B

    #pragma unroll
    for (int nt = 0; nt < 4; ++nt) {
        float bv = b1[hd * 128 + 64 * wc + 16 * nt + lc];
        #pragma unroll
        for (int rt = 0; rt < 2; ++rt)
            #pragma unroll
            for (int reg = 0; reg < 4; ++reg) acc[rt][nt][reg] += bv;
    }
    #pragma unroll
    for (int rt = 0; rt < 2; ++rt)
        #pragma unroll
        for (int reg = 0; reg < 4; ++reg) {
            float s1 = 0.f, s2 = 0.f;
            #pragma unroll
            for (int nt = 0; nt < 4; ++nt) { float v = acc[rt][nt][reg]; s1 += v; s2 += v * v; }
            #pragma unroll
            for (int off = 1; off < 16; off <<= 1) {
                s1 += __shfl_xor(s1, off, 64);
                s2 += __shfl_xor(s2, off, 64);
            }
            if (lc == 0) {
                int row = 32 * wr + 16 * rt + 4 * lg + reg;
                sS[(wc * 128 + row) * 2 + 0] = s1;
                sS[(wc * 128 + row) * 2 + 1] = s2;
            }
        }
    __syncthreads();

    float mu[2][4], rsig[2][4];
    #pragma unroll
    for (int rt = 0; rt < 2; ++rt)
        #pragma unroll
        for (int reg = 0; reg < 4; ++reg) {
            int row = 32 * wr + 16 * rt + 4 * lg + reg;
            float s1 = sS[row * 2 + 0] + sS[(128 + row) * 2 + 0];
            float s2 = sS[row * 2 + 1] + sS[(128 + row) * 2 + 1];
            float m = s1 * (1.0f / 128.0f);
            float var = s2 * (1.0f / 128.0f) - m * m;
            mu[rt][reg] = m;
            rsig[rt][reg] = rsqrtf(var + 1e-5f);
        }
    #pragma unroll
    for (int nt = 0; nt < 4; ++nt) {
        int col = 64 * wc + 16 * nt + lc;
        float gv = ln1g[hd * 128 + col];
        float bv = ln1b[hd * 128 + col];
        #pragma unroll
        for (int rt = 0; rt < 2; ++rt)
            #pragma unroll
            for (int reg = 0; reg < 4; ++reg) {
                float v = (acc[rt][nt][reg] - mu[rt][reg]) * rsig[rt][reg] * gv + bv;
                acc[rt][nt][reg] = gelu_exact(v);
            }
    }

    const char* W2b = (const char*)W2T + (size_t)hd * 16384;
    #pragma unroll
    for (int rt = 0; rt < 2; ++rt) {
        f32x4 acc2[4];
        #pragma unroll
        for (int nt2 = 0; nt2 < 4; ++nt2) acc2[nt2] = (f32x4){0.f, 0.f, 0.f, 0.f};
        #pragma unroll
        for (int kk2 = 0; kk2 < 2; ++kk2) {
            #pragma unroll
            for (int ntl = 0; ntl < 2; ++ntl) {
                const int nt = 2 * kk2 + ntl;
                const int kk = 16 * ntl + lc;
                #pragma unroll
                for (int reg = 0; reg < 4; ++reg)
                    hb[(4 * lg + reg) * 36 + kk] = f2bf(acc[rt][nt][reg]);
            }
            short8v af2 = *(const short8v*)((const char*)hb + lc * 72 + 16 * lg);
            const char* wb = W2b + (2 * wc + kk2) * 4096 + lane * 16;
            #pragma unroll
            for (int nt2 = 0; nt2 < 4; ++nt2) {
                short8v w2f = *(const short8v*)(wb + nt2 * 1024);
                acc2[nt2] = __builtin_amdgcn_mfma_f32_16x16x32_bf16(af2, w2f, acc2[nt2], 0, 0, 0);
            }
        }
        if (wc == 0) {
            #pragma unroll
            for (int nt2 = 0; nt2 < 4; ++nt2) {
                float bv = b2[hd * 64 + 16 * nt2 + lc];
                #pragma unroll
                for (int reg = 0; reg < 4; ++reg) {
                    int row = 32 * wr + 16 * rt + 4 * lg + reg;
                    int col = 16 * nt2 + lc;
                    *(float*)(smem + row * 256 + ((col * 4) ^ ((row & 7) << 4))) = acc2[nt2][reg] + bv;
                }
            }
        }
        __syncthreads();
        if (wc == 1) {
            #pragma unroll
            for (int nt2 = 0; nt2 < 4; ++nt2)
                #pragma unroll
                for (int reg = 0; reg < 4; ++reg) {
                    int row = 32 * wr + 16 * rt + 4 * lg + reg;
                    int col = 16 * nt2 + lc;
                    float* p = (float*)(smem + row * 256 + ((col * 4) ^ ((row & 7) << 4)));
                    *p += acc2[nt2][reg];
                }
        }
        __syncthreads();
    }

    if (w < 4) {
        int r = 16 * w + lc;
        int sw = (r & 7) << 4;
        float nt_ = 0.f, ni_ = 0.f, pr = 0.f;
        #pragma unroll
        for (int q2 = 0; q2 < 4; ++q2) {
            int c16 = 2 * lg + (q2 & 1) + (q2 >> 1) * 8;
            float4 a = *(const float4*)(smem + r * 256 + ((c16 * 16) ^ sw));
            float4 b = *(const float4*)(smem + (r + 64) * 256 + ((c16 * 16) ^ sw));
            nt_ += a.x * a.x + a.y * a.y + a.z * a.z + a.w * a.w;
            ni_ += b.x * b.x + b.y * b.y + b.z * b.z + b.w * b.w;
            pr  += a.x * b.x + a.y * b.y + a.z * b.z + a.w * b.w;
        }
        nt_ += __shfl_xor(nt_, 16, 64); ni_ += __shfl_xor(ni_, 16, 64); pr += __shfl_xor(pr, 16, 64);
        nt_ += __shfl_xor(nt_, 32, 64); ni_ += __shfl_xor(ni_, 32, 64); pr += __shfl_xor(pr, 32, 64);
        if (lg == 0) {
            float denom = fmaxf(sqrtf(nt_), 1e-12f) * fmaxf(sqrtf(ni_), 1e-12f);
            out_pa[(row0 + r) * 8 + hd] = pr / denom;
        }
    }
}

__global__ __launch_bounds__(512, 4) void global_kernel(
    const float* __restrict__ text, const float* __restrict__ image,
    const unsigned short* __restrict__ gW1T, const float* __restrict__ gb1,
    const float* __restrict__ glng, const float* __restrict__ glnb,
    const float* __restrict__ gW2, const float* __restrict__ gb2,
    const float* __restrict__ aw, const float* __restrict__ pa,
    float* __restrict__ out_conflict)
{
    __shared__ __align__(1024) char gsm[79872];
    const int tid = threadIdx.x;
    const int w = tid >> 6, lane = tid & 63, lg = lane >> 4, lc = lane & 15;
    const size_t row0 = (size_t)blockIdx.x * 64;
    const char* gWb = (const char*)gW1T;
    float* sStat = (float*)(gsm + 73728);
    float* sDot  = (float*)(gsm + 77824);

    const int r = tid >> 3, c4 = tid & 7;
    const float* arow_t = text + (row0 + r) * 512 + 4 * c4;
    const float* arow_i = image + (row0 + r) * 512 + 4 * c4;
    const int dstoffA = (c4 >> 1) * 1024 + r * 16 + (c4 & 1) * 8;

    float4 fv;
#define LOAD_FV(s_) do { fv = *(const float4*)(((s_) < 16 ? arow_t + (s_) * 32 : arow_i + ((s_) - 16) * 32)); } while (0)
#define WRITE_A(buf_) do { uint2 p_; p_.x = pk2(fv.x, fv.y); p_.y = pk2(fv.z, fv.w); *(uint2*)((buf_) + dstoffA) = p_; } while (0)
#define STAGE_B(buf_, s_) do { \
    const char* s2_ = gWb + (size_t)(s_) * 32768 + w * 4096 + lane * 16; \
    char* d2_ = (buf_) + w * 4096; \
    glds16(s2_, d2_); glds16(s2_ + 1024, d2_ + 1024); \
    glds16(s2_ + 2048, d2_ + 2048); glds16(s2_ + 3072, d2_ + 3072); } while (0)

    LOAD_FV(0);
    STAGE_B(gsm + 8192, 0);
    WRITE_A(gsm);
    LOAD_FV(1);
    __syncthreads();

    f32x4 acc[4][4];
    #pragma unroll
    for (int rt = 0; rt < 4; ++rt)
        #pragma unroll
        for (int nt = 0; nt < 4; ++nt) acc[rt][nt] = (f32x4){0.f, 0.f, 0.f, 0.f};

    #pragma unroll 2
    for (int s = 0; s < 32; ++s) {
        const int cur = s & 1;
        char* bufAc = gsm + cur * 4096;
        char* bufBc = gsm + 8192 + cur * 32768;
        if (s < 31) {
            WRITE_A(gsm + (cur ^ 1) * 4096);
            STAGE_B(gsm + 8192 + (cur ^ 1) * 32768, s + 1);
        }
        if (s < 30) LOAD_FV(s + 2);

        short8v af[4];
        #pragma unroll
        for (int rt = 0; rt < 4; ++rt)
            af[rt] = *(const short8v*)(bufAc + lg * 1024 + (16 * rt + lc) * 16);
        #pragma unroll
        for (int nt = 0; nt < 4; ++nt) {
            short8v bfv = *(const short8v*)(bufBc + (4 * w + nt) * 1024 + lane * 16);
            #pragma unroll
            for (int rt = 0; rt < 4; ++rt)
                acc[rt][nt] = __builtin_amdgcn_mfma_f32_16x16x32_bf16(af[rt], bfv, acc[rt][nt], 0, 0, 0);
        }
        __syncthreads();
    }
#undef LOAD_FV
#undef WRITE_A
#undef STAGE_B

    #pragma unroll
    for (int nt = 0; nt < 4; ++nt) {
        float bv = gb1[64 * w + 16 * nt + lc];
        #pragma unroll
        for (int rt = 0; rt < 4; ++rt)
            #pragma unroll
            for (int reg = 0; reg < 4; ++reg) acc[rt][nt][reg] += bv;
    }
    #pragma unroll
    for (int rt = 0; rt < 4; ++rt)
        #pragma unroll
        for (int reg = 0; reg < 4; ++reg) {
            float s1 = 0.f, s2 = 0.f;
            #pragma unroll
            for (int nt = 0; nt < 4; ++nt) { float v = acc[rt][nt][reg]; s1 += v; s2 += v * v; }
            #pragma unroll
            for (int off = 1; off < 16; off <<= 1) {
                s1 += __shfl_xor(s1, off, 64);
                s2 += __shfl_xor(s2, off, 64);
            }
            if (lc == 0) {
                int rr = 16 * rt + 4 * lg + reg;
                sStat[(w * 64 + rr) * 2 + 0] = s1;
                sStat[(w * 64 + rr) * 2 + 1] = s2;
            }
        }
    __syncthreads();

    float mug[4][4], rsg[4][4];
    #pragma unroll
    for (int rt = 0; rt < 4; ++rt)
        #pragma unroll
        for (int reg = 0; reg < 4; ++reg) {
            int rr = 16 * rt + 4 * lg + reg;
            float s1 = 0.f, s2 = 0.f;
            #pragma unroll
            for (int ww = 0; ww < 8; ++ww) {
                s1 += sStat[(ww * 64 + rr) * 2 + 0];
                s2 += sStat[(ww * 64 + rr) * 2 + 1];
            }
            float m = s1 * (1.0f / 512.0f);
            float var = s2 * (1.0f / 512.0f) - m * m;
            mug[rt][reg] = m;
            rsg[rt][reg] = rsqrtf(var + 1e-5f);
        }

    float dp[4][4];
    #pragma unroll
    for (int rt = 0; rt < 4; ++rt)
        #pragma unroll
        for (int reg = 0; reg < 4; ++reg) dp[rt][reg] = 0.f;
    #pragma unroll
    for (int nt = 0; nt < 4; ++nt) {
        int col = 64 * w + 16 * nt + lc;
        float gv = glng[col], bv = glnb[col], wv = gW2[col];
        #pragma unroll
        for (int rt = 0; rt < 4; ++rt)
            #pragma unroll
            for (int reg = 0; reg < 4; ++reg) {
                float v = (acc[rt][nt][reg] - mug[rt][reg]) * rsg[rt][reg] * gv + bv;
                dp[rt][reg] += gelu_exact(v) * wv;
            }
    }
    #pragma unroll
    for (int rt = 0; rt < 4; ++rt)
        #pragma unroll
        for (int reg = 0; reg < 4; ++reg) {
            float d = dp[rt][reg];
            #pragma unroll
            for (int off = 1; off < 16; off <<= 1) d += __shfl_xor(d, off, 64);
            if (lc == 0) sDot[w * 64 + 16 * rt + 4 * lg + reg] = d;
        }
    __syncthreads();

    if (tid < 64) {
        int rr = tid;
        float z = gb2[0];
        #pragma unroll
        for (int ww = 0; ww < 8; ++ww) z += sDot[ww * 64 + rr];
        float gs = 1.0f / (1.0f + expf(-z));
        float wv[8], mx = -1e30f;
        #pragma unroll
        for (int i = 0; i < 8; ++i) { wv[i] = aw[i]; mx = fmaxf(mx, wv[i]); }
        float sum = 0.f;
        #pragma unroll
        for (int i = 0; i < 8; ++i) { wv[i] = expf(wv[i] - mx); sum += wv[i]; }
        float inv = 1.0f / sum;
        const float* par = pa + (row0 + rr) * 8;
        float wsim = 0.f;
        #pragma unroll
        for (int i = 0; i < 8; ++i) wsim += par[i] * wv[i] * inv;
        float conf = 1.0f - (0.7f * wsim + 0.3f * gs);
        out_conflict[row0 + rr] = fminf(fmaxf(conf, 0.0f), 1.0f);
    }
}

extern "C" void kernel_launch(void* const* d_in, const int* in_sizes, int n_in,
                              void* d_out, int out_size, void* d_ws, size_t ws_size,
                              hipStream_t stream) {
    const float* text  = (const float*)d_in[0];
    const float* image = (const float*)d_in[1];
    const float* W1    = (const float*)d_in[2];
    const float* b1    = (const float*)d_in[3];
    const float* ln1g  = (const float*)d_in[4];
    const float* ln1b  = (const float*)d_in[5];
    const float* W2    = (const float*)d_in[6];
    const float* b2    = (const float*)d_in[7];
    const float* aw    = (const float*)d_in[8];
    const float* gW1   = (const float*)d_in[9];
    const float* gb1   = (const float*)d_in[10];
    const float* glng  = (const float*)d_in[11];
    const float* glnb  = (const float*)d_in[12];
    const float* gW2   = (const float*)d_in[13];
    const float* gb2   = (const float*)d_in[14];

    float* out = (float*)d_out;
    float* out_pa = out + B_TOTAL;

    const size_t NEED = 67108864ull * 2 + 1048576 + 131072 + 1048576;
    if (ws_size >= NEED) {
        unsigned short* textW  = (unsigned short*)d_ws;
        unsigned short* imageW = (unsigned short*)((char*)d_ws + 67108864);
        unsigned short* W1L    = (unsigned short*)((char*)d_ws + 134217728);
        unsigned short* W2T    = (unsigned short*)((char*)d_ws + 135266304);
        unsigned short* gW1T   = (unsigned short*)((char*)d_ws + 135397376);

        convert_weights<<<544, 256, 0, stream>>>(W1, W2, gW1, W1L, W2T, gW1T);
        convert_inputs<<<32768, 256, 0, stream>>>(text, image, textW, imageW);
        head_pre<<<8192, 512, 0, stream>>>(textW, imageW, W1L, b1, ln1g, ln1b, W2T, b2, out_pa);
        global_pre<<<1024, 512, 0, stream>>>(textW, imageW, gW1T, gb1, glng, glnb, gW2, gb2,
                                             aw, out_pa, out);
    } else {
        unsigned short* W1L  = (unsigned short*)d_ws;
        unsigned short* W2T  = (unsigned short*)((char*)d_ws + 1048576);
        unsigned short* gW1T = (unsigned short*)((char*)d_ws + 1179648);

        convert_weights<<<544, 256, 0, stream>>>(W1, W2, gW1, W1L, W2T, gW1T);
        head_kernel<<<8192, 512, 0, stream>>>(text, image, W1L, b1, ln1g, ln1b, W2T, b2, out_pa);
        global_kernel<<<1024, 512, 0, stream>>>(text, image, gW1T, gb1, glng, glnb, gW2, gb2,
                                                aw, out_pa, out);
    }
}

// Round 13
// 664.058 us; speedup vs baseline: 2.4293x; 1.0629x over previous
//
#include <hip/hip_runtime.h>
#include <hip/hip_bf16.h>
#include <math.h>

#define B_TOTAL 65536

typedef __attribute__((ext_vector_type(8))) short short8v;   // 8 bf16 (4 VGPRs)
typedef __attribute__((ext_vector_type(4))) float f32x4;

__device__ __forceinline__ unsigned short f2bf(float f) {
    union { float f; unsigned u; } v; v.f = f;
    unsigned r = v.u + 0x7FFF + ((v.u >> 16) & 1);   // RNE
    return (unsigned short)(r >> 16);
}

__device__ __forceinline__ unsigned pk2(float a, float b) {
    float2 t; t.x = a; t.y = b;
    __hip_bfloat162 h = __float22bfloat162_rn(t);    // v_cvt_pk_bf16_f32
    union { __hip_bfloat162 h; unsigned u; } c; c.h = h;
    return c.u;
}

// Abramowitz-Stegun 7.1.26 with v_rcp_f32 (rcp rel-err ~1e-7 << formula err 1.5e-7)
__device__ __forceinline__ float erf_fast(float x) {
    float ax = fabsf(x);
    float t = __builtin_amdgcn_rcpf(fmaf(0.3275911f, ax, 1.0f));
    float y = t * (0.254829592f + t * (-0.284496736f + t * (1.421413741f
              + t * (-1.453152027f + t * 1.061405429f))));
    float r = 1.0f - y * __expf(-ax * ax);
    return copysignf(r, x);
}

__device__ __forceinline__ float gelu_exact(float x) {
    return 0.5f * x * (1.0f + erf_fast(x * 0.70710678118654752440f));
}

__device__ __forceinline__ void glds16(const void* g, void* l) {
    __builtin_amdgcn_global_load_lds(
        (const __attribute__((address_space(1))) unsigned int*)g,
        (__attribute__((address_space(3))) unsigned int*)l, 16, 0, 0);
}

// ============== converter: weights -> fragment-linear bf16 in ws ==============
// W1L: [hd(8)][step(16)][nt(8)][lane(64)][j(8)]
//      elem j = W1[hd][step*32+8*(l>>4)+j][16*nt+(l&15)]         (8KB per 32-k step)
// W2T: [hd(8)][kb(4)][nt2(4)][lane][j]  elem j = W2[hd][32kb+8(l>>4)+j][16nt2+(l&15)]
// gW1T:[s(32)][nt(32)][lane][j]         elem j = gW1[32s+8(l>>4)+j][16nt+(l&15)]
__global__ void convert_weights(const float* __restrict__ W1, const float* __restrict__ W2,
                                const float* __restrict__ gW1,
                                unsigned short* __restrict__ W1L, unsigned short* __restrict__ W2T,
                                unsigned short* __restrict__ gW1T)
{
    int t = blockIdx.x * 256 + threadIdx.x;
    if (t < 65536) {
        int l = t & 63, nt = (t >> 6) & 7, step = (t >> 9) & 15, hd = t >> 13;
        int n = nt * 16 + (l & 15);
        int k = step * 32 + 8 * (l >> 4);
        const float* s = W1 + (size_t)hd * 65536 + (size_t)k * 128 + n;
        short8v o;
        #pragma unroll
        for (int j = 0; j < 8; ++j) o[j] = (short)f2bf(s[(size_t)j * 128]);
        *(short8v*)(W1L + (size_t)t * 8) = o;
    } else if (t < 65536 + 8192) {
        int u = t - 65536;
        int l = u & 63, nt = (u >> 6) & 3, kb = (u >> 8) & 3, hd = u >> 10;
        int m = 16 * nt + (l & 15);
        int k = 32 * kb + 8 * (l >> 4);
        const float* s = W2 + (size_t)hd * 8192 + (size_t)k * 64 + m;
        short8v o;
        #pragma unroll
        for (int j = 0; j < 8; ++j) o[j] = (short)f2bf(s[(size_t)j * 64]);
        *(short8v*)(W2T + (size_t)u * 8) = o;
    } else if (t < 65536 + 8192 + 65536) {
        int u = t - 73728;
        int l = u & 63, nt = (u >> 6) & 31, s0 = u >> 11;
        int n = 16 * nt + (l & 15);
        int k = 32 * s0 + 8 * (l >> 4);
        const float* s = gW1 + (size_t)k * 512 + n;
        short8v o;
        #pragma unroll
        for (int j = 0; j < 8; ++j) o[j] = (short)f2bf(s[(size_t)j * 512]);
        *(short8v*)(gW1T + (size_t)u * 8) = o;
    }
}

// ============== converter: inputs -> bf16 pre-swizzled, LDS-staged ==============
// ws image (16B units): idx = rb*4096 + s*512 + oct*64 + lane; content = input row
// rb*64+(lane^oct), cols s*64+oct*8..+8. R12 version gathered rows per-lane
// (64 x 32B scattered reads); this version: coalesced reads (256B segments) ->
// bf16 -> swizzled 8KB LDS image -> fully linear writes (2KB/wave).
__global__ __launch_bounds__(256) void convert_inputs(
    const float* __restrict__ text, const float* __restrict__ image,
    unsigned short* __restrict__ textW, unsigned short* __restrict__ imageW)
{
    __shared__ __align__(16) char cbuf[8192];

    const int t = threadIdx.x;
    const int tensor = blockIdx.x >> 10;
    const int rb = blockIdx.x & 1023;
    const float* in = tensor ? image : text;
    unsigned short* outp = tensor ? imageW : textW;

    const int row = t >> 2, cq = t & 3;

    for (int s = 0; s < 8; ++s) {
        // read 16 cols (64B contiguous/thread; lanes 0-3 = 256B segment)
        const float* src = in + ((size_t)rb * 64 + row) * 512 + s * 64 + cq * 16;
        float4 v0 = ((const float4*)src)[0];
        float4 v1 = ((const float4*)src)[1];
        float4 v2 = ((const float4*)src)[2];
        float4 v3 = ((const float4*)src)[3];
        // two 8-col octs -> swizzled LDS slots
        {
            int oct = 2 * cq;
            uint4 p; p.x = pk2(v0.x, v0.y); p.y = pk2(v0.z, v0.w);
            p.z = pk2(v1.x, v1.y); p.w = pk2(v1.z, v1.w);
            *(uint4*)(cbuf + oct * 1024 + ((row * 16) ^ (oct << 4))) = p;
        }
        {
            int oct = 2 * cq + 1;
            uint4 p; p.x = pk2(v2.x, v2.y); p.y = pk2(v2.z, v2.w);
            p.z = pk2(v3.x, v3.y); p.w = pk2(v3.z, v3.w);
            *(uint4*)(cbuf + oct * 1024 + ((row * 16) ^ (oct << 4))) = p;
        }
        __syncthreads();
        // linear write-out: 32B/thread, wave = 2KB contiguous
        unsigned short* dst = outp + ((size_t)rb * 4096 + s * 512 + t * 2) * 8;
        *(uint4*)dst = *(uint4*)(cbuf + t * 32);
        *(uint4*)(dst + 8) = *(uint4*)(cbuf + t * 32 + 16);
        __syncthreads();
    }
}

// ============== kernel H: per-head path -> per_aspect ==============
// 8192 blocks x 512 threads. XCD swizzle: xr=bid&7, q=bid>>3, hd=q&7, rb=((q>>3)<<3)|xr.
// 64 batch rows/block (A-rows 0..63 text, 64..127 image). GEMM1 128x128, BK=64, 8 steps.
// A AND B staged via global_load_lds (no staging VALU).
__global__ __launch_bounds__(512, 4) void head_pre(
    const unsigned short* __restrict__ textW, const unsigned short* __restrict__ imageW,
    const unsigned short* __restrict__ W1L, const float* __restrict__ b1,
    const float* __restrict__ ln1g, const float* __restrict__ ln1b,
    const unsigned short* __restrict__ W2T, const float* __restrict__ b2,
    float* __restrict__ out_pa)
{
    __shared__ __align__(1024) char smem[76800];
    // A0@0 (16K) | A1@16384 | B0@32768 (16K) | B1@49152 | sS@65536 (2K) | hB@67584 (8x1152)
    // epilogue: o2 [128][64] f32 (32KB) aliases @0..32768

    const int tid = threadIdx.x;
    const int w = tid >> 6, lane = tid & 63, lg = lane >> 4, lc = lane & 15;
    const int wr = w >> 1, wc = w & 1;
    const int bid = blockIdx.x;
    const int xr = bid & 7;
    const int q = bid >> 3;
    const int hd = q & 7;
    const int rb = ((q >> 3) << 3) | xr;
    const size_t row0 = (size_t)rb * 64;

    const char* W1base = (const char*)W1L + (size_t)hd * 131072;
    const char* tWb = (const char*)textW + (size_t)rb * 65536 + w * 1024 + lane * 16;
    const char* iWb = (const char*)imageW + (size_t)rb * 65536 + w * 1024 + lane * 16;
    float* sS = (float*)(smem + 65536);
    unsigned short* hb = (unsigned short*)(smem + 67584 + w * 1152);

#define STAGE_A(buf_, s_) do { \
    glds16(tWb + (s_) * 8192, (buf_) + w * 2048); \
    glds16(iWb + (s_) * 8192, (buf_) + w * 2048 + 1024); } while (0)
#define STAGE_B(buf_, s_) do { \
    const char* bs_ = W1base + (s_) * 16384 + w * 2048 + lane * 16; \
    glds16(bs_, (buf_) + w * 2048); \
    glds16(bs_ + 1024, (buf_) + w * 2048 + 1024); } while (0)

    // ---- prologue ----
    STAGE_A(smem, 0);
    STAGE_B(smem + 32768, 0);
    __syncthreads();

    f32x4 acc[2][4];
    #pragma unroll
    for (int rt = 0; rt < 2; ++rt)
        #pragma unroll
        for (int nt = 0; nt < 4; ++nt) acc[rt][nt] = (f32x4){0.f, 0.f, 0.f, 0.f};

    // ---- GEMM1 K-loop: 8 steps of BK=64 ----
    #pragma unroll
    for (int s = 0; s < 8; ++s) {
        const int cur = s & 1;
        char* bufAc = smem + cur * 16384;
        char* bufBc = smem + 32768 + cur * 16384;
        if (s < 7) {
            STAGE_A(smem + (cur ^ 1) * 16384, s + 1);
            STAGE_B(smem + 32768 + (cur ^ 1) * 16384, s + 1);
        }
        #pragma unroll
        for (int kk = 0; kk < 2; ++kk) {
            const int o = kk * 4 + lg;
            short8v afv[2];
            #pragma unroll
            for (int rt = 0; rt < 2; ++rt) {
                const int row = 32 * wr + 16 * rt + lc;
                afv[rt] = *(const short8v*)(bufAc + o * 2048 + ((row * 16) ^ (o << 4)));
            }
            #pragma unroll
            for (int nt = 0; nt < 4; ++nt) {
                short8v bfv = *(const short8v*)(bufBc + kk * 8192 + (4 * wc + nt) * 1024 + lane * 16);
                acc[0][nt] = __builtin_amdgcn_mfma_f32_16x16x32_bf16(afv[0], bfv, acc[0][nt], 0, 0, 0);
                acc[1][nt] = __builtin_amdgcn_mfma_f32_16x16x32_bf16(afv[1], bfv, acc[1][nt], 0, 0, 0);
            }
        }
        __syncthreads();
    }
#undef STAGE_A
#undef STAGE_B

    // ---- + b1, row-stat partials ----
    #pragma unroll
    for (int nt = 0; nt < 4; ++nt) {
        float bv = b1[hd * 128 + 64 * wc + 16 * nt + lc];
        #pragma unroll
        for (int rt = 0; rt < 2; ++rt)
            #pragma unroll
            for (int reg = 0; reg < 4; ++reg) acc[rt][nt][reg] += bv;
    }
    #pragma unroll
    for (int rt = 0; rt < 2; ++rt)
        #pragma unroll
        for (int reg = 0; reg < 4; ++reg) {
            float s1 = 0.f, s2 = 0.f;
            #pragma unroll
            for (int nt = 0; nt < 4; ++nt) { float v = acc[rt][nt][reg]; s1 += v; s2 += v * v; }
            #pragma unroll
            for (int off = 1; off < 16; off <<= 1) {
                s1 += __shfl_xor(s1, off, 64);
                s2 += __shfl_xor(s2, off, 64);
            }
            if (lc == 0) {
                int row = 32 * wr + 16 * rt + 4 * lg + reg;
                sS[(wc * 128 + row) * 2 + 0] = s1;
                sS[(wc * 128 + row) * 2 + 1] = s2;
            }
        }
    __syncthreads();

    // ---- LN + GELU in-register ----
    float mu[2][4], rsig[2][4];
    #pragma unroll
    for (int rt = 0; rt < 2; ++rt)
        #pragma unroll
        for (int reg = 0; reg < 4; ++reg) {
            int row = 32 * wr + 16 * rt + 4 * lg + reg;
            float s1 = sS[row * 2 + 0] + sS[(128 + row) * 2 + 0];
            float s2 = sS[row * 2 + 1] + sS[(128 + row) * 2 + 1];
            float m = s1 * (1.0f / 128.0f);
            float var = s2 * (1.0f / 128.0f) - m * m;
            mu[rt][reg] = m;
            rsig[rt][reg] = rsqrtf(var + 1e-5f);
        }
    #pragma unroll
    for (int nt = 0; nt < 4; ++nt) {
        int col = 64 * wc + 16 * nt + lc;
        float gv = ln1g[hd * 128 + col];
        float bv = ln1b[hd * 128 + col];
        #pragma unroll
        for (int rt = 0; rt < 2; ++rt)
            #pragma unroll
            for (int reg = 0; reg < 4; ++reg) {
                float v = (acc[rt][nt][reg] - mu[rt][reg]) * rsig[rt][reg] * gv + bv;
                acc[rt][nt][reg] = gelu_exact(v);
            }
    }

    // ---- GEMM2 per-wave half-K + 2-pass o2 accumulate ----
    const char* W2b = (const char*)W2T + (size_t)hd * 16384;
    #pragma unroll
    for (int rt = 0; rt < 2; ++rt) {
        f32x4 acc2[4];
        #pragma unroll
        for (int nt2 = 0; nt2 < 4; ++nt2) acc2[nt2] = (f32x4){0.f, 0.f, 0.f, 0.f};

        #pragma unroll
        for (int kk2 = 0; kk2 < 2; ++kk2) {
            #pragma unroll
            for (int ntl = 0; ntl < 2; ++ntl) {
                const int nt = 2 * kk2 + ntl;
                const int kk = 16 * ntl + lc;
                #pragma unroll
                for (int reg = 0; reg < 4; ++reg)
                    hb[(4 * lg + reg) * 36 + kk] = f2bf(acc[rt][nt][reg]);
            }
            short8v af2 = *(const short8v*)((const char*)hb + lc * 72 + 16 * lg);
            const char* wb = W2b + (2 * wc + kk2) * 4096 + lane * 16;
            #pragma unroll
            for (int nt2 = 0; nt2 < 4; ++nt2) {
                short8v w2f = *(const short8v*)(wb + nt2 * 1024);
                acc2[nt2] = __builtin_amdgcn_mfma_f32_16x16x32_bf16(af2, w2f, acc2[nt2], 0, 0, 0);
            }
        }
        if (wc == 0) {
            #pragma unroll
            for (int nt2 = 0; nt2 < 4; ++nt2) {
                float bv = b2[hd * 64 + 16 * nt2 + lc];
                #pragma unroll
                for (int reg = 0; reg < 4; ++reg) {
                    int row = 32 * wr + 16 * rt + 4 * lg + reg;
                    int col = 16 * nt2 + lc;
                    *(float*)(smem + row * 256 + ((col * 4) ^ ((row & 7) << 4))) = acc2[nt2][reg] + bv;
                }
            }
        }
        __syncthreads();
        if (wc == 1) {
            #pragma unroll
            for (int nt2 = 0; nt2 < 4; ++nt2)
                #pragma unroll
                for (int reg = 0; reg < 4; ++reg) {
                    int row = 32 * wr + 16 * rt + 4 * lg + reg;
                    int col = 16 * nt2 + lc;
                    float* p = (float*)(smem + row * 256 + ((col * 4) ^ ((row & 7) << 4)));
                    *p += acc2[nt2][reg];
                }
        }
        __syncthreads();
    }

    // ---- cosine ----
    if (w < 4) {
        int r = 16 * w + lc;
        int sw = (r & 7) << 4;
        float nt_ = 0.f, ni_ = 0.f, pr = 0.f;
        #pragma unroll
        for (int q2 = 0; q2 < 4; ++q2) {
            int c16 = 2 * lg + (q2 & 1) + (q2 >> 1) * 8;
            float4 a = *(const float4*)(smem + r * 256 + ((c16 * 16) ^ sw));
            float4 b = *(const float4*)(smem + (r + 64) * 256 + ((c16 * 16) ^ sw));
            nt_ += a.x * a.x + a.y * a.y + a.z * a.z + a.w * a.w;
            ni_ += b.x * b.x + b.y * b.y + b.z * b.z + b.w * b.w;
            pr  += a.x * b.x + a.y * b.y + a.z * b.z + a.w * b.w;
        }
        nt_ += __shfl_xor(nt_, 16, 64); ni_ += __shfl_xor(ni_, 16, 64); pr += __shfl_xor(pr, 16, 64);
        nt_ += __shfl_xor(nt_, 32, 64); ni_ += __shfl_xor(ni_, 32, 64); pr += __shfl_xor(pr, 32, 64);
        if (lg == 0) {
            float denom = fmaxf(sqrtf(nt_), 1e-12f) * fmaxf(sqrtf(ni_), 1e-12f);
            out_pa[(row0 + r) * 8 + hd] = pr / denom;
        }
    }
}

// ============== kernel G: global path -> conflict ==============
// 1024 blocks x 512 threads. 64 rows x 512 cols; 32 steps of BK=32 (st<16 text).
__global__ __launch_bounds__(512, 4) void global_pre(
    const unsigned short* __restrict__ textW, const unsigned short* __restrict__ imageW,
    const unsigned short* __restrict__ gW1T, const float* __restrict__ gb1,
    const float* __restrict__ glng, const float* __restrict__ glnb,
    const float* __restrict__ gW2, const float* __restrict__ gb2,
    const float* __restrict__ aw, const float* __restrict__ pa,
    float* __restrict__ out_conflict)
{
    __shared__ __align__(1024) char gsm[79872];
    // A0@0 (4K) | A1@4096 | B0@8192 (32K) | B1@40960 | sStat@73728 (4K) | sDot@77824 (2K)

    const int tid = threadIdx.x;
    const int w = tid >> 6, lane = tid & 63, lg = lane >> 4, lc = lane & 15;
    const int rb = blockIdx.x;
    const size_t row0 = (size_t)rb * 64;
    const char* gWb = (const char*)gW1T;
    const char* tWb = (const char*)textW + (size_t)rb * 65536;
    const char* iWb = (const char*)imageW + (size_t)rb * 65536;
    float* sStat = (float*)(gsm + 73728);
    float* sDot  = (float*)(gsm + 77824);

#define STAGE(p_, st_) do { \
    char* bb_ = gsm + 8192 + (p_) * 32768 + w * 4096; \
    const char* bs_ = gWb + (size_t)(st_) * 32768 + w * 4096 + lane * 16; \
    glds16(bs_, bb_); glds16(bs_ + 1024, bb_ + 1024); \
    glds16(bs_ + 2048, bb_ + 2048); glds16(bs_ + 3072, bb_ + 3072); \
    if (w < 4) { \
        int stx_ = ((st_) < 16) ? (st_) : ((st_) - 16); \
        const char* as_ = (((st_) < 16) ? tWb : iWb) \
                        + (stx_ >> 1) * 8192 + ((stx_ & 1) * 4 + w) * 1024 + lane * 16; \
        glds16(as_, gsm + (p_) * 4096 + w * 1024); \
    } } while (0)

    STAGE(0, 0);
    __syncthreads();

    f32x4 acc[4][4];
    #pragma unroll
    for (int rt = 0; rt < 4; ++rt)
        #pragma unroll
        for (int nt = 0; nt < 4; ++nt) acc[rt][nt] = (f32x4){0.f, 0.f, 0.f, 0.f};

    #pragma unroll 2
    for (int st = 0; st < 32; ++st) {
        const int cur = st & 1;
        char* bufAc = gsm + cur * 4096;
        char* bufBc = gsm + 8192 + cur * 32768;
        if (st < 31) STAGE(cur ^ 1, st + 1);

        const int xk = (st & 1) << 6;
        short8v af[4];
        #pragma unroll
        for (int rt = 0; rt < 4; ++rt) {
            const int row = 16 * rt + lc;
            af[rt] = *(const short8v*)(bufAc + lg * 1024 + ((row * 16) ^ (lg << 4) ^ xk));
        }
        #pragma unroll
        for (int nt = 0; nt < 4; ++nt) {
            short8v bfv = *(const short8v*)(bufBc + (4 * w + nt) * 1024 + lane * 16);
            #pragma unroll
            for (int rt = 0; rt < 4; ++rt)
                acc[rt][nt] = __builtin_amdgcn_mfma_f32_16x16x32_bf16(af[rt], bfv, acc[rt][nt], 0, 0, 0);
        }
        __syncthreads();
    }
#undef STAGE

    // ---- + gb1, LN stat partials ----
    #pragma unroll
    for (int nt = 0; nt < 4; ++nt) {
        float bv = gb1[64 * w + 16 * nt + lc];
        #pragma unroll
        for (int rt = 0; rt < 4; ++rt)
            #pragma unroll
            for (int reg = 0; reg < 4; ++reg) acc[rt][nt][reg] += bv;
    }
    #pragma unroll
    for (int rt = 0; rt < 4; ++rt)
        #pragma unroll
        for (int reg = 0; reg < 4; ++reg) {
            float s1 = 0.f, s2 = 0.f;
            #pragma unroll
            for (int nt = 0; nt < 4; ++nt) { float v = acc[rt][nt][reg]; s1 += v; s2 += v * v; }
            #pragma unroll
            for (int off = 1; off < 16; off <<= 1) {
                s1 += __shfl_xor(s1, off, 64);
                s2 += __shfl_xor(s2, off, 64);
            }
            if (lc == 0) {
                int rr = 16 * rt + 4 * lg + reg;
                sStat[(w * 64 + rr) * 2 + 0] = s1;
                sStat[(w * 64 + rr) * 2 + 1] = s2;
            }
        }
    __syncthreads();

    float mug[4][4], rsg[4][4];
    #pragma unroll
    for (int rt = 0; rt < 4; ++rt)
        #pragma unroll
        for (int reg = 0; reg < 4; ++reg) {
            int rr = 16 * rt + 4 * lg + reg;
            float s1 = 0.f, s2 = 0.f;
            #pragma unroll
            for (int ww = 0; ww < 8; ++ww) {
                s1 += sStat[(ww * 64 + rr) * 2 + 0];
                s2 += sStat[(ww * 64 + rr) * 2 + 1];
            }
            float m = s1 * (1.0f / 512.0f);
            float var = s2 * (1.0f / 512.0f) - m * m;
            mug[rt][reg] = m;
            rsg[rt][reg] = rsqrtf(var + 1e-5f);
        }

    // ---- LN + GELU + dot(gW2) partials ----
    float dp[4][4];
    #pragma unroll
    for (int rt = 0; rt < 4; ++rt)
        #pragma unroll
        for (int reg = 0; reg < 4; ++reg) dp[rt][reg] = 0.f;
    #pragma unroll
    for (int nt = 0; nt < 4; ++nt) {
        int col = 64 * w + 16 * nt + lc;
        float gv = glng[col], bv = glnb[col], wv = gW2[col];
        #pragma unroll
        for (int rt = 0; rt < 4; ++rt)
            #pragma unroll
            for (int reg = 0; reg < 4; ++reg) {
                float v = (acc[rt][nt][reg] - mug[rt][reg]) * rsg[rt][reg] * gv + bv;
                dp[rt][reg] += gelu_exact(v) * wv;
            }
    }
    #pragma unroll
    for (int rt = 0; rt < 4; ++rt)
        #pragma unroll
        for (int reg = 0; reg < 4; ++reg) {
            float d = dp[rt][reg];
            #pragma unroll
            for (int off = 1; off < 16; off <<= 1) d += __shfl_xor(d, off, 64);
            if (lc == 0) sDot[w * 64 + 16 * rt + 4 * lg + reg] = d;
        }
    __syncthreads();

    if (tid < 64) {
        int rr = tid;
        float z = gb2[0];
        #pragma unroll
        for (int ww = 0; ww < 8; ++ww) z += sDot[ww * 64 + rr];
        float gs = 1.0f / (1.0f + expf(-z));
        float wv[8], mx = -1e30f;
        #pragma unroll
        for (int i = 0; i < 8; ++i) { wv[i] = aw[i]; mx = fmaxf(mx, wv[i]); }
        float sum = 0.f;
        #pragma unroll
        for (int i = 0; i < 8; ++i) { wv[i] = expf(wv[i] - mx); sum += wv[i]; }
        float inv = 1.0f / sum;
        const float* par = pa + (row0 + rr) * 8;
        float wsim = 0.f;
        #pragma unroll
        for (int i = 0; i < 8; ++i) wsim += par[i] * wv[i] * inv;
        float conf = 1.0f - (0.7f * wsim + 0.3f * gs);
        out_conflict[row0 + rr] = fminf(fmaxf(conf, 0.0f), 1.0f);
    }
}

extern "C" void kernel_launch(void* const* d_in, const int* in_sizes, int n_in,
                              void* d_out, int out_size, void* d_ws, size_t ws_size,
                              hipStream_t stream) {
    const float* text  = (const float*)d_in[0];
    const float* image = (const float*)d_in[1];
    const float* W1    = (const float*)d_in[2];
    const float* b1    = (const float*)d_in[3];
    const float* ln1g  = (const float*)d_in[4];
    const float* ln1b  = (const float*)d_in[5];
    const float* W2    = (const float*)d_in[6];
    const float* b2    = (const float*)d_in[7];
    const float* aw    = (const float*)d_in[8];
    const float* gW1   = (const float*)d_in[9];
    const float* gb1   = (const float*)d_in[10];
    const float* glng  = (const float*)d_in[11];
    const float* glnb  = (const float*)d_in[12];
    const float* gW2   = (const float*)d_in[13];
    const float* gb2   = (const float*)d_in[14];

    float* out = (float*)d_out;
    float* out_pa = out + B_TOTAL;

    unsigned short* textW  = (unsigned short*)d_ws;                           // 64MB
    unsigned short* imageW = (unsigned short*)((char*)d_ws + 67108864);       // 64MB
    unsigned short* W1L    = (unsigned short*)((char*)d_ws + 134217728);      // 1MB
    unsigned short* W2T    = (unsigned short*)((char*)d_ws + 135266304);      // 128KB
    unsigned short* gW1T   = (unsigned short*)((char*)d_ws + 135397376);      // 1MB

    convert_weights<<<544, 256, 0, stream>>>(W1, W2, gW1, W1L, W2T, gW1T);
    convert_inputs<<<2048, 256, 0, stream>>>(text, image, textW, imageW);
    head_pre<<<8192, 512, 0, stream>>>(textW, imageW, W1L, b1, ln1g, ln1b, W2T, b2, out_pa);
    global_pre<<<1024, 512, 0, stream>>>(textW, imageW, gW1T, gb1, glng, glnb, gW2, gb2,
                                         aw, out_pa, out);
}

// Round 14
// 635.249 us; speedup vs baseline: 2.5395x; 1.0454x over previous
//
#include <hip/hip_runtime.h>
#include <hip/hip_bf16.h>
#include <math.h>

#define B_TOTAL 65536

typedef __attribute__((ext_vector_type(8))) short short8v;   // 8 bf16 (4 VGPRs)
typedef __attribute__((ext_vector_type(4))) float f32x4;

__device__ __forceinline__ unsigned short f2bf(float f) {
    union { float f; unsigned u; } v; v.f = f;
    unsigned r = v.u + 0x7FFF + ((v.u >> 16) & 1);   // RNE
    return (unsigned short)(r >> 16);
}

__device__ __forceinline__ unsigned pk2(float a, float b) {
    float2 t; t.x = a; t.y = b;
    __hip_bfloat162 h = __float22bfloat162_rn(t);    // v_cvt_pk_bf16_f32
    union { __hip_bfloat162 h; unsigned u; } c; c.h = h;
    return c.u;
}

// Abramowitz-Stegun 7.1.26 with v_rcp_f32 (rcp rel-err ~1e-7 << formula err 1.5e-7)
__device__ __forceinline__ float erf_fast(float x) {
    float ax = fabsf(x);
    float t = __builtin_amdgcn_rcpf(fmaf(0.3275911f, ax, 1.0f));
    float y = t * (0.254829592f + t * (-0.284496736f + t * (1.421413741f
              + t * (-1.453152027f + t * 1.061405429f))));
    float r = 1.0f - y * __expf(-ax * ax);
    return copysignf(r, x);
}

__device__ __forceinline__ float gelu_exact(float x) {
    return 0.5f * x * (1.0f + erf_fast(x * 0.70710678118654752440f));
}

__device__ __forceinline__ void glds16(const void* g, void* l) {
    __builtin_amdgcn_global_load_lds(
        (const __attribute__((address_space(1))) unsigned int*)g,
        (__attribute__((address_space(3))) unsigned int*)l, 16, 0, 0);
}

// ============== converter: weights -> fragment-linear bf16 in ws ==============
__global__ void convert_weights(const float* __restrict__ W1, const float* __restrict__ W2,
                                const float* __restrict__ gW1,
                                unsigned short* __restrict__ W1L, unsigned short* __restrict__ W2T,
                                unsigned short* __restrict__ gW1T)
{
    int t = blockIdx.x * 256 + threadIdx.x;
    if (t < 65536) {
        int l = t & 63, nt = (t >> 6) & 7, step = (t >> 9) & 15, hd = t >> 13;
        int n = nt * 16 + (l & 15);
        int k = step * 32 + 8 * (l >> 4);
        const float* s = W1 + (size_t)hd * 65536 + (size_t)k * 128 + n;
        short8v o;
        #pragma unroll
        for (int j = 0; j < 8; ++j) o[j] = (short)f2bf(s[(size_t)j * 128]);
        *(short8v*)(W1L + (size_t)t * 8) = o;
    } else if (t < 65536 + 8192) {
        int u = t - 65536;
        int l = u & 63, nt = (u >> 6) & 3, kb = (u >> 8) & 3, hd = u >> 10;
        int m = 16 * nt + (l & 15);
        int k = 32 * kb + 8 * (l >> 4);
        const float* s = W2 + (size_t)hd * 8192 + (size_t)k * 64 + m;
        short8v o;
        #pragma unroll
        for (int j = 0; j < 8; ++j) o[j] = (short)f2bf(s[(size_t)j * 64]);
        *(short8v*)(W2T + (size_t)u * 8) = o;
    } else if (t < 65536 + 8192 + 65536) {
        int u = t - 73728;
        int l = u & 63, nt = (u >> 6) & 31, s0 = u >> 11;
        int n = 16 * nt + (l & 15);
        int k = 32 * s0 + 8 * (l >> 4);
        const float* s = gW1 + (size_t)k * 512 + n;
        short8v o;
        #pragma unroll
        for (int j = 0; j < 8; ++j) o[j] = (short)f2bf(s[(size_t)j * 512]);
        *(short8v*)(gW1T + (size_t)u * 8) = o;
    }
}

// ============== converter: inputs -> bf16 pre-swizzled, LDS-staged ==============
__global__ __launch_bounds__(256) void convert_inputs(
    const float* __restrict__ text, const float* __restrict__ image,
    unsigned short* __restrict__ textW, unsigned short* __restrict__ imageW)
{
    __shared__ __align__(16) char cbuf[8192];

    const int t = threadIdx.x;
    const int tensor = blockIdx.x >> 10;
    const int rb = blockIdx.x & 1023;
    const float* in = tensor ? image : text;
    unsigned short* outp = tensor ? imageW : textW;

    const int row = t >> 2, cq = t & 3;

    for (int s = 0; s < 8; ++s) {
        const float* src = in + ((size_t)rb * 64 + row) * 512 + s * 64 + cq * 16;
        float4 v0 = ((const float4*)src)[0];
        float4 v1 = ((const float4*)src)[1];
        float4 v2 = ((const float4*)src)[2];
        float4 v3 = ((const float4*)src)[3];
        {
            int oct = 2 * cq;
            uint4 p; p.x = pk2(v0.x, v0.y); p.y = pk2(v0.z, v0.w);
            p.z = pk2(v1.x, v1.y); p.w = pk2(v1.z, v1.w);
            *(uint4*)(cbuf + oct * 1024 + ((row * 16) ^ (oct << 4))) = p;
        }
        {
            int oct = 2 * cq + 1;
            uint4 p; p.x = pk2(v2.x, v2.y); p.y = pk2(v2.z, v2.w);
            p.z = pk2(v3.x, v3.y); p.w = pk2(v3.z, v3.w);
            *(uint4*)(cbuf + oct * 1024 + ((row * 16) ^ (oct << 4))) = p;
        }
        __syncthreads();
        unsigned short* dst = outp + ((size_t)rb * 4096 + s * 512 + t * 2) * 8;
        *(uint4*)dst = *(uint4*)(cbuf + t * 32);
        *(uint4*)(dst + 8) = *(uint4*)(cbuf + t * 32 + 16);
        __syncthreads();
    }
}

// ============== fused main: blocks 0..1023 global path (gs -> out[conflict]),
//                blocks 1024..9215 head path (per_aspect) ==============
// Global blocks dispatch FIRST so their stage-bound waves co-reside with head
// blocks' MFMA-heavy waves throughout the dispatch (complementary pipes).
// Head XCD swizzle preserved: hbid = bid-1024, hw XCD = bid%8 = hbid%8 (1024%8==0).
__global__ __launch_bounds__(512, 4) void fused_main(
    const unsigned short* __restrict__ textW, const unsigned short* __restrict__ imageW,
    const unsigned short* __restrict__ W1L, const float* __restrict__ b1,
    const float* __restrict__ ln1g, const float* __restrict__ ln1b,
    const unsigned short* __restrict__ W2T, const float* __restrict__ b2,
    const unsigned short* __restrict__ gW1T, const float* __restrict__ gb1,
    const float* __restrict__ glng, const float* __restrict__ glnb,
    const float* __restrict__ gW2, const float* __restrict__ gb2,
    float* __restrict__ out_gs_conflict, float* __restrict__ out_pa)
{
    __shared__ __align__(1024) char smem[79872];

    const int tid = threadIdx.x;
    const int w = tid >> 6, lane = tid & 63, lg = lane >> 4, lc = lane & 15;

    if (blockIdx.x < 1024) {
        // ================= GLOBAL PATH (R13 body; epilogue writes gs) =================
        char* gsm = smem;
        const int rb = blockIdx.x;
        const size_t row0 = (size_t)rb * 64;
        const char* gWb = (const char*)gW1T;
        const char* tWb = (const char*)textW + (size_t)rb * 65536;
        const char* iWb = (const char*)imageW + (size_t)rb * 65536;
        float* sStat = (float*)(gsm + 73728);
        float* sDot  = (float*)(gsm + 77824);

#define STAGE(p_, st_) do { \
    char* bb_ = gsm + 8192 + (p_) * 32768 + w * 4096; \
    const char* bs_ = gWb + (size_t)(st_) * 32768 + w * 4096 + lane * 16; \
    glds16(bs_, bb_); glds16(bs_ + 1024, bb_ + 1024); \
    glds16(bs_ + 2048, bb_ + 2048); glds16(bs_ + 3072, bb_ + 3072); \
    if (w < 4) { \
        int stx_ = ((st_) < 16) ? (st_) : ((st_) - 16); \
        const char* as_ = (((st_) < 16) ? tWb : iWb) \
                        + (stx_ >> 1) * 8192 + ((stx_ & 1) * 4 + w) * 1024 + lane * 16; \
        glds16(as_, gsm + (p_) * 4096 + w * 1024); \
    } } while (0)

        STAGE(0, 0);
        __syncthreads();

        f32x4 acc[4][4];
        #pragma unroll
        for (int rt = 0; rt < 4; ++rt)
            #pragma unroll
            for (int nt = 0; nt < 4; ++nt) acc[rt][nt] = (f32x4){0.f, 0.f, 0.f, 0.f};

        #pragma unroll 2
        for (int st = 0; st < 32; ++st) {
            const int cur = st & 1;
            char* bufAc = gsm + cur * 4096;
            char* bufBc = gsm + 8192 + cur * 32768;
            if (st < 31) STAGE(cur ^ 1, st + 1);

            const int xk = (st & 1) << 6;
            short8v af[4];
            #pragma unroll
            for (int rt = 0; rt < 4; ++rt) {
                const int row = 16 * rt + lc;
                af[rt] = *(const short8v*)(bufAc + lg * 1024 + ((row * 16) ^ (lg << 4) ^ xk));
            }
            #pragma unroll
            for (int nt = 0; nt < 4; ++nt) {
                short8v bfv = *(const short8v*)(bufBc + (4 * w + nt) * 1024 + lane * 16);
                #pragma unroll
                for (int rt = 0; rt < 4; ++rt)
                    acc[rt][nt] = __builtin_amdgcn_mfma_f32_16x16x32_bf16(af[rt], bfv, acc[rt][nt], 0, 0, 0);
            }
            __syncthreads();
        }
#undef STAGE

        #pragma unroll
        for (int nt = 0; nt < 4; ++nt) {
            float bv = gb1[64 * w + 16 * nt + lc];
            #pragma unroll
            for (int rt = 0; rt < 4; ++rt)
                #pragma unroll
                for (int reg = 0; reg < 4; ++reg) acc[rt][nt][reg] += bv;
        }
        #pragma unroll
        for (int rt = 0; rt < 4; ++rt)
            #pragma unroll
            for (int reg = 0; reg < 4; ++reg) {
                float s1 = 0.f, s2 = 0.f;
                #pragma unroll
                for (int nt = 0; nt < 4; ++nt) { float v = acc[rt][nt][reg]; s1 += v; s2 += v * v; }
                #pragma unroll
                for (int off = 1; off < 16; off <<= 1) {
                    s1 += __shfl_xor(s1, off, 64);
                    s2 += __shfl_xor(s2, off, 64);
                }
                if (lc == 0) {
                    int rr = 16 * rt + 4 * lg + reg;
                    sStat[(w * 64 + rr) * 2 + 0] = s1;
                    sStat[(w * 64 + rr) * 2 + 1] = s2;
                }
            }
        __syncthreads();

        float mug[4][4], rsg[4][4];
        #pragma unroll
        for (int rt = 0; rt < 4; ++rt)
            #pragma unroll
            for (int reg = 0; reg < 4; ++reg) {
                int rr = 16 * rt + 4 * lg + reg;
                float s1 = 0.f, s2 = 0.f;
                #pragma unroll
                for (int ww = 0; ww < 8; ++ww) {
                    s1 += sStat[(ww * 64 + rr) * 2 + 0];
                    s2 += sStat[(ww * 64 + rr) * 2 + 1];
                }
                float m = s1 * (1.0f / 512.0f);
                float var = s2 * (1.0f / 512.0f) - m * m;
                mug[rt][reg] = m;
                rsg[rt][reg] = rsqrtf(var + 1e-5f);
            }

        float dp[4][4];
        #pragma unroll
        for (int rt = 0; rt < 4; ++rt)
            #pragma unroll
            for (int reg = 0; reg < 4; ++reg) dp[rt][reg] = 0.f;
        #pragma unroll
        for (int nt = 0; nt < 4; ++nt) {
            int col = 64 * w + 16 * nt + lc;
            float gv = glng[col], bv = glnb[col], wv = gW2[col];
            #pragma unroll
            for (int rt = 0; rt < 4; ++rt)
                #pragma unroll
                for (int reg = 0; reg < 4; ++reg) {
                    float v = (acc[rt][nt][reg] - mug[rt][reg]) * rsg[rt][reg] * gv + bv;
                    dp[rt][reg] += gelu_exact(v) * wv;
                }
        }
        #pragma unroll
        for (int rt = 0; rt < 4; ++rt)
            #pragma unroll
            for (int reg = 0; reg < 4; ++reg) {
                float d = dp[rt][reg];
                #pragma unroll
                for (int off = 1; off < 16; off <<= 1) d += __shfl_xor(d, off, 64);
                if (lc == 0) sDot[w * 64 + 16 * rt + 4 * lg + reg] = d;
            }
        __syncthreads();

        if (tid < 64) {
            int rr = tid;
            float z = gb2[0];
            #pragma unroll
            for (int ww = 0; ww < 8; ++ww) z += sDot[ww * 64 + rr];
            // write sigmoid (gs) into the conflict slot; finalize combines with pa
            out_gs_conflict[row0 + rr] = 1.0f / (1.0f + expf(-z));
        }
        return;
    }

    // ================= HEAD PATH (R13 body, bid shifted) =================
    const int bid = blockIdx.x - 1024;
    const int wr = w >> 1, wc = w & 1;
    const int xr = bid & 7;
    const int q = bid >> 3;
    const int hd = q & 7;
    const int rb = ((q >> 3) << 3) | xr;
    const size_t row0 = (size_t)rb * 64;

    const char* W1base = (const char*)W1L + (size_t)hd * 131072;
    const char* tWb = (const char*)textW + (size_t)rb * 65536 + w * 1024 + lane * 16;
    const char* iWb = (const char*)imageW + (size_t)rb * 65536 + w * 1024 + lane * 16;
    float* sS = (float*)(smem + 65536);
    unsigned short* hb = (unsigned short*)(smem + 67584 + w * 1152);

#define STAGE_A(buf_, s_) do { \
    glds16(tWb + (s_) * 8192, (buf_) + w * 2048); \
    glds16(iWb + (s_) * 8192, (buf_) + w * 2048 + 1024); } while (0)
#define STAGE_B(buf_, s_) do { \
    const char* bs_ = W1base + (s_) * 16384 + w * 2048 + lane * 16; \
    glds16(bs_, (buf_) + w * 2048); \
    glds16(bs_ + 1024, (buf_) + w * 2048 + 1024); } while (0)

    STAGE_A(smem, 0);
    STAGE_B(smem + 32768, 0);
    __syncthreads();

    f32x4 acc[2][4];
    #pragma unroll
    for (int rt = 0; rt < 2; ++rt)
        #pragma unroll
        for (int nt = 0; nt < 4; ++nt) acc[rt][nt] = (f32x4){0.f, 0.f, 0.f, 0.f};

    #pragma unroll
    for (int s = 0; s < 8; ++s) {
        const int cur = s & 1;
        char* bufAc = smem + cur * 16384;
        char* bufBc = smem + 32768 + cur * 16384;
        if (s < 7) {
            STAGE_A(smem + (cur ^ 1) * 16384, s + 1);
            STAGE_B(smem + 32768 + (cur ^ 1) * 16384, s + 1);
        }
        #pragma unroll
        for (int kk = 0; kk < 2; ++kk) {
            const int o = kk * 4 + lg;
            short8v afv[2];
            #pragma unroll
            for (int rt = 0; rt < 2; ++rt) {
                const int row = 32 * wr + 16 * rt + lc;
                afv[rt] = *(const short8v*)(bufAc + o * 2048 + ((row * 16) ^ (o << 4)));
            }
            #pragma unroll
            for (int nt = 0; nt < 4; ++nt) {
                short8v bfv = *(const short8v*)(bufBc + kk * 8192 + (4 * wc + nt) * 1024 + lane * 16);
                acc[0][nt] = __builtin_amdgcn_mfma_f32_16x16x32_bf16(afv[0], bfv, acc[0][nt], 0, 0, 0);
                acc[1][nt] = __builtin_amdgcn_mfma_f32_16x16x32_bf16(afv[1], bfv, acc[1][nt], 0, 0, 0);
            }
        }
        __syncthreads();
    }
#undef STAGE_A
#undef STAGE_B

    #pragma unroll
    for (int nt = 0; nt < 4; ++nt) {
        float bv = b1[hd * 128 + 64 * wc + 16 * nt + lc];
        #pragma unroll
        for (int rt = 0; rt < 2; ++rt)
            #pragma unroll
            for (int reg = 0; reg < 4; ++reg) acc[rt][nt][reg] += bv;
    }
    #pragma unroll
    for (int rt = 0; rt < 2; ++rt)
        #pragma unroll
        for (int reg = 0; reg < 4; ++reg) {
            float s1 = 0.f, s2 = 0.f;
            #pragma unroll
            for (int nt = 0; nt < 4; ++nt) { float v = acc[rt][nt][reg]; s1 += v; s2 += v * v; }
            #pragma unroll
            for (int off = 1; off < 16; off <<= 1) {
                s1 += __shfl_xor(s1, off, 64);
                s2 += __shfl_xor(s2, off, 64);
            }
            if (lc == 0) {
                int row = 32 * wr + 16 * rt + 4 * lg + reg;
                sS[(wc * 128 + row) * 2 + 0] = s1;
                sS[(wc * 128 + row) * 2 + 1] = s2;
            }
        }
    __syncthreads();

    float mu[2][4], rsig[2][4];
    #pragma unroll
    for (int rt = 0; rt < 2; ++rt)
        #pragma unroll
        for (int reg = 0; reg < 4; ++reg) {
            int row = 32 * wr + 16 * rt + 4 * lg + reg;
            float s1 = sS[row * 2 + 0] + sS[(128 + row) * 2 + 0];
            float s2 = sS[row * 2 + 1] + sS[(128 + row) * 2 + 1];
            float m = s1 * (1.0f / 128.0f);
            float var = s2 * (1.0f / 128.0f) - m * m;
            mu[rt][reg] = m;
            rsig[rt][reg] = rsqrtf(var + 1e-5f);
        }
    #pragma unroll
    for (int nt = 0; nt < 4; ++nt) {
        int col = 64 * wc + 16 * nt + lc;
        float gv = ln1g[hd * 128 + col];
        float bv = ln1b[hd * 128 + col];
        #pragma unroll
        for (int rt = 0; rt < 2; ++rt)
            #pragma unroll
            for (int reg = 0; reg < 4; ++reg) {
                float v = (acc[rt][nt][reg] - mu[rt][reg]) * rsig[rt][reg] * gv + bv;
                acc[rt][nt][reg] = gelu_exact(v);
            }
    }

    const char* W2b = (const char*)W2T + (size_t)hd * 16384;
    #pragma unroll
    for (int rt = 0; rt < 2; ++rt) {
        f32x4 acc2[4];
        #pragma unroll
        for (int nt2 = 0; nt2 < 4; ++nt2) acc2[nt2] = (f32x4){0.f, 0.f, 0.f, 0.f};

        #pragma unroll
        for (int kk2 = 0; kk2 < 2; ++kk2) {
            #pragma unroll
            for (int ntl = 0; ntl < 2; ++ntl) {
                const int nt = 2 * kk2 + ntl;
                const int kk = 16 * ntl + lc;
                #pragma unroll
                for (int reg = 0; reg < 4; ++reg)
                    hb[(4 * lg + reg) * 36 + kk] = f2bf(acc[rt][nt][reg]);
            }
            short8v af2 = *(const short8v*)((const char*)hb + lc * 72 + 16 * lg);
            const char* wb = W2b + (2 * wc + kk2) * 4096 + lane * 16;
            #pragma unroll
            for (int nt2 = 0; nt2 < 4; ++nt2) {
                short8v w2f = *(const short8v*)(wb + nt2 * 1024);
                acc2[nt2] = __builtin_amdgcn_mfma_f32_16x16x32_bf16(af2, w2f, acc2[nt2], 0, 0, 0);
            }
        }
        if (wc == 0) {
            #pragma unroll
            for (int nt2 = 0; nt2 < 4; ++nt2) {
                float bv = b2[hd * 64 + 16 * nt2 + lc];
                #pragma unroll
                for (int reg = 0; reg < 4; ++reg) {
                    int row = 32 * wr + 16 * rt + 4 * lg + reg;
                    int col = 16 * nt2 + lc;
                    *(float*)(smem + row * 256 + ((col * 4) ^ ((row & 7) << 4))) = acc2[nt2][reg] + bv;
                }
            }
        }
        __syncthreads();
        if (wc == 1) {
            #pragma unroll
            for (int nt2 = 0; nt2 < 4; ++nt2)
                #pragma unroll
                for (int reg = 0; reg < 4; ++reg) {
                    int row = 32 * wr + 16 * rt + 4 * lg + reg;
                    int col = 16 * nt2 + lc;
                    float* p = (float*)(smem + row * 256 + ((col * 4) ^ ((row & 7) << 4)));
                    *p += acc2[nt2][reg];
                }
        }
        __syncthreads();
    }

    if (w < 4) {
        int r = 16 * w + lc;
        int sw = (r & 7) << 4;
        float nt_ = 0.f, ni_ = 0.f, pr = 0.f;
        #pragma unroll
        for (int q2 = 0; q2 < 4; ++q2) {
            int c16 = 2 * lg + (q2 & 1) + (q2 >> 1) * 8;
            float4 a = *(const float4*)(smem + r * 256 + ((c16 * 16) ^ sw));
            float4 b = *(const float4*)(smem + (r + 64) * 256 + ((c16 * 16) ^ sw));
            nt_ += a.x * a.x + a.y * a.y + a.z * a.z + a.w * a.w;
            ni_ += b.x * b.x + b.y * b.y + b.z * b.z + b.w * b.w;
            pr  += a.x * b.x + a.y * b.y + a.z * b.z + a.w * b.w;
        }
        nt_ += __shfl_xor(nt_, 16, 64); ni_ += __shfl_xor(ni_, 16, 64); pr += __shfl_xor(pr, 16, 64);
        nt_ += __shfl_xor(nt_, 32, 64); ni_ += __shfl_xor(ni_, 32, 64); pr += __shfl_xor(pr, 32, 64);
        if (lg == 0) {
            float denom = fmaxf(sqrtf(nt_), 1e-12f) * fmaxf(sqrtf(ni_), 1e-12f);
            out_pa[(row0 + r) * 8 + hd] = pr / denom;
        }
    }
}

// ============== finalize: conflict = clip(1 - 0.7*softmax(aw)@pa - 0.3*gs) ==============
__global__ __launch_bounds__(256) void finalize(
    const float* __restrict__ aw, const float* __restrict__ pa,
    float* __restrict__ out_conflict)
{
    int r = blockIdx.x * 256 + threadIdx.x;
    float wv[8], mx = -1e30f;
    #pragma unroll
    for (int i = 0; i < 8; ++i) { wv[i] = aw[i]; mx = fmaxf(mx, wv[i]); }
    float sum = 0.f;
    #pragma unroll
    for (int i = 0; i < 8; ++i) { wv[i] = __expf(wv[i] - mx); sum += wv[i]; }
    float inv = __builtin_amdgcn_rcpf(sum);
    const float* par = pa + (size_t)r * 8;
    float4 p0 = ((const float4*)par)[0];
    float4 p1 = ((const float4*)par)[1];
    float wsim = p0.x * wv[0] + p0.y * wv[1] + p0.z * wv[2] + p0.w * wv[3]
               + p1.x * wv[4] + p1.y * wv[5] + p1.z * wv[6] + p1.w * wv[7];
    wsim *= inv;
    float gs = out_conflict[r];
    float conf = 1.0f - (0.7f * wsim + 0.3f * gs);
    out_conflict[r] = fminf(fmaxf(conf, 0.0f), 1.0f);
}

extern "C" void kernel_launch(void* const* d_in, const int* in_sizes, int n_in,
                              void* d_out, int out_size, void* d_ws, size_t ws_size,
                              hipStream_t stream) {
    const float* text  = (const float*)d_in[0];
    const float* image = (const float*)d_in[1];
    const float* W1    = (const float*)d_in[2];
    const float* b1    = (const float*)d_in[3];
    const float* ln1g  = (const float*)d_in[4];
    const float* ln1b  = (const float*)d_in[5];
    const float* W2    = (const float*)d_in[6];
    const float* b2    = (const float*)d_in[7];
    const float* aw    = (const float*)d_in[8];
    const float* gW1   = (const float*)d_in[9];
    const float* gb1   = (const float*)d_in[10];
    const float* glng  = (const float*)d_in[11];
    const float* glnb  = (const float*)d_in[12];
    const float* gW2   = (const float*)d_in[13];
    const float* gb2   = (const float*)d_in[14];

    float* out = (float*)d_out;
    float* out_pa = out + B_TOTAL;

    unsigned short* textW  = (unsigned short*)d_ws;                           // 64MB
    unsigned short* imageW = (unsigned short*)((char*)d_ws + 67108864);       // 64MB
    unsigned short* W1L    = (unsigned short*)((char*)d_ws + 134217728);      // 1MB
    unsigned short* W2T    = (unsigned short*)((char*)d_ws + 135266304);      // 128KB
    unsigned short* gW1T   = (unsigned short*)((char*)d_ws + 135397376);      // 1MB

    convert_weights<<<544, 256, 0, stream>>>(W1, W2, gW1, W1L, W2T, gW1T);
    convert_inputs<<<2048, 256, 0, stream>>>(text, image, textW, imageW);
    fused_main<<<9216, 512, 0, stream>>>(textW, imageW, W1L, b1, ln1g, ln1b, W2T, b2,
                                         gW1T, gb1, glng, glnb, gW2, gb2,
                                         out, out_pa);
    finalize<<<256, 256, 0, stream>>>(aw, out_pa, out);
}